// Round 1
// baseline (2955.091 us; speedup 1.0000x reference)
//
#include <hip/hip_runtime.h>
#include <math.h>

// Problem constants
#define NE    1024   // n_embd
#define DI    2048   // d_inner
#define LSEQ  2048   // L
#define NB    2      // batch
#define DS    16     // d_state
#define DTR   64     // dt_rank
#define XDW   96     // dt_rank + 2*d_state

__device__ __forceinline__ float softplusf(float x) {
    return (x > 20.f) ? x : log1pf(expf(x));
}
__device__ __forceinline__ float siluf(float x) {
    return x / (1.f + expf(-x));
}

// ---------------- LayerNorm: one block per row ----------------
__global__ __launch_bounds__(256) void ln_kernel(
    const float* __restrict__ x, const float* __restrict__ g,
    const float* __restrict__ b, float* __restrict__ xn)
{
    int row = blockIdx.x;
    int tid = threadIdx.x;
    const float4* xr = (const float4*)(x + (size_t)row * NE);
    float4 v = xr[tid];                       // 256 threads * 4 = 1024
    float s  = v.x + v.y + v.z + v.w;
    float sq = v.x*v.x + v.y*v.y + v.z*v.z + v.w*v.w;
    #pragma unroll
    for (int off = 32; off > 0; off >>= 1) {  // wave64 reduce
        s  += __shfl_down(s, off);
        sq += __shfl_down(sq, off);
    }
    __shared__ float ss[4], ssq[4];
    __shared__ float smu, srstd;
    int wv = tid >> 6, lane = tid & 63;
    if (lane == 0) { ss[wv] = s; ssq[wv] = sq; }
    __syncthreads();
    if (tid == 0) {
        float a = ss[0] + ss[1] + ss[2] + ss[3];
        float q = ssq[0] + ssq[1] + ssq[2] + ssq[3];
        float mu  = a * (1.f / NE);
        float var = q * (1.f / NE) - mu * mu;   // biased var, matches jnp.var
        smu = mu; srstd = rsqrtf(var + 1e-5f);
    }
    __syncthreads();
    float mu = smu, rstd = srstd;
    float4 gv = ((const float4*)g)[tid];
    float4 bv = ((const float4*)b)[tid];
    float4 o;
    o.x = (v.x - mu) * rstd * gv.x + bv.x;
    o.y = (v.y - mu) * rstd * gv.y + bv.y;
    o.z = (v.z - mu) * rstd * gv.z + bv.z;
    o.w = (v.w - mu) * rstd * gv.w + bv.w;
    ((float4*)(xn + (size_t)row * NE))[tid] = o;
}

// ---------------- Generic tiled fp32 GEMM: C = act(A * W^T + bias) + resid ----
// A: M x K (row stride lda), W: N x K (row-major, stride K), C: M x N (stride ldc)
// M must be a multiple of 128; K a multiple of 8; N guarded.
#define BM 128
#define BN 128
#define BK 8

template<int ACT>  // 0 = none, 1 = softplus
__global__ __launch_bounds__(256) void gemm_nt(
    const float* __restrict__ A, int lda,
    const float* __restrict__ W,
    const float* __restrict__ bias,
    const float* __restrict__ resid, int ldr,
    float* __restrict__ C, int ldc,
    int M, int N, int K)
{
    __shared__ float As[BK][BM];
    __shared__ float Ws[BK][BN];
    int tid = threadIdx.x;
    int tx = tid & 15, ty = tid >> 4;          // 16x16 thread grid
    int row0 = blockIdx.y * BM, col0 = blockIdx.x * BN;
    int lr = tid >> 1;                         // 0..127 tile row
    int lk = (tid & 1) * 4;                    // 0 or 4
    float acc[8][8];
    #pragma unroll
    for (int i = 0; i < 8; ++i)
        #pragma unroll
        for (int j = 0; j < 8; ++j) acc[i][j] = 0.f;

    for (int k0 = 0; k0 < K; k0 += BK) {
        float4 av = *(const float4*)(A + (size_t)(row0 + lr) * lda + k0 + lk);
        int wrow = col0 + lr;
        float4 wv = make_float4(0.f, 0.f, 0.f, 0.f);
        if (wrow < N) wv = *(const float4*)(W + (size_t)wrow * K + k0 + lk);
        As[lk+0][lr] = av.x; As[lk+1][lr] = av.y; As[lk+2][lr] = av.z; As[lk+3][lr] = av.w;
        Ws[lk+0][lr] = wv.x; Ws[lk+1][lr] = wv.y; Ws[lk+2][lr] = wv.z; Ws[lk+3][lr] = wv.w;
        __syncthreads();
        #pragma unroll
        for (int kk = 0; kk < BK; ++kk) {
            float a[8], w[8];
            #pragma unroll
            for (int i = 0; i < 8; ++i) a[i] = As[kk][ty*8 + i];
            #pragma unroll
            for (int j = 0; j < 8; ++j) w[j] = Ws[kk][tx*8 + j];
            #pragma unroll
            for (int i = 0; i < 8; ++i)
                #pragma unroll
                for (int j = 0; j < 8; ++j)
                    acc[i][j] = fmaf(a[i], w[j], acc[i][j]);
        }
        __syncthreads();
    }
    #pragma unroll
    for (int i = 0; i < 8; ++i) {
        size_t r = (size_t)(row0 + ty*8 + i);
        #pragma unroll
        for (int j = 0; j < 8; ++j) {
            int c = col0 + tx*8 + j;
            if (c < N) {
                float v = acc[i][j];
                if (bias)  v += bias[c];
                if (ACT == 1) v = softplusf(v);
                if (resid) v += resid[r * (size_t)ldr + c];
                C[r * (size_t)ldc + c] = v;
            }
        }
    }
}

// ---------------- Causal depthwise conv (width 4) + SiLU ----------------
// u = xz[..., 0:DI];  uc[b,t,d] = silu(conv_b[d] + sum_k w[d][k]*u[b,t-3+k,d])
__global__ __launch_bounds__(256) void conv_silu_kernel(
    const float* __restrict__ xz, const float* __restrict__ cw,
    const float* __restrict__ cb, float* __restrict__ uc)
{
    size_t idx = (size_t)blockIdx.x * 256 + threadIdx.x;  // over NB*LSEQ*DI
    int d = (int)(idx & (DI - 1));
    size_t bt = idx >> 11;                                // row index b*L+t
    int t = (int)(bt & (LSEQ - 1));
    float4 w4 = *(const float4*)(cw + (size_t)d * 4);
    float wv[4] = {w4.x, w4.y, w4.z, w4.w};
    float acc = cb[d];
    #pragma unroll
    for (int k = 0; k < 4; ++k) {
        int tp = t - 3 + k;
        if (tp >= 0)
            acc = fmaf(wv[k], xz[((bt - (size_t)(3 - k)) << 12) + d], acc);
    }
    uc[idx] = siluf(acc);
}

// ---------------- Selective scan: one thread per (b, d) ----------------
__global__ __launch_bounds__(256) void scan_kernel(
    const float* __restrict__ dlt, const float* __restrict__ uc,
    const float* __restrict__ xdbl, const float* __restrict__ A_log,
    const float* __restrict__ Dp, float* __restrict__ y)
{
    int b = blockIdx.x >> 3;
    int d = ((blockIdx.x & 7) << 8) + threadIdx.x;
    float Ac[DS], h[DS];
    #pragma unroll
    for (int s = 0; s < DS; ++s) {
        Ac[s] = -expf(A_log[(size_t)d * DS + s]);
        h[s] = 0.f;
    }
    float Dd = Dp[d];
    size_t ix = (size_t)b * LSEQ * DI + d;
    size_t xr = (size_t)b * LSEQ * XDW;
    for (int t = 0; t < LSEQ; ++t) {
        float dv = dlt[ix];
        float ut = uc[ix];
        const float4* Bp = (const float4*)(xdbl + xr + DTR);  // B at [64:80], C at [80:96]
        float4 B0 = Bp[0], B1 = Bp[1], B2 = Bp[2], B3 = Bp[3];
        float4 C0 = Bp[4], C1 = Bp[5], C2 = Bp[6], C3 = Bp[7];
        float Bv[16] = {B0.x,B0.y,B0.z,B0.w, B1.x,B1.y,B1.z,B1.w,
                        B2.x,B2.y,B2.z,B2.w, B3.x,B3.y,B3.z,B3.w};
        float Cv[16] = {C0.x,C0.y,C0.z,C0.w, C1.x,C1.y,C1.z,C1.w,
                        C2.x,C2.y,C2.z,C2.w, C3.x,C3.y,C3.z,C3.w};
        float du = dv * ut;
        float yacc = 0.f;
        #pragma unroll
        for (int s = 0; s < DS; ++s) {
            float dA = expf(dv * Ac[s]);
            h[s] = fmaf(dA, h[s], du * Bv[s]);
            yacc = fmaf(h[s], Cv[s], yacc);
        }
        y[ix] = fmaf(ut, Dd, yacc);
        ix += DI;
        xr += XDW;
    }
}

// ---------------- Gate: y *= silu(res), in place ----------------
__global__ __launch_bounds__(256) void gate_kernel(
    float* __restrict__ y, const float* __restrict__ xz)
{
    size_t i4 = ((size_t)blockIdx.x * 256 + threadIdx.x) * 4;  // over NB*LSEQ*DI
    size_t row = i4 >> 11;
    int dd = (int)(i4 & (DI - 1));
    float4 yv = *(float4*)(y + i4);
    float4 r = *(const float4*)(xz + (row << 12) + DI + dd);   // res half
    yv.x *= siluf(r.x); yv.y *= siluf(r.y);
    yv.z *= siluf(r.z); yv.w *= siluf(r.w);
    *(float4*)(y + i4) = yv;
}

extern "C" void kernel_launch(void* const* d_in, const int* in_sizes, int n_in,
                              void* d_out, int out_size, void* d_ws, size_t ws_size,
                              hipStream_t stream)
{
    const float* x        = (const float*)d_in[0];
    const float* ln_g     = (const float*)d_in[1];
    const float* ln_b     = (const float*)d_in[2];
    const float* in_w     = (const float*)d_in[3];   // (4096, 1024)
    const float* conv_w   = (const float*)d_in[4];   // (2048, 1, 4)
    const float* conv_b   = (const float*)d_in[5];
    const float* xproj_w  = (const float*)d_in[6];   // (96, 2048)
    const float* dtproj_w = (const float*)d_in[7];   // (2048, 64)
    const float* dtproj_b = (const float*)d_in[8];
    const float* A_log    = (const float*)d_in[9];   // (2048, 16)
    const float* Dvec     = (const float*)d_in[10];
    const float* out_w    = (const float*)d_in[11];  // (1024, 2048)
    float* out = (float*)d_out;

    // Workspace layout (floats). Total 42,336,256 floats = 169.3 MB.
    float* ws    = (float*)d_ws;
    float* xz    = ws;                  // 4096 x 4096  (u | res)
    float* uc    = ws + 16777216;       // 4096 x 2048
    float* yb    = ws + 25165824;       // 4096 x 2048
    float* dlt   = ws + 33554432;       // 4096 x 2048
    float* xnorm = ws + 33554432;       // 4096 x 1024 (dead before dlt written)
    float* xdbl  = ws + 41943040;       // 4096 x 96

    const int R = NB * LSEQ;            // 4096 rows

    // 1. LayerNorm
    ln_kernel<<<R, 256, 0, stream>>>(x, ln_g, ln_b, xnorm);
    // 2. in_proj: xz = xnorm @ in_w^T            (4096 x 4096)
    gemm_nt<0><<<dim3((2*DI)/BN, R/BM), 256, 0, stream>>>(
        xnorm, NE, in_w, nullptr, nullptr, 0, xz, 2*DI, R, 2*DI, NE);
    // 3. causal depthwise conv + SiLU -> uc
    conv_silu_kernel<<<(R * DI) / 256, 256, 0, stream>>>(xz, conv_w, conv_b, uc);
    // 4. x_proj: xdbl = uc @ xproj_w^T           (4096 x 96)
    gemm_nt<0><<<dim3(1, R/BM), 256, 0, stream>>>(
        uc, DI, xproj_w, nullptr, nullptr, 0, xdbl, XDW, R, XDW, DI);
    // 5. dt_proj + softplus: dlt = softplus(xdbl[:, :64] @ dtproj_w^T + b)
    gemm_nt<1><<<dim3(DI/BN, R/BM), 256, 0, stream>>>(
        xdbl, XDW, dtproj_w, dtproj_b, nullptr, 0, dlt, DI, R, DI, DTR);
    // 6. selective scan -> yb
    scan_kernel<<<NB * (DI / 256), 256, 0, stream>>>(dlt, uc, xdbl, A_log, Dvec, yb);
    // 7. gate: yb *= silu(res)
    gate_kernel<<<(R * DI / 4) / 256, 256, 0, stream>>>(yb, xz);
    // 8. out_proj + residual: out = x + yb @ out_w^T
    gemm_nt<0><<<dim3(NE/BN, R/BM), 256, 0, stream>>>(
        yb, DI, out_w, nullptr, x, NE, out, NE, R, NE, DI);
}

// Round 2
// 1308.528 us; speedup vs baseline: 2.2583x; 2.2583x over previous
//
#include <hip/hip_runtime.h>
#include <math.h>

// Problem constants
#define NE    1024   // n_embd
#define DI    2048   // d_inner
#define LSEQ  2048   // L
#define NB    2      // batch
#define DS    16     // d_state
#define DTR   64     // dt_rank
#define XDW   96     // dt_rank + 2*d_state

#define CCH   64           // number of time chunks for the scan
#define TCH   (LSEQ/CCH)   // 32 timesteps per chunk

__device__ __forceinline__ float softplusf(float x) {
    return (x > 20.f) ? x : log1pf(expf(x));
}
__device__ __forceinline__ float siluf(float x) {
    return x / (1.f + __expf(-x));
}

// ---------------- LayerNorm: one block per row ----------------
__global__ __launch_bounds__(256) void ln_kernel(
    const float* __restrict__ x, const float* __restrict__ g,
    const float* __restrict__ b, float* __restrict__ xn)
{
    int row = blockIdx.x;
    int tid = threadIdx.x;
    const float4* xr = (const float4*)(x + (size_t)row * NE);
    float4 v = xr[tid];                       // 256 threads * 4 = 1024
    float s  = v.x + v.y + v.z + v.w;
    float sq = v.x*v.x + v.y*v.y + v.z*v.z + v.w*v.w;
    #pragma unroll
    for (int off = 32; off > 0; off >>= 1) {  // wave64 reduce
        s  += __shfl_down(s, off);
        sq += __shfl_down(sq, off);
    }
    __shared__ float ss[4], ssq[4];
    __shared__ float smu, srstd;
    int wv = tid >> 6, lane = tid & 63;
    if (lane == 0) { ss[wv] = s; ssq[wv] = sq; }
    __syncthreads();
    if (tid == 0) {
        float a = ss[0] + ss[1] + ss[2] + ss[3];
        float q = ssq[0] + ssq[1] + ssq[2] + ssq[3];
        float mu  = a * (1.f / NE);
        float var = q * (1.f / NE) - mu * mu;   // biased var, matches jnp.var
        smu = mu; srstd = rsqrtf(var + 1e-5f);
    }
    __syncthreads();
    float mu = smu, rstd = srstd;
    float4 gv = ((const float4*)g)[tid];
    float4 bv = ((const float4*)b)[tid];
    float4 o;
    o.x = (v.x - mu) * rstd * gv.x + bv.x;
    o.y = (v.y - mu) * rstd * gv.y + bv.y;
    o.z = (v.z - mu) * rstd * gv.z + bv.z;
    o.w = (v.w - mu) * rstd * gv.w + bv.w;
    ((float4*)(xn + (size_t)row * NE))[tid] = o;
}

// ---------------- Generic tiled fp32 GEMM: C = act(A * W^T + bias) + resid ----
// A: M x K (row stride lda), W: N x K (row-major, stride K), C: M x N (stride ldc)
// M must be a multiple of 128; K a multiple of 8; N guarded.
#define BM 128
#define BN 128
#define BK 8

template<int ACT>  // 0 = none, 1 = softplus
__global__ __launch_bounds__(256) void gemm_nt(
    const float* __restrict__ A, int lda,
    const float* __restrict__ W,
    const float* __restrict__ bias,
    const float* __restrict__ resid, int ldr,
    float* __restrict__ C, int ldc,
    int M, int N, int K)
{
    __shared__ float As[BK][BM];
    __shared__ float Ws[BK][BN];
    int tid = threadIdx.x;
    int tx = tid & 15, ty = tid >> 4;          // 16x16 thread grid
    int row0 = blockIdx.y * BM, col0 = blockIdx.x * BN;
    int lr = tid >> 1;                         // 0..127 tile row
    int lk = (tid & 1) * 4;                    // 0 or 4
    float acc[8][8];
    #pragma unroll
    for (int i = 0; i < 8; ++i)
        #pragma unroll
        for (int j = 0; j < 8; ++j) acc[i][j] = 0.f;

    for (int k0 = 0; k0 < K; k0 += BK) {
        float4 av = *(const float4*)(A + (size_t)(row0 + lr) * lda + k0 + lk);
        int wrow = col0 + lr;
        float4 wv = make_float4(0.f, 0.f, 0.f, 0.f);
        if (wrow < N) wv = *(const float4*)(W + (size_t)wrow * K + k0 + lk);
        As[lk+0][lr] = av.x; As[lk+1][lr] = av.y; As[lk+2][lr] = av.z; As[lk+3][lr] = av.w;
        Ws[lk+0][lr] = wv.x; Ws[lk+1][lr] = wv.y; Ws[lk+2][lr] = wv.z; Ws[lk+3][lr] = wv.w;
        __syncthreads();
        #pragma unroll
        for (int kk = 0; kk < BK; ++kk) {
            float a[8], w[8];
            #pragma unroll
            for (int i = 0; i < 8; ++i) a[i] = As[kk][ty*8 + i];
            #pragma unroll
            for (int j = 0; j < 8; ++j) w[j] = Ws[kk][tx*8 + j];
            #pragma unroll
            for (int i = 0; i < 8; ++i)
                #pragma unroll
                for (int j = 0; j < 8; ++j)
                    acc[i][j] = fmaf(a[i], w[j], acc[i][j]);
        }
        __syncthreads();
    }
    #pragma unroll
    for (int i = 0; i < 8; ++i) {
        size_t r = (size_t)(row0 + ty*8 + i);
        #pragma unroll
        for (int j = 0; j < 8; ++j) {
            int c = col0 + tx*8 + j;
            if (c < N) {
                float v = acc[i][j];
                if (bias)  v += bias[c];
                if (ACT == 1) v = softplusf(v);
                if (resid) v += resid[r * (size_t)ldr + c];
                C[r * (size_t)ldc + c] = v;
            }
        }
    }
}

// ---------------- Causal depthwise conv (width 4) + SiLU ----------------
// u = xz[..., 0:DI];  uc[b,t,d] = silu(conv_b[d] + sum_k w[d][k]*u[b,t-3+k,d])
__global__ __launch_bounds__(256) void conv_silu_kernel(
    const float* __restrict__ xz, const float* __restrict__ cw,
    const float* __restrict__ cb, float* __restrict__ uc)
{
    size_t idx = (size_t)blockIdx.x * 256 + threadIdx.x;  // over NB*LSEQ*DI
    int d = (int)(idx & (DI - 1));
    size_t bt = idx >> 11;                                // row index b*L+t
    int t = (int)(bt & (LSEQ - 1));
    float4 w4 = *(const float4*)(cw + (size_t)d * 4);
    float wv[4] = {w4.x, w4.y, w4.z, w4.w};
    float acc = cb[d];
    #pragma unroll
    for (int k = 0; k < 4; ++k) {
        int tp = t - 3 + k;
        if (tp >= 0)
            acc = fmaf(wv[k], xz[((bt - (size_t)(3 - k)) << 12) + d], acc);
    }
    uc[idx] = siluf(acc);
}

// ---------------- Chunk-parallel selective scan ----------------
// Pass A (FINAL=false): per (b,d,chunk) compute P = prod dA, S = local scan from 0.
// Pass C (FINAL=true):  re-scan chunk from H0 (stored in S by pass B), write
//                       y = (sum_s h*C + u*D) * silu(res)  [gate fused].
// Block = 256 threads over d; B/C rows of the chunk staged in LDS once per block.
template<bool FINAL>
__global__ __launch_bounds__(256) void scan_chunk_kernel(
    const float* __restrict__ dlt, const float* __restrict__ uc,
    const float* __restrict__ xdbl, const float* __restrict__ A_log,
    const float* __restrict__ Dp, const float* __restrict__ xz,
    float* __restrict__ P, float* __restrict__ S, float* __restrict__ y)
{
    __shared__ float sBC[TCH][32];     // [tt][0:16]=B, [16:32]=C
    int tid = threadIdx.x;
    int d = blockIdx.x * 256 + tid;
    int c = blockIdx.y;
    int b = blockIdx.z;
    int row0 = b * LSEQ + c * TCH;

    {   // stage B,C: TCH*32 floats = 256 float4 loads
        int tt = tid >> 3, j4 = (tid & 7) * 4;
        const float4* src = (const float4*)(xdbl + (size_t)(row0 + tt) * XDW + DTR + j4);
        *(float4*)(&sBC[tt][j4]) = *src;
    }
    __syncthreads();

    float Ac[DS], h[DS], p[DS];
    #pragma unroll
    for (int s = 0; s < DS; ++s) {
        Ac[s] = -expf(A_log[(size_t)d * DS + s]);
        p[s] = 1.f;
    }
    size_t soff = (((size_t)b * CCH + c) * DI + d) * DS;
    if (FINAL) {
        #pragma unroll
        for (int s = 0; s < DS; ++s) h[s] = S[soff + s];   // H0 from pass B
    } else {
        #pragma unroll
        for (int s = 0; s < DS; ++s) h[s] = 0.f;
    }
    float Dd = Dp[d];
    size_t ix = (size_t)row0 * DI + d;
    for (int tt = 0; tt < TCH; ++tt) {
        float dv = dlt[ix];
        float ut = uc[ix];
        float du = dv * ut;
        float yacc = 0.f;
        #pragma unroll
        for (int s = 0; s < DS; ++s) {
            float e = __expf(dv * Ac[s]);
            h[s] = fmaf(e, h[s], du * sBC[tt][s]);
            if (FINAL) yacc = fmaf(h[s], sBC[tt][16 + s], yacc);
            else       p[s] *= e;
        }
        if (FINAL) {
            float res = xz[((size_t)(row0 + tt) << 12) + DI + d];
            y[ix] = fmaf(ut, Dd, yacc) * siluf(res);
        }
        ix += DI;
    }
    if (!FINAL) {
        #pragma unroll
        for (int s = 0; s < DS; ++s) { P[soff + s] = p[s]; S[soff + s] = h[s]; }
    }
}

// Pass B: per (b,d,s), sequentially combine chunks; S[c] becomes H0 of chunk c.
__global__ __launch_bounds__(256) void scan_combine_kernel(
    const float* __restrict__ P, float* __restrict__ S)
{
    int idx = blockIdx.x * 256 + threadIdx.x;   // over NB*DI*DS = 65536
    int b = idx >> 15;                          // DI*DS = 32768
    int rest = idx & 32767;
    float h = 0.f;
    for (int c = 0; c < CCH; ++c) {
        size_t off = (((size_t)b * CCH + c) << 15) + rest;
        float tmp = S[off];
        float pv  = P[off];
        S[off] = h;                             // chunk-start state
        h = fmaf(pv, h, tmp);                   // chunk-end state
    }
}

extern "C" void kernel_launch(void* const* d_in, const int* in_sizes, int n_in,
                              void* d_out, int out_size, void* d_ws, size_t ws_size,
                              hipStream_t stream)
{
    const float* x        = (const float*)d_in[0];
    const float* ln_g     = (const float*)d_in[1];
    const float* ln_b     = (const float*)d_in[2];
    const float* in_w     = (const float*)d_in[3];   // (4096, 1024)
    const float* conv_w   = (const float*)d_in[4];   // (2048, 1, 4)
    const float* conv_b   = (const float*)d_in[5];
    const float* xproj_w  = (const float*)d_in[6];   // (96, 2048)
    const float* dtproj_w = (const float*)d_in[7];   // (2048, 64)
    const float* dtproj_b = (const float*)d_in[8];
    const float* A_log    = (const float*)d_in[9];   // (2048, 16)
    const float* Dvec     = (const float*)d_in[10];
    const float* out_w    = (const float*)d_in[11];  // (1024, 2048)
    float* out = (float*)d_out;

    // Workspace layout (floats). Total 50,724,864 floats = 202.9 MB.
    float* ws    = (float*)d_ws;
    float* xz    = ws;                  // 4096 x 4096  (u | res)
    float* uc    = ws + 16777216;       // 4096 x 2048
    float* yb    = ws + 25165824;       // 4096 x 2048
    float* dlt   = ws + 33554432;       // 4096 x 2048
    float* xnorm = ws + 33554432;       // 4096 x 1024 (dead before dlt written)
    float* xdbl  = ws + 41943040;       // 4096 x 96
    float* Pch   = ws + 42336256;       // NB*CCH*DI*DS = 4,194,304
    float* Sch   = ws + 46530560;       // NB*CCH*DI*DS = 4,194,304

    const int R = NB * LSEQ;            // 4096 rows

    // 1. LayerNorm
    ln_kernel<<<R, 256, 0, stream>>>(x, ln_g, ln_b, xnorm);
    // 2. in_proj: xz = xnorm @ in_w^T            (4096 x 4096)
    gemm_nt<0><<<dim3((2*DI)/BN, R/BM), 256, 0, stream>>>(
        xnorm, NE, in_w, nullptr, nullptr, 0, xz, 2*DI, R, 2*DI, NE);
    // 3. causal depthwise conv + SiLU -> uc
    conv_silu_kernel<<<(R * DI) / 256, 256, 0, stream>>>(xz, conv_w, conv_b, uc);
    // 4. x_proj: xdbl = uc @ xproj_w^T           (4096 x 96)
    gemm_nt<0><<<dim3(1, R/BM), 256, 0, stream>>>(
        uc, DI, xproj_w, nullptr, nullptr, 0, xdbl, XDW, R, XDW, DI);
    // 5. dt_proj + softplus: dlt = softplus(xdbl[:, :64] @ dtproj_w^T + b)
    gemm_nt<1><<<dim3(DI/BN, R/BM), 256, 0, stream>>>(
        xdbl, XDW, dtproj_w, dtproj_b, nullptr, 0, dlt, DI, R, DI, DTR);
    // 6. chunk-parallel selective scan (gate fused into final pass) -> yb
    dim3 gScan(DI / 256, CCH, NB);      // 8 x 64 x 2 = 1024 blocks
    scan_chunk_kernel<false><<<gScan, 256, 0, stream>>>(
        dlt, uc, xdbl, A_log, Dvec, xz, Pch, Sch, yb);
    scan_combine_kernel<<<(NB * DI * DS) / 256, 256, 0, stream>>>(Pch, Sch);
    scan_chunk_kernel<true><<<gScan, 256, 0, stream>>>(
        dlt, uc, xdbl, A_log, Dvec, xz, Pch, Sch, yb);
    // 7. out_proj + residual: out = x + yb @ out_w^T
    gemm_nt<0><<<dim3(NE/BN, R/BM), 256, 0, stream>>>(
        yb, DI, out_w, nullptr, x, NE, out, NE, R, NE, DI);
}

// Round 3
// 539.868 us; speedup vs baseline: 5.4737x; 2.4238x over previous
//
#include <hip/hip_runtime.h>
#include <hip/hip_bf16.h>
#include <math.h>

// Problem constants
#define NE    1024   // n_embd
#define DI    2048   // d_inner
#define LSEQ  2048   // L
#define NB    2      // batch
#define DS    16     // d_state
#define DTR   64     // dt_rank
#define XDW   96     // dt_rank + 2*d_state

#define CCH   64           // number of time chunks for the scan
#define TCH   (LSEQ/CCH)   // 32 timesteps per chunk

#define SKX   8            // split-K factor for x_proj
#define XPROJ_PART (4096*96)

typedef __attribute__((ext_vector_type(8))) short short8;   // 8 x bf16 (4 VGPRs)
typedef __attribute__((ext_vector_type(4))) float floatx4;  // MFMA accumulator

__device__ __forceinline__ float softplusf(float x) {
    return (x > 20.f) ? x : log1pf(expf(x));
}
__device__ __forceinline__ float siluf(float x) {
    return x / (1.f + __expf(-x));
}

__device__ __forceinline__ void gld16(const void* g, void* l) {
    __builtin_amdgcn_global_load_lds(
        (const __attribute__((address_space(1))) unsigned int*)g,
        (__attribute__((address_space(3))) unsigned int*)l, 16, 0, 0);
}

// ---------------- fp32 -> bf16 convert (weights) ----------------
__global__ __launch_bounds__(256) void f2bf_kernel(
    const float* __restrict__ src, ushort4* __restrict__ dst)
{
    int i = blockIdx.x * 256 + threadIdx.x;
    float4 v = ((const float4*)src)[i];
    union { __hip_bfloat16 h[4]; ushort4 u; } cv;
    cv.h[0] = __float2bfloat16(v.x);
    cv.h[1] = __float2bfloat16(v.y);
    cv.h[2] = __float2bfloat16(v.z);
    cv.h[3] = __float2bfloat16(v.w);
    dst[i] = cv.u;
}

// ---------------- LayerNorm: one block per row, bf16 output ----------------
__global__ __launch_bounds__(256) void ln_kernel(
    const float* __restrict__ x, const float* __restrict__ g,
    const float* __restrict__ b, __hip_bfloat16* __restrict__ xn)
{
    int row = blockIdx.x;
    int tid = threadIdx.x;
    const float4* xr = (const float4*)(x + (size_t)row * NE);
    float4 v = xr[tid];                       // 256 threads * 4 = 1024
    float s  = v.x + v.y + v.z + v.w;
    float sq = v.x*v.x + v.y*v.y + v.z*v.z + v.w*v.w;
    #pragma unroll
    for (int off = 32; off > 0; off >>= 1) {  // wave64 reduce
        s  += __shfl_down(s, off);
        sq += __shfl_down(sq, off);
    }
    __shared__ float ss[4], ssq[4];
    __shared__ float smu, srstd;
    int wv = tid >> 6, lane = tid & 63;
    if (lane == 0) { ss[wv] = s; ssq[wv] = sq; }
    __syncthreads();
    if (tid == 0) {
        float a = ss[0] + ss[1] + ss[2] + ss[3];
        float q = ssq[0] + ssq[1] + ssq[2] + ssq[3];
        float mu  = a * (1.f / NE);
        float var = q * (1.f / NE) - mu * mu;   // biased var, matches jnp.var
        smu = mu; srstd = rsqrtf(var + 1e-5f);
    }
    __syncthreads();
    float mu = smu, rstd = srstd;
    float4 gv = ((const float4*)g)[tid];
    float4 bv = ((const float4*)b)[tid];
    union { __hip_bfloat16 h[4]; ushort4 u; } cv;
    cv.h[0] = __float2bfloat16((v.x - mu) * rstd * gv.x + bv.x);
    cv.h[1] = __float2bfloat16((v.y - mu) * rstd * gv.y + bv.y);
    cv.h[2] = __float2bfloat16((v.z - mu) * rstd * gv.z + bv.z);
    cv.h[3] = __float2bfloat16((v.w - mu) * rstd * gv.w + bv.w);
    ((ushort4*)xn)[row * 256 + tid] = cv.u;
}

// ---------------- bf16 MFMA GEMM: C = A @ W^T (+ resid), fp32 out ----------
// A: M x K bf16 (row-major), W: N x K bf16 (row-major), C: M x N fp32 (ldc=N).
// 128x128 tile, BK=32, 256 threads = 4 waves, each wave 64x64 (4x4 frags).
// m97 structure: global_load_lds width-16 staging, 2-barrier K-loop.
template<bool RESID>
__global__ __launch_bounds__(256) void gemm_bf16mm(
    const __hip_bfloat16* __restrict__ A,
    const __hip_bfloat16* __restrict__ W,
    const float* __restrict__ resid,
    float* __restrict__ C, int N, int K)
{
    __shared__ __hip_bfloat16 As[128 * 32];   // row-major, 64 B per row
    __shared__ __hip_bfloat16 Bs[128 * 32];
    int tid = threadIdx.x;
    int lane = tid & 63;
    int w = tid >> 6, wr = w >> 1, wc = w & 1;
    int row0 = blockIdx.y * 128, col0 = blockIdx.x * 128;

    // Staging: thread tid covers LDS bytes tid*16 (+4096 for rows 64..127).
    // LDS row r (64 B) = global tile row r, k-slice of 32 bf16.
    const __hip_bfloat16* ag = A + (size_t)(row0 + (tid >> 2)) * K + (tid & 3) * 8;
    const __hip_bfloat16* bg = W + (size_t)(col0 + (tid >> 2)) * K + (tid & 3) * 8;
    char* la_st = (char*)As + w * 1024;       // wave-uniform base + lane*16
    char* lb_st = (char*)Bs + w * 1024;
    const size_t rowskip = (size_t)64 * K;

    floatx4 acc[4][4];
    #pragma unroll
    for (int i = 0; i < 4; ++i)
        #pragma unroll
        for (int j = 0; j < 4; ++j) acc[i][j] = (floatx4){0.f, 0.f, 0.f, 0.f};

    // A-frag: A[m = lane&15][k = (lane>>4)*8 + 0..7]; same for B (NT layout).
    const char* la = (const char*)As + (wr * 64 + (lane & 15)) * 64 + (lane >> 4) * 16;
    const char* lb = (const char*)Bs + (wc * 64 + (lane & 15)) * 64 + (lane >> 4) * 16;

    for (int k0 = 0; k0 < K; k0 += 32) {
        gld16(ag,           la_st);
        gld16(ag + rowskip, la_st + 4096);
        gld16(bg,           lb_st);
        gld16(bg + rowskip, lb_st + 4096);
        ag += 32; bg += 32;
        __syncthreads();                       // drain staging (vmcnt before barrier)
        short8 af[4], bf[4];
        #pragma unroll
        for (int i = 0; i < 4; ++i) {
            af[i] = *(const short8*)(la + i * 1024);   // +16 tile rows
            bf[i] = *(const short8*)(lb + i * 1024);
        }
        #pragma unroll
        for (int i = 0; i < 4; ++i)
            #pragma unroll
            for (int j = 0; j < 4; ++j)
                acc[i][j] = __builtin_amdgcn_mfma_f32_16x16x32_bf16(
                    af[i], bf[j], acc[i][j], 0, 0, 0);
        __syncthreads();                       // reads done before next stage
    }

    // C/D layout: col = lane&15 (n), row = (lane>>4)*4 + reg (m)
    int crow = row0 + wr * 64 + (lane >> 4) * 4;
    int ccol = col0 + wc * 64 + (lane & 15);
    #pragma unroll
    for (int i = 0; i < 4; ++i)
        #pragma unroll
        for (int j = 0; j < 4; ++j)
            #pragma unroll
            for (int r = 0; r < 4; ++r) {
                size_t rr = (size_t)(crow + i * 16 + r);
                int cc = ccol + j * 16;
                float v = acc[i][j][r];
                if (RESID) v += resid[rr * N + cc];
                C[rr * N + cc] = v;
            }
}

// ---------------- Generic tiled fp32 GEMM (split-K capable) ----------------
// C = act(A * W^T + bias); blockIdx.z = k-chunk: A += z*K, C += z*M*ldc.
#define BM 128
#define BN 128
#define BK 8

template<int ACT>  // 0 = none, 1 = softplus
__global__ __launch_bounds__(256) void gemm_nt(
    const float* __restrict__ A, int lda,
    const float* __restrict__ W,
    const float* __restrict__ bias,
    float* __restrict__ C, int ldc,
    int M, int N, int K)
{
    int kz = blockIdx.z;
    A += (size_t)kz * K;                       // K = chunk length (cols within row)
    W += (size_t)kz * K;
    C += (size_t)kz * (size_t)M * ldc;         // per-chunk partial buffer
    __shared__ float As[BK][BM];
    __shared__ float Ws[BK][BN];
    int tid = threadIdx.x;
    int tx = tid & 15, ty = tid >> 4;          // 16x16 thread grid
    int row0 = blockIdx.y * BM, col0 = blockIdx.x * BN;
    int lr = tid >> 1;                         // 0..127 tile row
    int lk = (tid & 1) * 4;                    // 0 or 4
    float acc[8][8];
    #pragma unroll
    for (int i = 0; i < 8; ++i)
        #pragma unroll
        for (int j = 0; j < 8; ++j) acc[i][j] = 0.f;

    for (int k0 = 0; k0 < K; k0 += BK) {
        float4 av = *(const float4*)(A + (size_t)(row0 + lr) * lda + k0 + lk);
        int wrow = col0 + lr;
        float4 wv = make_float4(0.f, 0.f, 0.f, 0.f);
        if (wrow < N) wv = *(const float4*)(W + (size_t)wrow * K + k0 + lk);
        As[lk+0][lr] = av.x; As[lk+1][lr] = av.y; As[lk+2][lr] = av.z; As[lk+3][lr] = av.w;
        Ws[lk+0][lr] = wv.x; Ws[lk+1][lr] = wv.y; Ws[lk+2][lr] = wv.z; Ws[lk+3][lr] = wv.w;
        __syncthreads();
        #pragma unroll
        for (int kk = 0; kk < BK; ++kk) {
            float a[8], ww[8];
            #pragma unroll
            for (int i = 0; i < 8; ++i) a[i] = As[kk][ty*8 + i];
            #pragma unroll
            for (int j = 0; j < 8; ++j) ww[j] = Ws[kk][tx*8 + j];
            #pragma unroll
            for (int i = 0; i < 8; ++i)
                #pragma unroll
                for (int j = 0; j < 8; ++j)
                    acc[i][j] = fmaf(a[i], ww[j], acc[i][j]);
        }
        __syncthreads();
    }
    #pragma unroll
    for (int i = 0; i < 8; ++i) {
        size_t r = (size_t)(row0 + ty*8 + i);
        #pragma unroll
        for (int j = 0; j < 8; ++j) {
            int c = col0 + tx*8 + j;
            if (c < N) {
                float v = acc[i][j];
                if (bias)  v += bias[c];
                if (ACT == 1) v = softplusf(v);
                C[r * (size_t)ldc + c] = v;
            }
        }
    }
}

// W^T split-K note: gemm_nt shifts W by kz*K too (W rows are K-major) — correct
// because chunk kz needs W[n][kz*K .. kz*K+K), i.e. W + n*Kfull + kz*K; since the
// kernel indexes W[wrow*K + k] with K=chunk, we must pass W pre-strided. To keep
// it simple the x_proj launch passes Kfull via lda trick: see launch (we pass
// W with its true row stride by using K=chunk only for A; so instead we pass a
// W pointer already offset and index with ldw). -- handled by xproj_gemm below.

// Dedicated x_proj split-K kernel would duplicate gemm_nt; instead we use a
// small wrapper-compatible variant with separate W row stride:
template<int ACT>
__global__ __launch_bounds__(256) void gemm_nt_ldw(
    const float* __restrict__ A, int lda,
    const float* __restrict__ W, int ldw,
    float* __restrict__ C, int ldc,
    int M, int N, int K)
{
    int kz = blockIdx.z;
    A += (size_t)kz * K;
    W += (size_t)kz * K;
    C += (size_t)kz * (size_t)M * ldc;
    __shared__ float As[BK][BM];
    __shared__ float Ws[BK][BN];
    int tid = threadIdx.x;
    int tx = tid & 15, ty = tid >> 4;
    int row0 = blockIdx.y * BM, col0 = blockIdx.x * BN;
    int lr = tid >> 1;
    int lk = (tid & 1) * 4;
    float acc[8][8];
    #pragma unroll
    for (int i = 0; i < 8; ++i)
        #pragma unroll
        for (int j = 0; j < 8; ++j) acc[i][j] = 0.f;

    for (int k0 = 0; k0 < K; k0 += BK) {
        float4 av = *(const float4*)(A + (size_t)(row0 + lr) * lda + k0 + lk);
        int wrow = col0 + lr;
        float4 wv = make_float4(0.f, 0.f, 0.f, 0.f);
        if (wrow < N) wv = *(const float4*)(W + (size_t)wrow * ldw + k0 + lk);
        As[lk+0][lr] = av.x; As[lk+1][lr] = av.y; As[lk+2][lr] = av.z; As[lk+3][lr] = av.w;
        Ws[lk+0][lr] = wv.x; Ws[lk+1][lr] = wv.y; Ws[lk+2][lr] = wv.z; Ws[lk+3][lr] = wv.w;
        __syncthreads();
        #pragma unroll
        for (int kk = 0; kk < BK; ++kk) {
            float a[8], ww[8];
            #pragma unroll
            for (int i = 0; i < 8; ++i) a[i] = As[kk][ty*8 + i];
            #pragma unroll
            for (int j = 0; j < 8; ++j) ww[j] = Ws[kk][tx*8 + j];
            #pragma unroll
            for (int i = 0; i < 8; ++i)
                #pragma unroll
                for (int j = 0; j < 8; ++j)
                    acc[i][j] = fmaf(a[i], ww[j], acc[i][j]);
        }
        __syncthreads();
    }
    #pragma unroll
    for (int i = 0; i < 8; ++i) {
        size_t r = (size_t)(row0 + ty*8 + i);
        #pragma unroll
        for (int j = 0; j < 8; ++j) {
            int c = col0 + tx*8 + j;
            if (c < N)
                C[r * (size_t)ldc + c] = acc[i][j];
        }
    }
}

// Reduce the SKX partial buffers of x_proj into xdbl.
__global__ __launch_bounds__(256) void reduce8_kernel(
    const float* __restrict__ part, float* __restrict__ xdbl)
{
    int i = blockIdx.x * 256 + threadIdx.x;    // over 4096*96
    float s = 0.f;
    #pragma unroll
    for (int k = 0; k < SKX; ++k) s += part[(size_t)k * XPROJ_PART + i];
    xdbl[i] = s;
}

// ---------------- Causal depthwise conv (width 4) + SiLU ----------------
__global__ __launch_bounds__(256) void conv_silu_kernel(
    const float* __restrict__ xz, const float* __restrict__ cw,
    const float* __restrict__ cb, float* __restrict__ uc)
{
    size_t idx = (size_t)blockIdx.x * 256 + threadIdx.x;  // over NB*LSEQ*DI
    int d = (int)(idx & (DI - 1));
    size_t bt = idx >> 11;                                // row index b*L+t
    int t = (int)(bt & (LSEQ - 1));
    float4 w4 = *(const float4*)(cw + (size_t)d * 4);
    float wv[4] = {w4.x, w4.y, w4.z, w4.w};
    float acc = cb[d];
    #pragma unroll
    for (int k = 0; k < 4; ++k) {
        int tp = t - 3 + k;
        if (tp >= 0)
            acc = fmaf(wv[k], xz[((bt - (size_t)(3 - k)) << 12) + d], acc);
    }
    uc[idx] = siluf(acc);
}

// ---------------- Chunk-parallel selective scan ----------------
// Pass A (FINAL=false): per (b,d,chunk) P = prod dA, S = local scan from 0.
// Pass C (FINAL=true):  re-scan from H0 (in S), write bf16
//                       y = (sum_s h*C + u*D) * silu(res)  [gate fused].
template<bool FINAL>
__global__ __launch_bounds__(256) void scan_chunk_kernel(
    const float* __restrict__ dlt, const float* __restrict__ uc,
    const float* __restrict__ xdbl, const float* __restrict__ A_log,
    const float* __restrict__ Dp, const float* __restrict__ xz,
    float* __restrict__ P, float* __restrict__ S, void* __restrict__ y)
{
    __shared__ float sBC[TCH][32];     // [tt][0:16]=B, [16:32]=C
    int tid = threadIdx.x;
    int d = blockIdx.x * 256 + tid;
    int c = blockIdx.y;
    int b = blockIdx.z;
    int row0 = b * LSEQ + c * TCH;

    {   // stage B,C rows of this chunk
        int tt = tid >> 3, j4 = (tid & 7) * 4;
        const float4* src = (const float4*)(xdbl + (size_t)(row0 + tt) * XDW + DTR + j4);
        *(float4*)(&sBC[tt][j4]) = *src;
    }
    __syncthreads();

    float Ac[DS], h[DS], p[DS];
    #pragma unroll
    for (int s = 0; s < DS; ++s) {
        Ac[s] = -expf(A_log[(size_t)d * DS + s]);
        p[s] = 1.f;
    }
    size_t soff = (((size_t)b * CCH + c) * DI + d) * DS;
    if (FINAL) {
        #pragma unroll
        for (int s = 0; s < DS; ++s) h[s] = S[soff + s];   // H0 from pass B
    } else {
        #pragma unroll
        for (int s = 0; s < DS; ++s) h[s] = 0.f;
    }
    float Dd = Dp[d];
    size_t ix = (size_t)row0 * DI + d;
    for (int tt = 0; tt < TCH; ++tt) {
        float dv = dlt[ix];
        float ut = uc[ix];
        float du = dv * ut;
        float yacc = 0.f;
        #pragma unroll
        for (int s = 0; s < DS; ++s) {
            float e = __expf(dv * Ac[s]);
            h[s] = fmaf(e, h[s], du * sBC[tt][s]);
            if (FINAL) yacc = fmaf(h[s], sBC[tt][16 + s], yacc);
            else       p[s] *= e;
        }
        if (FINAL) {
            float res = xz[((size_t)(row0 + tt) << 12) + DI + d];
            ((__hip_bfloat16*)y)[ix] =
                __float2bfloat16(fmaf(ut, Dd, yacc) * siluf(res));
        }
        ix += DI;
    }
    if (!FINAL) {
        #pragma unroll
        for (int s = 0; s < DS; ++s) { P[soff + s] = p[s]; S[soff + s] = h[s]; }
    }
}

// Pass B: per (b,d,s), sequentially combine chunks; S[c] becomes H0 of chunk c.
__global__ __launch_bounds__(256) void scan_combine_kernel(
    const float* __restrict__ P, float* __restrict__ S)
{
    int idx = blockIdx.x * 256 + threadIdx.x;   // over NB*DI*DS = 65536
    int b = idx >> 15;                          // DI*DS = 32768
    int rest = idx & 32767;
    float h = 0.f;
    for (int c = 0; c < CCH; ++c) {
        size_t off = (((size_t)b * CCH + c) << 15) + rest;
        float tmp = S[off];
        float pv  = P[off];
        S[off] = h;                             // chunk-start state
        h = fmaf(pv, h, tmp);                   // chunk-end state
    }
}

extern "C" void kernel_launch(void* const* d_in, const int* in_sizes, int n_in,
                              void* d_out, int out_size, void* d_ws, size_t ws_size,
                              hipStream_t stream)
{
    const float* x        = (const float*)d_in[0];
    const float* ln_g     = (const float*)d_in[1];
    const float* ln_b     = (const float*)d_in[2];
    const float* in_w     = (const float*)d_in[3];   // (4096, 1024)
    const float* conv_w   = (const float*)d_in[4];   // (2048, 1, 4)
    const float* conv_b   = (const float*)d_in[5];
    const float* xproj_w  = (const float*)d_in[6];   // (96, 2048)
    const float* dtproj_w = (const float*)d_in[7];   // (2048, 64)
    const float* dtproj_b = (const float*)d_in[8];
    const float* A_log    = (const float*)d_in[9];   // (2048, 16)
    const float* Dvec     = (const float*)d_in[10];
    const float* out_w    = (const float*)d_in[11];  // (1024, 2048)
    float* out = (float*)d_out;

    // Workspace layout (float offsets). Total 51,773,440 floats = 207.1 MB.
    float* ws    = (float*)d_ws;
    float* xz    = ws;                        // 4096 x 4096 fp32 (u | res)
    float* uc    = ws + 16777216;             // 4096 x 2048 fp32
    float* dlt   = ws + 25165824;             // 4096 x 2048 fp32
    float* xdbl  = ws + 33554432;             // 4096 x 96 fp32
    float* xpart = ws + 33947648;             // SKX x 4096 x 96 (dead after reduce)
    float* Pch   = ws + 33947648;             // aliases xpart (used later)
    float* Sch   = ws + 38141952;             // NB*CCH*DI*DS
    __hip_bfloat16* xnorm_bf = (__hip_bfloat16*)(ws + 42336256);  // 4096 x 1024
    __hip_bfloat16* yb_bf    = (__hip_bfloat16*)(ws + 44433408);  // 4096 x 2048
    __hip_bfloat16* inw_bf   = (__hip_bfloat16*)(ws + 48627712);  // 4096 x 1024
    __hip_bfloat16* outw_bf  = (__hip_bfloat16*)(ws + 50724864);  // 1024 x 2048

    const int R = NB * LSEQ;                  // 4096 rows

    // 0. weight conversions fp32 -> bf16
    f2bf_kernel<<<(4096 * 1024 / 4) / 256, 256, 0, stream>>>(in_w,  (ushort4*)inw_bf);
    f2bf_kernel<<<(1024 * 2048 / 4) / 256, 256, 0, stream>>>(out_w, (ushort4*)outw_bf);
    // 1. LayerNorm -> bf16
    ln_kernel<<<R, 256, 0, stream>>>(x, ln_g, ln_b, xnorm_bf);
    // 2. in_proj (bf16 MFMA): xz = xnorm @ in_w^T      (4096 x 4096, K=1024)
    gemm_bf16mm<false><<<dim3((2*DI)/128, R/128), 256, 0, stream>>>(
        xnorm_bf, inw_bf, nullptr, xz, 2*DI, NE);
    // 3. causal depthwise conv + SiLU -> uc
    conv_silu_kernel<<<(R * DI) / 256, 256, 0, stream>>>(xz, conv_w, conv_b, uc);
    // 4. x_proj split-K: xpart[kz] = uc[:, kz*256:(kz+1)*256] @ xproj_w^T slice
    gemm_nt_ldw<0><<<dim3(1, R/BM, SKX), 256, 0, stream>>>(
        uc, DI, xproj_w, DI, xpart, XDW, R, XDW, DI / SKX);
    reduce8_kernel<<<(R * XDW) / 256, 256, 0, stream>>>(xpart, xdbl);
    // 5. dt_proj + softplus: dlt = softplus(xdbl[:, :64] @ dtproj_w^T + b)
    gemm_nt<1><<<dim3(DI/BN, R/BM), 256, 0, stream>>>(
        xdbl, XDW, dtproj_w, dtproj_b, dlt, DI, R, DI, DTR);
    // 6. chunk-parallel selective scan (gate fused, bf16 y) -> yb_bf
    dim3 gScan(DI / 256, CCH, NB);            // 8 x 64 x 2 = 1024 blocks
    scan_chunk_kernel<false><<<gScan, 256, 0, stream>>>(
        dlt, uc, xdbl, A_log, Dvec, xz, Pch, Sch, (void*)yb_bf);
    scan_combine_kernel<<<(NB * DI * DS) / 256, 256, 0, stream>>>(Pch, Sch);
    scan_chunk_kernel<true><<<gScan, 256, 0, stream>>>(
        dlt, uc, xdbl, A_log, Dvec, xz, Pch, Sch, (void*)yb_bf);
    // 7. out_proj (bf16 MFMA) + residual: out = x + yb @ out_w^T
    gemm_bf16mm<true><<<dim3(NE/128, R/128), 256, 0, stream>>>(
        yb_bf, outw_bf, x, out, NE, DI);
}

// Round 4
// 427.605 us; speedup vs baseline: 6.9108x; 1.2625x over previous
//
#include <hip/hip_runtime.h>
#include <hip/hip_bf16.h>
#include <math.h>

// Problem constants
#define NE    1024   // n_embd
#define DI    2048   // d_inner
#define LSEQ  2048   // L
#define NB    2      // batch
#define DS    16     // d_state
#define DTR   64     // dt_rank
#define XDW   96     // dt_rank + 2*d_state

#define CCH   64           // number of time chunks for the scan
#define TCH   (LSEQ/CCH)   // 32 timesteps per chunk

#define SKX   8            // split-K factor for x_proj
#define XPROJ_PART (4096*96)

typedef __attribute__((ext_vector_type(8))) short short8;   // 8 x bf16 (4 VGPRs)
typedef __attribute__((ext_vector_type(4))) float floatx4;  // MFMA accumulator

__device__ __forceinline__ float softplusf(float x) {
    return (x > 20.f) ? x : log1pf(expf(x));
}
__device__ __forceinline__ float siluf(float x) {
    return x / (1.f + __expf(-x));
}

__device__ __forceinline__ void gld16(const void* g, void* l) {
    __builtin_amdgcn_global_load_lds(
        (const __attribute__((address_space(1))) unsigned int*)g,
        (__attribute__((address_space(3))) unsigned int*)l, 16, 0, 0);
}

// ---------------- fp32 -> bf16 convert (weights) ----------------
__global__ __launch_bounds__(256) void f2bf_kernel(
    const float* __restrict__ src, ushort4* __restrict__ dst)
{
    int i = blockIdx.x * 256 + threadIdx.x;
    float4 v = ((const float4*)src)[i];
    union { __hip_bfloat16 h[4]; ushort4 u; } cv;
    cv.h[0] = __float2bfloat16(v.x);
    cv.h[1] = __float2bfloat16(v.y);
    cv.h[2] = __float2bfloat16(v.z);
    cv.h[3] = __float2bfloat16(v.w);
    dst[i] = cv.u;
}

// ---------------- LayerNorm: one block per row, bf16 output ----------------
__global__ __launch_bounds__(256) void ln_kernel(
    const float* __restrict__ x, const float* __restrict__ g,
    const float* __restrict__ b, __hip_bfloat16* __restrict__ xn)
{
    int row = blockIdx.x;
    int tid = threadIdx.x;
    const float4* xr = (const float4*)(x + (size_t)row * NE);
    float4 v = xr[tid];                       // 256 threads * 4 = 1024
    float s  = v.x + v.y + v.z + v.w;
    float sq = v.x*v.x + v.y*v.y + v.z*v.z + v.w*v.w;
    #pragma unroll
    for (int off = 32; off > 0; off >>= 1) {  // wave64 reduce
        s  += __shfl_down(s, off);
        sq += __shfl_down(sq, off);
    }
    __shared__ float ss[4], ssq[4];
    __shared__ float smu, srstd;
    int wv = tid >> 6, lane = tid & 63;
    if (lane == 0) { ss[wv] = s; ssq[wv] = sq; }
    __syncthreads();
    if (tid == 0) {
        float a = ss[0] + ss[1] + ss[2] + ss[3];
        float q = ssq[0] + ssq[1] + ssq[2] + ssq[3];
        float mu  = a * (1.f / NE);
        float var = q * (1.f / NE) - mu * mu;   // biased var, matches jnp.var
        smu = mu; srstd = rsqrtf(var + 1e-5f);
    }
    __syncthreads();
    float mu = smu, rstd = srstd;
    float4 gv = ((const float4*)g)[tid];
    float4 bv = ((const float4*)b)[tid];
    union { __hip_bfloat16 h[4]; ushort4 u; } cv;
    cv.h[0] = __float2bfloat16((v.x - mu) * rstd * gv.x + bv.x);
    cv.h[1] = __float2bfloat16((v.y - mu) * rstd * gv.y + bv.y);
    cv.h[2] = __float2bfloat16((v.z - mu) * rstd * gv.z + bv.z);
    cv.h[3] = __float2bfloat16((v.w - mu) * rstd * gv.w + bv.w);
    ((ushort4*)xn)[row * 256 + tid] = cv.u;
}

// ---------------- bf16 MFMA GEMM: C = A @ W^T (+ resid), fp32 out ----------
// A: M x K bf16 (row-major), W: N x K bf16 (row-major), C: M x N fp32 (ldc=N).
// 128x128 tile, BK=32, 256 threads = 4 waves, each wave 64x64 (4x4 frags).
template<bool RESID>
__global__ __launch_bounds__(256) void gemm_bf16mm(
    const __hip_bfloat16* __restrict__ A,
    const __hip_bfloat16* __restrict__ W,
    const float* __restrict__ resid,
    float* __restrict__ C, int N, int K)
{
    __shared__ __hip_bfloat16 As[128 * 32];   // row-major, 64 B per row
    __shared__ __hip_bfloat16 Bs[128 * 32];
    int tid = threadIdx.x;
    int lane = tid & 63;
    int w = tid >> 6, wr = w >> 1, wc = w & 1;
    int row0 = blockIdx.y * 128, col0 = blockIdx.x * 128;

    const __hip_bfloat16* ag = A + (size_t)(row0 + (tid >> 2)) * K + (tid & 3) * 8;
    const __hip_bfloat16* bg = W + (size_t)(col0 + (tid >> 2)) * K + (tid & 3) * 8;
    char* la_st = (char*)As + w * 1024;       // wave-uniform base + lane*16
    char* lb_st = (char*)Bs + w * 1024;
    const size_t rowskip = (size_t)64 * K;

    floatx4 acc[4][4];
    #pragma unroll
    for (int i = 0; i < 4; ++i)
        #pragma unroll
        for (int j = 0; j < 4; ++j) acc[i][j] = (floatx4){0.f, 0.f, 0.f, 0.f};

    const char* la = (const char*)As + (wr * 64 + (lane & 15)) * 64 + (lane >> 4) * 16;
    const char* lb = (const char*)Bs + (wc * 64 + (lane & 15)) * 64 + (lane >> 4) * 16;

    for (int k0 = 0; k0 < K; k0 += 32) {
        gld16(ag,           la_st);
        gld16(ag + rowskip, la_st + 4096);
        gld16(bg,           lb_st);
        gld16(bg + rowskip, lb_st + 4096);
        ag += 32; bg += 32;
        __syncthreads();
        short8 af[4], bf[4];
        #pragma unroll
        for (int i = 0; i < 4; ++i) {
            af[i] = *(const short8*)(la + i * 1024);
            bf[i] = *(const short8*)(lb + i * 1024);
        }
        #pragma unroll
        for (int i = 0; i < 4; ++i)
            #pragma unroll
            for (int j = 0; j < 4; ++j)
                acc[i][j] = __builtin_amdgcn_mfma_f32_16x16x32_bf16(
                    af[i], bf[j], acc[i][j], 0, 0, 0);
        __syncthreads();
    }

    // C/D layout: col = lane&15 (n), row = (lane>>4)*4 + reg (m)
    int crow = row0 + wr * 64 + (lane >> 4) * 4;
    int ccol = col0 + wc * 64 + (lane & 15);
    #pragma unroll
    for (int i = 0; i < 4; ++i)
        #pragma unroll
        for (int j = 0; j < 4; ++j)
            #pragma unroll
            for (int r = 0; r < 4; ++r) {
                size_t rr = (size_t)(crow + i * 16 + r);
                int cc = ccol + j * 16;
                float v = acc[i][j][r];
                if (RESID) v += resid[rr * N + cc];
                C[rr * N + cc] = v;
            }
}

// ---------------- dt_proj: small-K fp32 GEMM, K=64 staged once ----------------
// dlt[r, n] = softplus(xdbl[r, 0:64] . W[n, :] + bias[n]); 64x64 tile, 4x4/thread.
__global__ __launch_bounds__(256) void dtproj_kernel(
    const float* __restrict__ xdbl, const float* __restrict__ W,
    const float* __restrict__ bias, float* __restrict__ dlt)
{
    __shared__ float As[64 * 64];   // [k][m]
    __shared__ float Ws[64 * 64];   // [k][n]
    int tid = threadIdx.x;
    int col0 = blockIdx.x * 64, row0 = blockIdx.y * 64;
    #pragma unroll
    for (int it = 0; it < 4; ++it) {
        int li = it * 256 + tid;
        int m  = li & 63;           // lane-contiguous -> 2-way LDS banks (free)
        int kq = li >> 6;           // 0..15, wave-uniform
        float4 av = *(const float4*)(xdbl + (size_t)(row0 + m) * XDW + kq * 4);
        float4 wv = *(const float4*)(W + (size_t)(col0 + m) * DTR + kq * 4);
        As[(kq*4+0)*64 + m] = av.x; As[(kq*4+1)*64 + m] = av.y;
        As[(kq*4+2)*64 + m] = av.z; As[(kq*4+3)*64 + m] = av.w;
        Ws[(kq*4+0)*64 + m] = wv.x; Ws[(kq*4+1)*64 + m] = wv.y;
        Ws[(kq*4+2)*64 + m] = wv.z; Ws[(kq*4+3)*64 + m] = wv.w;
    }
    __syncthreads();
    int tx = tid & 15, ty = tid >> 4;
    float acc[4][4];
    #pragma unroll
    for (int i = 0; i < 4; ++i)
        #pragma unroll
        for (int j = 0; j < 4; ++j) acc[i][j] = 0.f;
    #pragma unroll 8
    for (int k = 0; k < DTR; ++k) {
        float4 a = *(const float4*)(As + k*64 + ty*4);  // broadcast within 16 lanes
        float4 w = *(const float4*)(Ws + k*64 + tx*4);  // 2-way banks (free)
        float av4[4] = {a.x, a.y, a.z, a.w};
        float wv4[4] = {w.x, w.y, w.z, w.w};
        #pragma unroll
        for (int i = 0; i < 4; ++i)
            #pragma unroll
            for (int j = 0; j < 4; ++j)
                acc[i][j] = fmaf(av4[i], wv4[j], acc[i][j]);
    }
    float4 bv = *(const float4*)(bias + col0 + tx*4);
    float b4[4] = {bv.x, bv.y, bv.z, bv.w};
    #pragma unroll
    for (int i = 0; i < 4; ++i) {
        float4 o;
        o.x = softplusf(acc[i][0] + b4[0]);
        o.y = softplusf(acc[i][1] + b4[1]);
        o.z = softplusf(acc[i][2] + b4[2]);
        o.w = softplusf(acc[i][3] + b4[3]);
        *(float4*)(dlt + (size_t)(row0 + ty*4 + i) * DI + col0 + tx*4) = o;
    }
}

// ---------------- fp32 split-K GEMM for x_proj (separate W row stride) -------
#define BM 128
#define BN 128
#define BK 8

__global__ __launch_bounds__(256) void gemm_nt_ldw(
    const float* __restrict__ A, int lda,
    const float* __restrict__ W, int ldw,
    float* __restrict__ C, int ldc,
    int M, int N, int K)
{
    int kz = blockIdx.z;
    A += (size_t)kz * K;
    W += (size_t)kz * K;
    C += (size_t)kz * (size_t)M * ldc;
    __shared__ float As[BK][BM];
    __shared__ float Ws[BK][BN];
    int tid = threadIdx.x;
    int tx = tid & 15, ty = tid >> 4;
    int row0 = blockIdx.y * BM, col0 = blockIdx.x * BN;
    int lr = tid >> 1;
    int lk = (tid & 1) * 4;
    float acc[8][8];
    #pragma unroll
    for (int i = 0; i < 8; ++i)
        #pragma unroll
        for (int j = 0; j < 8; ++j) acc[i][j] = 0.f;

    for (int k0 = 0; k0 < K; k0 += BK) {
        float4 av = *(const float4*)(A + (size_t)(row0 + lr) * lda + k0 + lk);
        int wrow = col0 + lr;
        float4 wv = make_float4(0.f, 0.f, 0.f, 0.f);
        if (wrow < N) wv = *(const float4*)(W + (size_t)wrow * ldw + k0 + lk);
        As[lk+0][lr] = av.x; As[lk+1][lr] = av.y; As[lk+2][lr] = av.z; As[lk+3][lr] = av.w;
        Ws[lk+0][lr] = wv.x; Ws[lk+1][lr] = wv.y; Ws[lk+2][lr] = wv.z; Ws[lk+3][lr] = wv.w;
        __syncthreads();
        #pragma unroll
        for (int kk = 0; kk < BK; ++kk) {
            float a[8], ww[8];
            #pragma unroll
            for (int i = 0; i < 8; ++i) a[i] = As[kk][ty*8 + i];
            #pragma unroll
            for (int j = 0; j < 8; ++j) ww[j] = Ws[kk][tx*8 + j];
            #pragma unroll
            for (int i = 0; i < 8; ++i)
                #pragma unroll
                for (int j = 0; j < 8; ++j)
                    acc[i][j] = fmaf(a[i], ww[j], acc[i][j]);
        }
        __syncthreads();
    }
    #pragma unroll
    for (int i = 0; i < 8; ++i) {
        size_t r = (size_t)(row0 + ty*8 + i);
        #pragma unroll
        for (int j = 0; j < 8; ++j) {
            int c = col0 + tx*8 + j;
            if (c < N)
                C[r * (size_t)ldc + c] = acc[i][j];
        }
    }
}

// Reduce the SKX partial buffers of x_proj into xdbl.
__global__ __launch_bounds__(256) void reduce8_kernel(
    const float* __restrict__ part, float* __restrict__ xdbl)
{
    int i = blockIdx.x * 256 + threadIdx.x;    // over 4096*96
    float s = 0.f;
    #pragma unroll
    for (int k = 0; k < SKX; ++k) s += part[(size_t)k * XPROJ_PART + i];
    xdbl[i] = s;
}

// ---------------- Causal depthwise conv (width 4) + SiLU, float4 ----------------
__global__ __launch_bounds__(256) void conv_silu_kernel(
    const float* __restrict__ xz, const float* __restrict__ cw,
    const float* __restrict__ cb, float* __restrict__ uc)
{
    int i4 = blockIdx.x * 256 + threadIdx.x;   // float4 index over NB*LSEQ*DI/4
    int d4 = i4 & 511;                          // DI/4 = 512
    int bt = i4 >> 9;
    int t  = bt & (LSEQ - 1);
    int d  = d4 * 4;
    float4 w0 = *(const float4*)(cw + (size_t)(d+0) * 4);
    float4 w1 = *(const float4*)(cw + (size_t)(d+1) * 4);
    float4 w2 = *(const float4*)(cw + (size_t)(d+2) * 4);
    float4 w3 = *(const float4*)(cw + (size_t)(d+3) * 4);
    const float* wt0 = (const float*)&w0;
    const float* wt1 = (const float*)&w1;
    const float* wt2 = (const float*)&w2;
    const float* wt3 = (const float*)&w3;
    float4 acc = *(const float4*)(cb + d);
    const float* base = xz + ((size_t)bt << 12) + d;   // u-half of row bt
    #pragma unroll
    for (int k = 0; k < 4; ++k) {
        int tp = t - 3 + k;
        if (tp >= 0) {
            float4 u = *(const float4*)(base - ((size_t)(3 - k) << 12));
            acc.x = fmaf(wt0[k], u.x, acc.x);
            acc.y = fmaf(wt1[k], u.y, acc.y);
            acc.z = fmaf(wt2[k], u.z, acc.z);
            acc.w = fmaf(wt3[k], u.w, acc.w);
        }
    }
    acc.x = siluf(acc.x); acc.y = siluf(acc.y);
    acc.z = siluf(acc.z); acc.w = siluf(acc.w);
    *(float4*)(uc + ((size_t)bt << 11) + d) = acc;
}

// ---------------- Chunk-parallel selective scan ----------------
template<bool FINAL>
__global__ __launch_bounds__(256) void scan_chunk_kernel(
    const float* __restrict__ dlt, const float* __restrict__ uc,
    const float* __restrict__ xdbl, const float* __restrict__ A_log,
    const float* __restrict__ Dp, const float* __restrict__ xz,
    float* __restrict__ P, float* __restrict__ S, void* __restrict__ y)
{
    __shared__ float sBC[TCH][32];     // [tt][0:16]=B, [16:32]=C
    int tid = threadIdx.x;
    int d = blockIdx.x * 256 + tid;
    int c = blockIdx.y;
    int b = blockIdx.z;
    int row0 = b * LSEQ + c * TCH;

    {   // stage B,C rows of this chunk
        int tt = tid >> 3, j4 = (tid & 7) * 4;
        const float4* src = (const float4*)(xdbl + (size_t)(row0 + tt) * XDW + DTR + j4);
        *(float4*)(&sBC[tt][j4]) = *src;
    }
    __syncthreads();

    float Ac[DS], h[DS], p[DS];
    #pragma unroll
    for (int s = 0; s < DS; ++s) {
        Ac[s] = -expf(A_log[(size_t)d * DS + s]);
        p[s] = 1.f;
    }
    size_t soff = (((size_t)b * CCH + c) * DI + d) * DS;
    if (FINAL) {
        #pragma unroll
        for (int s = 0; s < DS; ++s) h[s] = S[soff + s];   // H0 from pass B
    } else {
        #pragma unroll
        for (int s = 0; s < DS; ++s) h[s] = 0.f;
    }
    float Dd = Dp[d];
    size_t ix = (size_t)row0 * DI + d;
    for (int tt = 0; tt < TCH; ++tt) {
        float dv = dlt[ix];
        float ut = uc[ix];
        float du = dv * ut;
        float yacc = 0.f;
        #pragma unroll
        for (int s = 0; s < DS; ++s) {
            float e = __expf(dv * Ac[s]);
            h[s] = fmaf(e, h[s], du * sBC[tt][s]);
            if (FINAL) yacc = fmaf(h[s], sBC[tt][16 + s], yacc);
            else       p[s] *= e;
        }
        if (FINAL) {
            float res = xz[((size_t)(row0 + tt) << 12) + DI + d];
            ((__hip_bfloat16*)y)[ix] =
                __float2bfloat16(fmaf(ut, Dd, yacc) * siluf(res));
        }
        ix += DI;
    }
    if (!FINAL) {
        #pragma unroll
        for (int s = 0; s < DS; ++s) { P[soff + s] = p[s]; S[soff + s] = h[s]; }
    }
}

// Pass B: per (b,d,s), sequentially combine chunks; S[c] becomes H0 of chunk c.
__global__ __launch_bounds__(256) void scan_combine_kernel(
    const float* __restrict__ P, float* __restrict__ S)
{
    int idx = blockIdx.x * 256 + threadIdx.x;   // over NB*DI*DS = 65536
    int b = idx >> 15;                          // DI*DS = 32768
    int rest = idx & 32767;
    float h = 0.f;
    for (int c = 0; c < CCH; ++c) {
        size_t off = (((size_t)b * CCH + c) << 15) + rest;
        float tmp = S[off];
        float pv  = P[off];
        S[off] = h;                             // chunk-start state
        h = fmaf(pv, h, tmp);                   // chunk-end state
    }
}

extern "C" void kernel_launch(void* const* d_in, const int* in_sizes, int n_in,
                              void* d_out, int out_size, void* d_ws, size_t ws_size,
                              hipStream_t stream)
{
    const float* x        = (const float*)d_in[0];
    const float* ln_g     = (const float*)d_in[1];
    const float* ln_b     = (const float*)d_in[2];
    const float* in_w     = (const float*)d_in[3];   // (4096, 1024)
    const float* conv_w   = (const float*)d_in[4];   // (2048, 1, 4)
    const float* conv_b   = (const float*)d_in[5];
    const float* xproj_w  = (const float*)d_in[6];   // (96, 2048)
    const float* dtproj_w = (const float*)d_in[7];   // (2048, 64)
    const float* dtproj_b = (const float*)d_in[8];
    const float* A_log    = (const float*)d_in[9];   // (2048, 16)
    const float* Dvec     = (const float*)d_in[10];
    const float* out_w    = (const float*)d_in[11];  // (1024, 2048)
    float* out = (float*)d_out;

    // Workspace layout (float offsets). Total 51,773,440 floats = 207.1 MB.
    float* ws    = (float*)d_ws;
    float* xz    = ws;                        // 4096 x 4096 fp32 (u | res)
    float* uc    = ws + 16777216;             // 4096 x 2048 fp32
    float* dlt   = ws + 25165824;             // 4096 x 2048 fp32
    float* xdbl  = ws + 33554432;             // 4096 x 96 fp32
    float* xpart = ws + 33947648;             // SKX x 4096 x 96 (dead after reduce)
    float* Pch   = ws + 33947648;             // aliases xpart (used later)
    float* Sch   = ws + 38141952;             // NB*CCH*DI*DS
    __hip_bfloat16* xnorm_bf = (__hip_bfloat16*)(ws + 42336256);  // 4096 x 1024
    __hip_bfloat16* yb_bf    = (__hip_bfloat16*)(ws + 44433408);  // 4096 x 2048
    __hip_bfloat16* inw_bf   = (__hip_bfloat16*)(ws + 48627712);  // 4096 x 1024
    __hip_bfloat16* outw_bf  = (__hip_bfloat16*)(ws + 50724864);  // 1024 x 2048

    const int R = NB * LSEQ;                  // 4096 rows

    // 0. weight conversions fp32 -> bf16
    f2bf_kernel<<<(4096 * 1024 / 4) / 256, 256, 0, stream>>>(in_w,  (ushort4*)inw_bf);
    f2bf_kernel<<<(1024 * 2048 / 4) / 256, 256, 0, stream>>>(out_w, (ushort4*)outw_bf);
    // 1. LayerNorm -> bf16
    ln_kernel<<<R, 256, 0, stream>>>(x, ln_g, ln_b, xnorm_bf);
    // 2. in_proj (bf16 MFMA): xz = xnorm @ in_w^T      (4096 x 4096, K=1024)
    gemm_bf16mm<false><<<dim3((2*DI)/128, R/128), 256, 0, stream>>>(
        xnorm_bf, inw_bf, nullptr, xz, 2*DI, NE);
    // 3. causal depthwise conv + SiLU -> uc (float4 over d)
    conv_silu_kernel<<<(R * DI / 4) / 256, 256, 0, stream>>>(xz, conv_w, conv_b, uc);
    // 4. x_proj split-K: xpart[kz] = uc[:, kz*256:] @ xproj_w^T slice, then reduce
    gemm_nt_ldw<<<dim3(1, R/BM, SKX), 256, 0, stream>>>(
        uc, DI, xproj_w, DI, xpart, XDW, R, XDW, DI / SKX);
    reduce8_kernel<<<(R * XDW) / 256, 256, 0, stream>>>(xpart, xdbl);
    // 5. dt_proj + softplus (small-K kernel): dlt = softplus(xdbl[:,:64] @ W^T + b)
    dtproj_kernel<<<dim3(DI/64, R/64), 256, 0, stream>>>(
        xdbl, dtproj_w, dtproj_b, dlt);
    // 6. chunk-parallel selective scan (gate fused, bf16 y) -> yb_bf
    dim3 gScan(DI / 256, CCH, NB);            // 8 x 64 x 2 = 1024 blocks
    scan_chunk_kernel<false><<<gScan, 256, 0, stream>>>(
        dlt, uc, xdbl, A_log, Dvec, xz, Pch, Sch, (void*)yb_bf);
    scan_combine_kernel<<<(NB * DI * DS) / 256, 256, 0, stream>>>(Pch, Sch);
    scan_chunk_kernel<true><<<gScan, 256, 0, stream>>>(
        dlt, uc, xdbl, A_log, Dvec, xz, Pch, Sch, (void*)yb_bf);
    // 7. out_proj (bf16 MFMA) + residual: out = x + yb @ out_w^T
    gemm_bf16mm<true><<<dim3(NE/128, R/128), 256, 0, stream>>>(
        yb_bf, outw_bf, x, out, NE, DI);
}

// Round 5
// 397.157 us; speedup vs baseline: 7.4406x; 1.0767x over previous
//
#include <hip/hip_runtime.h>
#include <hip/hip_bf16.h>
#include <math.h>

// Problem constants
#define NE    1024   // n_embd
#define DI    2048   // d_inner
#define LSEQ  2048   // L
#define NB    2      // batch
#define DS    16     // d_state
#define DTR   64     // dt_rank
#define XDW   96     // dt_rank + 2*d_state

#define CCH   64           // number of time chunks for the scan
#define TCH   (LSEQ/CCH)   // 32 timesteps per chunk

#define SKX   8            // split-K factor for x_proj
#define XPROJ_PART (4096*96)

typedef __attribute__((ext_vector_type(8))) short short8;   // 8 x bf16 (4 VGPRs)
typedef __attribute__((ext_vector_type(4))) float floatx4;  // MFMA accumulator

__device__ __forceinline__ float softplusf(float x) {
    return (x > 20.f) ? x : log1pf(expf(x));
}
__device__ __forceinline__ float siluf(float x) {
    return x / (1.f + __expf(-x));
}

__device__ __forceinline__ void gld16(const void* g, void* l) {
    __builtin_amdgcn_global_load_lds(
        (const __attribute__((address_space(1))) unsigned int*)g,
        (__attribute__((address_space(3))) unsigned int*)l, 16, 0, 0);
}

// ---------------- fp32 -> bf16 convert (weights) ----------------
__global__ __launch_bounds__(256) void f2bf_kernel(
    const float* __restrict__ src, ushort4* __restrict__ dst)
{
    int i = blockIdx.x * 256 + threadIdx.x;
    float4 v = ((const float4*)src)[i];
    union { __hip_bfloat16 h[4]; ushort4 u; } cv;
    cv.h[0] = __float2bfloat16(v.x);
    cv.h[1] = __float2bfloat16(v.y);
    cv.h[2] = __float2bfloat16(v.z);
    cv.h[3] = __float2bfloat16(v.w);
    dst[i] = cv.u;
}

// ---------------- LayerNorm: one block per row, bf16 output ----------------
__global__ __launch_bounds__(256) void ln_kernel(
    const float* __restrict__ x, const float* __restrict__ g,
    const float* __restrict__ b, __hip_bfloat16* __restrict__ xn)
{
    int row = blockIdx.x;
    int tid = threadIdx.x;
    const float4* xr = (const float4*)(x + (size_t)row * NE);
    float4 v = xr[tid];                       // 256 threads * 4 = 1024
    float s  = v.x + v.y + v.z + v.w;
    float sq = v.x*v.x + v.y*v.y + v.z*v.z + v.w*v.w;
    #pragma unroll
    for (int off = 32; off > 0; off >>= 1) {  // wave64 reduce
        s  += __shfl_down(s, off);
        sq += __shfl_down(sq, off);
    }
    __shared__ float ss[4], ssq[4];
    __shared__ float smu, srstd;
    int wv = tid >> 6, lane = tid & 63;
    if (lane == 0) { ss[wv] = s; ssq[wv] = sq; }
    __syncthreads();
    if (tid == 0) {
        float a = ss[0] + ss[1] + ss[2] + ss[3];
        float q = ssq[0] + ssq[1] + ssq[2] + ssq[3];
        float mu  = a * (1.f / NE);
        float var = q * (1.f / NE) - mu * mu;   // biased var, matches jnp.var
        smu = mu; srstd = rsqrtf(var + 1e-5f);
    }
    __syncthreads();
    float mu = smu, rstd = srstd;
    float4 gv = ((const float4*)g)[tid];
    float4 bv = ((const float4*)b)[tid];
    union { __hip_bfloat16 h[4]; ushort4 u; } cv;
    cv.h[0] = __float2bfloat16((v.x - mu) * rstd * gv.x + bv.x);
    cv.h[1] = __float2bfloat16((v.y - mu) * rstd * gv.y + bv.y);
    cv.h[2] = __float2bfloat16((v.z - mu) * rstd * gv.z + bv.z);
    cv.h[3] = __float2bfloat16((v.w - mu) * rstd * gv.w + bv.w);
    ((ushort4*)xn)[row * 256 + tid] = cv.u;
}

// ---------------- bf16 MFMA GEMM: C = A @ W^T (+ resid), fp32 out ----------
// A: M x K bf16 (row-major), W: N x K bf16 (row-major), C: M x N fp32 (ldc=N).
// 128x128 tile, BK=32, 256 threads = 4 waves, each wave 64x64 (4x4 frags).
template<bool RESID>
__global__ __launch_bounds__(256) void gemm_bf16mm(
    const __hip_bfloat16* __restrict__ A,
    const __hip_bfloat16* __restrict__ W,
    const float* __restrict__ resid,
    float* __restrict__ C, int N, int K)
{
    __shared__ __hip_bfloat16 As[128 * 32];   // row-major, 64 B per row
    __shared__ __hip_bfloat16 Bs[128 * 32];
    int tid = threadIdx.x;
    int lane = tid & 63;
    int w = tid >> 6, wr = w >> 1, wc = w & 1;
    int row0 = blockIdx.y * 128, col0 = blockIdx.x * 128;

    const __hip_bfloat16* ag = A + (size_t)(row0 + (tid >> 2)) * K + (tid & 3) * 8;
    const __hip_bfloat16* bg = W + (size_t)(col0 + (tid >> 2)) * K + (tid & 3) * 8;
    char* la_st = (char*)As + w * 1024;       // wave-uniform base + lane*16
    char* lb_st = (char*)Bs + w * 1024;
    const size_t rowskip = (size_t)64 * K;

    floatx4 acc[4][4];
    #pragma unroll
    for (int i = 0; i < 4; ++i)
        #pragma unroll
        for (int j = 0; j < 4; ++j) acc[i][j] = (floatx4){0.f, 0.f, 0.f, 0.f};

    const char* la = (const char*)As + (wr * 64 + (lane & 15)) * 64 + (lane >> 4) * 16;
    const char* lb = (const char*)Bs + (wc * 64 + (lane & 15)) * 64 + (lane >> 4) * 16;

    for (int k0 = 0; k0 < K; k0 += 32) {
        gld16(ag,           la_st);
        gld16(ag + rowskip, la_st + 4096);
        gld16(bg,           lb_st);
        gld16(bg + rowskip, lb_st + 4096);
        ag += 32; bg += 32;
        __syncthreads();
        short8 af[4], bf[4];
        #pragma unroll
        for (int i = 0; i < 4; ++i) {
            af[i] = *(const short8*)(la + i * 1024);
            bf[i] = *(const short8*)(lb + i * 1024);
        }
        #pragma unroll
        for (int i = 0; i < 4; ++i)
            #pragma unroll
            for (int j = 0; j < 4; ++j)
                acc[i][j] = __builtin_amdgcn_mfma_f32_16x16x32_bf16(
                    af[i], bf[j], acc[i][j], 0, 0, 0);
        __syncthreads();
    }

    // C/D layout: col = lane&15 (n), row = (lane>>4)*4 + reg (m)
    int crow = row0 + wr * 64 + (lane >> 4) * 4;
    int ccol = col0 + wc * 64 + (lane & 15);
    #pragma unroll
    for (int i = 0; i < 4; ++i)
        #pragma unroll
        for (int j = 0; j < 4; ++j)
            #pragma unroll
            for (int r = 0; r < 4; ++r) {
                size_t rr = (size_t)(crow + i * 16 + r);
                int cc = ccol + j * 16;
                float v = acc[i][j][r];
                if (RESID) v += resid[rr * N + cc];
                C[rr * N + cc] = v;
            }
}

// ---------------- x_proj: bf16 MFMA, N=96, register-only (no LDS) ----------
// xpart[kz][r][n] = uc_bf[r, kz*256:(kz+1)*256] @ xpw_bf[n, same]^T
// Grid (R/128, SKX); 4 waves/block, wave w handles rows row0+w*32..+31, all 96 cols.
// Frags loaded straight from global: each lane's A/B fragment is 16 contiguous
// bytes of a K-contiguous row. W (384 KB) is L2-hot and reused by all row blocks.
__global__ __launch_bounds__(256) void xproj_kernel(
    const __hip_bfloat16* __restrict__ A,    // 4096 x 2048
    const __hip_bfloat16* __restrict__ W,    // 96 x 2048
    float* __restrict__ xpart)
{
    int tid = threadIdx.x;
    int lane = tid & 63;
    int w = tid >> 6;
    int kz = blockIdx.y;
    int row0 = blockIdx.x * 128 + w * 32;
    int m  = lane & 15;
    int kq = lane >> 4;                      // 0..3

    floatx4 acc[2][6];
    #pragma unroll
    for (int i = 0; i < 2; ++i)
        #pragma unroll
        for (int j = 0; j < 6; ++j) acc[i][j] = (floatx4){0.f, 0.f, 0.f, 0.f};

    const __hip_bfloat16* a0 = A + (size_t)(row0 + m) * DI + kz * (DI / SKX) + kq * 8;
    const __hip_bfloat16* b0 = W + (size_t)m * DI + kz * (DI / SKX) + kq * 8;

    #pragma unroll
    for (int ks = 0; ks < (DI / SKX) / 32; ++ks) {   // 8 steps of BK=32
        short8 af0 = *(const short8*)(a0);
        short8 af1 = *(const short8*)(a0 + (size_t)16 * DI);
        #pragma unroll
        for (int j = 0; j < 6; ++j) {
            short8 bf = *(const short8*)(b0 + (size_t)j * 16 * DI);
            acc[0][j] = __builtin_amdgcn_mfma_f32_16x16x32_bf16(af0, bf, acc[0][j], 0, 0, 0);
            acc[1][j] = __builtin_amdgcn_mfma_f32_16x16x32_bf16(af1, bf, acc[1][j], 0, 0, 0);
        }
        a0 += 32; b0 += 32;
    }

    float* cp = xpart + (size_t)kz * XPROJ_PART;
    int crow = row0 + kq * 4;
    #pragma unroll
    for (int i = 0; i < 2; ++i)
        #pragma unroll
        for (int j = 0; j < 6; ++j)
            #pragma unroll
            for (int r = 0; r < 4; ++r)
                cp[(size_t)(crow + i * 16 + r) * XDW + j * 16 + m] = acc[i][j][r];
}

// Reduce the SKX partial buffers of x_proj into xdbl.
__global__ __launch_bounds__(256) void reduce8_kernel(
    const float* __restrict__ part, float* __restrict__ xdbl)
{
    int i = blockIdx.x * 256 + threadIdx.x;    // over 4096*96
    float s = 0.f;
    #pragma unroll
    for (int k = 0; k < SKX; ++k) s += part[(size_t)k * XPROJ_PART + i];
    xdbl[i] = s;
}

// ---------------- dt_proj: small-K fp32 GEMM, K=64 staged once ----------------
__global__ __launch_bounds__(256) void dtproj_kernel(
    const float* __restrict__ xdbl, const float* __restrict__ W,
    const float* __restrict__ bias, float* __restrict__ dlt)
{
    __shared__ float As[64 * 64];   // [k][m]
    __shared__ float Ws[64 * 64];   // [k][n]
    int tid = threadIdx.x;
    int col0 = blockIdx.x * 64, row0 = blockIdx.y * 64;
    #pragma unroll
    for (int it = 0; it < 4; ++it) {
        int li = it * 256 + tid;
        int m  = li & 63;
        int kq = li >> 6;
        float4 av = *(const float4*)(xdbl + (size_t)(row0 + m) * XDW + kq * 4);
        float4 wv = *(const float4*)(W + (size_t)(col0 + m) * DTR + kq * 4);
        As[(kq*4+0)*64 + m] = av.x; As[(kq*4+1)*64 + m] = av.y;
        As[(kq*4+2)*64 + m] = av.z; As[(kq*4+3)*64 + m] = av.w;
        Ws[(kq*4+0)*64 + m] = wv.x; Ws[(kq*4+1)*64 + m] = wv.y;
        Ws[(kq*4+2)*64 + m] = wv.z; Ws[(kq*4+3)*64 + m] = wv.w;
    }
    __syncthreads();
    int tx = tid & 15, ty = tid >> 4;
    float acc[4][4];
    #pragma unroll
    for (int i = 0; i < 4; ++i)
        #pragma unroll
        for (int j = 0; j < 4; ++j) acc[i][j] = 0.f;
    #pragma unroll 8
    for (int k = 0; k < DTR; ++k) {
        float4 a = *(const float4*)(As + k*64 + ty*4);
        float4 w = *(const float4*)(Ws + k*64 + tx*4);
        float av4[4] = {a.x, a.y, a.z, a.w};
        float wv4[4] = {w.x, w.y, w.z, w.w};
        #pragma unroll
        for (int i = 0; i < 4; ++i)
            #pragma unroll
            for (int j = 0; j < 4; ++j)
                acc[i][j] = fmaf(av4[i], wv4[j], acc[i][j]);
    }
    float4 bv = *(const float4*)(bias + col0 + tx*4);
    float b4[4] = {bv.x, bv.y, bv.z, bv.w};
    #pragma unroll
    for (int i = 0; i < 4; ++i) {
        float4 o;
        o.x = softplusf(acc[i][0] + b4[0]);
        o.y = softplusf(acc[i][1] + b4[1]);
        o.z = softplusf(acc[i][2] + b4[2]);
        o.w = softplusf(acc[i][3] + b4[3]);
        *(float4*)(dlt + (size_t)(row0 + ty*4 + i) * DI + col0 + tx*4) = o;
    }
}

// ---------------- Causal depthwise conv (width 4) + SiLU, float4 ------------
// Writes fp32 uc (for scan) and bf16 uc_bf (for x_proj MFMA).
__global__ __launch_bounds__(256) void conv_silu_kernel(
    const float* __restrict__ xz, const float* __restrict__ cw,
    const float* __restrict__ cb, float* __restrict__ uc,
    ushort4* __restrict__ uc_bf)
{
    int i4 = blockIdx.x * 256 + threadIdx.x;   // float4 index over NB*LSEQ*DI/4
    int d4 = i4 & 511;                          // DI/4 = 512
    int bt = i4 >> 9;
    int t  = bt & (LSEQ - 1);
    int d  = d4 * 4;
    float4 w0 = *(const float4*)(cw + (size_t)(d+0) * 4);
    float4 w1 = *(const float4*)(cw + (size_t)(d+1) * 4);
    float4 w2 = *(const float4*)(cw + (size_t)(d+2) * 4);
    float4 w3 = *(const float4*)(cw + (size_t)(d+3) * 4);
    const float* wt0 = (const float*)&w0;
    const float* wt1 = (const float*)&w1;
    const float* wt2 = (const float*)&w2;
    const float* wt3 = (const float*)&w3;
    float4 acc = *(const float4*)(cb + d);
    const float* base = xz + ((size_t)bt << 12) + d;   // u-half of row bt
    #pragma unroll
    for (int k = 0; k < 4; ++k) {
        int tp = t - 3 + k;
        if (tp >= 0) {
            float4 u = *(const float4*)(base - ((size_t)(3 - k) << 12));
            acc.x = fmaf(wt0[k], u.x, acc.x);
            acc.y = fmaf(wt1[k], u.y, acc.y);
            acc.z = fmaf(wt2[k], u.z, acc.z);
            acc.w = fmaf(wt3[k], u.w, acc.w);
        }
    }
    acc.x = siluf(acc.x); acc.y = siluf(acc.y);
    acc.z = siluf(acc.z); acc.w = siluf(acc.w);
    *(float4*)(uc + ((size_t)bt << 11) + d) = acc;
    union { __hip_bfloat16 h[4]; ushort4 u; } cv;
    cv.h[0] = __float2bfloat16(acc.x);
    cv.h[1] = __float2bfloat16(acc.y);
    cv.h[2] = __float2bfloat16(acc.z);
    cv.h[3] = __float2bfloat16(acc.w);
    uc_bf[i4] = cv.u;
}

// ---------------- Chunk-parallel selective scan ----------------
template<bool FINAL>
__global__ __launch_bounds__(256) void scan_chunk_kernel(
    const float* __restrict__ dlt, const float* __restrict__ uc,
    const float* __restrict__ xdbl, const float* __restrict__ A_log,
    const float* __restrict__ Dp, const float* __restrict__ xz,
    float* __restrict__ P, float* __restrict__ S, void* __restrict__ y)
{
    __shared__ float sBC[TCH][32];     // [tt][0:16]=B, [16:32]=C
    int tid = threadIdx.x;
    int d = blockIdx.x * 256 + tid;
    int c = blockIdx.y;
    int b = blockIdx.z;
    int row0 = b * LSEQ + c * TCH;

    {   // stage B,C rows of this chunk
        int tt = tid >> 3, j4 = (tid & 7) * 4;
        const float4* src = (const float4*)(xdbl + (size_t)(row0 + tt) * XDW + DTR + j4);
        *(float4*)(&sBC[tt][j4]) = *src;
    }
    __syncthreads();

    float Ac[DS], h[DS], p[DS];
    #pragma unroll
    for (int s = 0; s < DS; ++s) {
        Ac[s] = -expf(A_log[(size_t)d * DS + s]);
        p[s] = 1.f;
    }
    size_t soff = (((size_t)b * CCH + c) * DI + d) * DS;
    if (FINAL) {
        #pragma unroll
        for (int s = 0; s < DS; ++s) h[s] = S[soff + s];   // H0 from pass B
    } else {
        #pragma unroll
        for (int s = 0; s < DS; ++s) h[s] = 0.f;
    }
    float Dd = Dp[d];
    size_t ix = (size_t)row0 * DI + d;
    for (int tt = 0; tt < TCH; ++tt) {
        float dv = dlt[ix];
        float ut = uc[ix];
        float du = dv * ut;
        float yacc = 0.f;
        #pragma unroll
        for (int s = 0; s < DS; ++s) {
            float e = __expf(dv * Ac[s]);
            h[s] = fmaf(e, h[s], du * sBC[tt][s]);
            if (FINAL) yacc = fmaf(h[s], sBC[tt][16 + s], yacc);
            else       p[s] *= e;
        }
        if (FINAL) {
            float res = xz[((size_t)(row0 + tt) << 12) + DI + d];
            ((__hip_bfloat16*)y)[ix] =
                __float2bfloat16(fmaf(ut, Dd, yacc) * siluf(res));
        }
        ix += DI;
    }
    if (!FINAL) {
        #pragma unroll
        for (int s = 0; s < DS; ++s) { P[soff + s] = p[s]; S[soff + s] = h[s]; }
    }
}

// Pass B: per (b,d,s), sequentially combine chunks; S[c] becomes H0 of chunk c.
__global__ __launch_bounds__(256) void scan_combine_kernel(
    const float* __restrict__ P, float* __restrict__ S)
{
    int idx = blockIdx.x * 256 + threadIdx.x;   // over NB*DI*DS = 65536
    int b = idx >> 15;                          // DI*DS = 32768
    int rest = idx & 32767;
    float h = 0.f;
    for (int c = 0; c < CCH; ++c) {
        size_t off = (((size_t)b * CCH + c) << 15) + rest;
        float tmp = S[off];
        float pv  = P[off];
        S[off] = h;                             // chunk-start state
        h = fmaf(pv, h, tmp);                   // chunk-end state
    }
}

extern "C" void kernel_launch(void* const* d_in, const int* in_sizes, int n_in,
                              void* d_out, int out_size, void* d_ws, size_t ws_size,
                              hipStream_t stream)
{
    const float* x        = (const float*)d_in[0];
    const float* ln_g     = (const float*)d_in[1];
    const float* ln_b     = (const float*)d_in[2];
    const float* in_w     = (const float*)d_in[3];   // (4096, 1024)
    const float* conv_w   = (const float*)d_in[4];   // (2048, 1, 4)
    const float* conv_b   = (const float*)d_in[5];
    const float* xproj_w  = (const float*)d_in[6];   // (96, 2048)
    const float* dtproj_w = (const float*)d_in[7];   // (2048, 64)
    const float* dtproj_b = (const float*)d_in[8];
    const float* A_log    = (const float*)d_in[9];   // (2048, 16)
    const float* Dvec     = (const float*)d_in[10];
    const float* out_w    = (const float*)d_in[11];  // (1024, 2048)
    float* out = (float*)d_out;

    // Workspace layout (float offsets). Total ~51.9M floats = 207.5 MB.
    float* ws    = (float*)d_ws;
    float* xz    = ws;                        // 4096 x 4096 fp32 (u | res)
    float* uc    = ws + 16777216;             // 4096 x 2048 fp32
    float* dlt   = ws + 25165824;             // 4096 x 2048 fp32
    float* xdbl  = ws + 33554432;             // 4096 x 96 fp32
    float* xpart = ws + 33947648;             // SKX x 4096 x 96 (dead after reduce)
    float* Pch   = ws + 33947648;             // aliases xpart (used later)
    float* Sch   = ws + 38141952;             // NB*CCH*DI*DS
    __hip_bfloat16* xnorm_bf = (__hip_bfloat16*)(ws + 42336256);  // 4096 x 1024
    // uc_bf aliases yb_bf: uc_bf dead after x_proj; yb_bf born at scan pass C.
    __hip_bfloat16* yb_bf    = (__hip_bfloat16*)(ws + 44433408);  // 4096 x 2048
    __hip_bfloat16* uc_bf    = (__hip_bfloat16*)(ws + 44433408);  // alias
    __hip_bfloat16* inw_bf   = (__hip_bfloat16*)(ws + 48627712);  // 4096 x 1024
    __hip_bfloat16* outw_bf  = (__hip_bfloat16*)(ws + 50724864);  // 1024 x 2048
    __hip_bfloat16* xpw_bf   = (__hip_bfloat16*)(ws + 51773440);  // 96 x 2048

    const int R = NB * LSEQ;                  // 4096 rows

    // 0. weight conversions fp32 -> bf16
    f2bf_kernel<<<(4096 * 1024 / 4) / 256, 256, 0, stream>>>(in_w,  (ushort4*)inw_bf);
    f2bf_kernel<<<(1024 * 2048 / 4) / 256, 256, 0, stream>>>(out_w, (ushort4*)outw_bf);
    f2bf_kernel<<<(96 * 2048 / 4) / 256, 256, 0, stream>>>(xproj_w, (ushort4*)xpw_bf);
    // 1. LayerNorm -> bf16
    ln_kernel<<<R, 256, 0, stream>>>(x, ln_g, ln_b, xnorm_bf);
    // 2. in_proj (bf16 MFMA): xz = xnorm @ in_w^T      (4096 x 4096, K=1024)
    gemm_bf16mm<false><<<dim3((2*DI)/128, R/128), 256, 0, stream>>>(
        xnorm_bf, inw_bf, nullptr, xz, 2*DI, NE);
    // 3. causal depthwise conv + SiLU -> uc (fp32) + uc_bf (bf16)
    conv_silu_kernel<<<(R * DI / 4) / 256, 256, 0, stream>>>(
        xz, conv_w, conv_b, uc, (ushort4*)uc_bf);
    // 4. x_proj (bf16 MFMA, register-only, split-K) + reduce
    xproj_kernel<<<dim3(R/128, SKX), 256, 0, stream>>>(uc_bf, xpw_bf, xpart);
    reduce8_kernel<<<(R * XDW) / 256, 256, 0, stream>>>(xpart, xdbl);
    // 5. dt_proj + softplus (small-K kernel): dlt = softplus(xdbl[:,:64] @ W^T + b)
    dtproj_kernel<<<dim3(DI/64, R/64), 256, 0, stream>>>(
        xdbl, dtproj_w, dtproj_b, dlt);
    // 6. chunk-parallel selective scan (gate fused, bf16 y) -> yb_bf
    dim3 gScan(DI / 256, CCH, NB);            // 8 x 64 x 2 = 1024 blocks
    scan_chunk_kernel<false><<<gScan, 256, 0, stream>>>(
        dlt, uc, xdbl, A_log, Dvec, xz, Pch, Sch, (void*)yb_bf);
    scan_combine_kernel<<<(NB * DI * DS) / 256, 256, 0, stream>>>(Pch, Sch);
    scan_chunk_kernel<true><<<gScan, 256, 0, stream>>>(
        dlt, uc, xdbl, A_log, Dvec, xz, Pch, Sch, (void*)yb_bf);
    // 7. out_proj (bf16 MFMA) + residual: out = x + yb @ out_w^T
    gemm_bf16mm<true><<<dim3(NE/128, R/128), 256, 0, stream>>>(
        yb_bf, outw_bf, x, out, NE, DI);
}

// Round 6
// 387.491 us; speedup vs baseline: 7.6262x; 1.0249x over previous
//
#include <hip/hip_runtime.h>
#include <hip/hip_bf16.h>
#include <math.h>

// Problem constants
#define NE    1024   // n_embd
#define DI    2048   // d_inner
#define LSEQ  2048   // L
#define NB    2      // batch
#define DS    16     // d_state
#define DTR   64     // dt_rank
#define XDW   96     // dt_rank + 2*d_state

#define CCH   64           // number of time chunks for the scan
#define TCH   (LSEQ/CCH)   // 32 timesteps per chunk

#define SKX   8            // split-K factor for x_proj
#define XPROJ_PART (4096*96)

typedef __attribute__((ext_vector_type(8))) short short8;   // 8 x bf16 (4 VGPRs)
typedef __attribute__((ext_vector_type(4))) float floatx4;  // MFMA accumulator

__device__ __forceinline__ float softplusf(float x) {
    return (x > 20.f) ? x : log1pf(expf(x));
}
__device__ __forceinline__ float siluf(float x) {
    return x / (1.f + __expf(-x));
}

__device__ __forceinline__ void gld16(const void* g, void* l) {
    __builtin_amdgcn_global_load_lds(
        (const __attribute__((address_space(1))) unsigned int*)g,
        (__attribute__((address_space(3))) unsigned int*)l, 16, 0, 0);
}

// ---------------- fp32 -> bf16 convert (weights) ----------------
__global__ __launch_bounds__(256) void f2bf_kernel(
    const float* __restrict__ src, ushort4* __restrict__ dst)
{
    int i = blockIdx.x * 256 + threadIdx.x;
    float4 v = ((const float4*)src)[i];
    union { __hip_bfloat16 h[4]; ushort4 u; } cv;
    cv.h[0] = __float2bfloat16(v.x);
    cv.h[1] = __float2bfloat16(v.y);
    cv.h[2] = __float2bfloat16(v.z);
    cv.h[3] = __float2bfloat16(v.w);
    dst[i] = cv.u;
}

// ---------------- LayerNorm: one block per row, bf16 output ----------------
__global__ __launch_bounds__(256) void ln_kernel(
    const float* __restrict__ x, const float* __restrict__ g,
    const float* __restrict__ b, __hip_bfloat16* __restrict__ xn)
{
    int row = blockIdx.x;
    int tid = threadIdx.x;
    const float4* xr = (const float4*)(x + (size_t)row * NE);
    float4 v = xr[tid];                       // 256 threads * 4 = 1024
    float s  = v.x + v.y + v.z + v.w;
    float sq = v.x*v.x + v.y*v.y + v.z*v.z + v.w*v.w;
    #pragma unroll
    for (int off = 32; off > 0; off >>= 1) {  // wave64 reduce
        s  += __shfl_down(s, off);
        sq += __shfl_down(sq, off);
    }
    __shared__ float ss[4], ssq[4];
    __shared__ float smu, srstd;
    int wv = tid >> 6, lane = tid & 63;
    if (lane == 0) { ss[wv] = s; ssq[wv] = sq; }
    __syncthreads();
    if (tid == 0) {
        float a = ss[0] + ss[1] + ss[2] + ss[3];
        float q = ssq[0] + ssq[1] + ssq[2] + ssq[3];
        float mu  = a * (1.f / NE);
        float var = q * (1.f / NE) - mu * mu;   // biased var, matches jnp.var
        smu = mu; srstd = rsqrtf(var + 1e-5f);
    }
    __syncthreads();
    float mu = smu, rstd = srstd;
    float4 gv = ((const float4*)g)[tid];
    float4 bv = ((const float4*)b)[tid];
    union { __hip_bfloat16 h[4]; ushort4 u; } cv;
    cv.h[0] = __float2bfloat16((v.x - mu) * rstd * gv.x + bv.x);
    cv.h[1] = __float2bfloat16((v.y - mu) * rstd * gv.y + bv.y);
    cv.h[2] = __float2bfloat16((v.z - mu) * rstd * gv.z + bv.z);
    cv.h[3] = __float2bfloat16((v.w - mu) * rstd * gv.w + bv.w);
    ((ushort4*)xn)[row * 256 + tid] = cv.u;
}

// ---------------- bf16 MFMA GEMM, 128x128 tile: C = A @ W^T ----------------
// A: M x K bf16, W: N x K bf16, C: M x N (bf16 if BF16OUT else fp32).
// BK=32, 256 threads = 4 waves, each wave 64x64 (4x4 frags). m97 structure.
template<bool BF16OUT>
__global__ __launch_bounds__(256) void gemm_bf16mm(
    const __hip_bfloat16* __restrict__ A,
    const __hip_bfloat16* __restrict__ W,
    void* __restrict__ Cv, int N, int K)
{
    __shared__ __hip_bfloat16 As[128 * 32];   // row-major, 64 B per row
    __shared__ __hip_bfloat16 Bs[128 * 32];
    int tid = threadIdx.x;
    int lane = tid & 63;
    int w = tid >> 6, wr = w >> 1, wc = w & 1;
    int row0 = blockIdx.y * 128, col0 = blockIdx.x * 128;

    const __hip_bfloat16* ag = A + (size_t)(row0 + (tid >> 2)) * K + (tid & 3) * 8;
    const __hip_bfloat16* bg = W + (size_t)(col0 + (tid >> 2)) * K + (tid & 3) * 8;
    char* la_st = (char*)As + w * 1024;       // wave-uniform base + lane*16
    char* lb_st = (char*)Bs + w * 1024;
    const size_t rowskip = (size_t)64 * K;

    floatx4 acc[4][4];
    #pragma unroll
    for (int i = 0; i < 4; ++i)
        #pragma unroll
        for (int j = 0; j < 4; ++j) acc[i][j] = (floatx4){0.f, 0.f, 0.f, 0.f};

    const char* la = (const char*)As + (wr * 64 + (lane & 15)) * 64 + (lane >> 4) * 16;
    const char* lb = (const char*)Bs + (wc * 64 + (lane & 15)) * 64 + (lane >> 4) * 16;

    for (int k0 = 0; k0 < K; k0 += 32) {
        gld16(ag,           la_st);
        gld16(ag + rowskip, la_st + 4096);
        gld16(bg,           lb_st);
        gld16(bg + rowskip, lb_st + 4096);
        ag += 32; bg += 32;
        __syncthreads();
        short8 af[4], bf[4];
        #pragma unroll
        for (int i = 0; i < 4; ++i) {
            af[i] = *(const short8*)(la + i * 1024);
            bf[i] = *(const short8*)(lb + i * 1024);
        }
        #pragma unroll
        for (int i = 0; i < 4; ++i)
            #pragma unroll
            for (int j = 0; j < 4; ++j)
                acc[i][j] = __builtin_amdgcn_mfma_f32_16x16x32_bf16(
                    af[i], bf[j], acc[i][j], 0, 0, 0);
        __syncthreads();
    }

    // C/D layout: col = lane&15 (n), row = (lane>>4)*4 + reg (m)
    int crow = row0 + wr * 64 + (lane >> 4) * 4;
    int ccol = col0 + wc * 64 + (lane & 15);
    #pragma unroll
    for (int i = 0; i < 4; ++i)
        #pragma unroll
        for (int j = 0; j < 4; ++j)
            #pragma unroll
            for (int r = 0; r < 4; ++r) {
                size_t rr = (size_t)(crow + i * 16 + r);
                int cc = ccol + j * 16;
                if (BF16OUT)
                    ((__hip_bfloat16*)Cv)[rr * N + cc] = __float2bfloat16(acc[i][j][r]);
                else
                    ((float*)Cv)[rr * N + cc] = acc[i][j][r];
            }
}

// ---------------- bf16 MFMA GEMM, 64x128 tile, fp32 out + resid ------------
// For out_proj (M=4096, N=1024, K=2048): grid (N/128, M/64) = 512 blocks.
// 4 waves: wave w covers all 64 rows x cols [w*32, w*32+32). 12 KB LDS.
__global__ __launch_bounds__(256) void gemm_bf16_n128(
    const __hip_bfloat16* __restrict__ A,
    const __hip_bfloat16* __restrict__ W,
    const float* __restrict__ resid,
    float* __restrict__ C, int N, int K)
{
    __shared__ __hip_bfloat16 As[64 * 32];    // 4 KB
    __shared__ __hip_bfloat16 Bs[128 * 32];   // 8 KB
    int tid = threadIdx.x;
    int lane = tid & 63;
    int w = tid >> 6;
    int row0 = blockIdx.y * 64, col0 = blockIdx.x * 128;

    const __hip_bfloat16* ag = A + (size_t)(row0 + (tid >> 2)) * K + (tid & 3) * 8;
    const __hip_bfloat16* bg = W + (size_t)(col0 + (tid >> 2)) * K + (tid & 3) * 8;
    char* la_st = (char*)As + w * 1024;
    char* lb_st = (char*)Bs + w * 1024;
    const size_t rowskip = (size_t)64 * K;

    floatx4 acc[4][2];
    #pragma unroll
    for (int i = 0; i < 4; ++i)
        #pragma unroll
        for (int j = 0; j < 2; ++j) acc[i][j] = (floatx4){0.f, 0.f, 0.f, 0.f};

    const char* la = (const char*)As + (lane & 15) * 64 + (lane >> 4) * 16;
    const char* lb = (const char*)Bs + (w * 32 + (lane & 15)) * 64 + (lane >> 4) * 16;

    for (int k0 = 0; k0 < K; k0 += 32) {
        gld16(ag,           la_st);           // A tile: 256 x 16 B = 4 KB
        gld16(bg,           lb_st);
        gld16(bg + rowskip, lb_st + 4096);
        ag += 32; bg += 32;
        __syncthreads();
        short8 af[4], bf[2];
        #pragma unroll
        for (int i = 0; i < 4; ++i) af[i] = *(const short8*)(la + i * 1024);
        #pragma unroll
        for (int j = 0; j < 2; ++j) bf[j] = *(const short8*)(lb + j * 1024);
        #pragma unroll
        for (int i = 0; i < 4; ++i)
            #pragma unroll
            for (int j = 0; j < 2; ++j)
                acc[i][j] = __builtin_amdgcn_mfma_f32_16x16x32_bf16(
                    af[i], bf[j], acc[i][j], 0, 0, 0);
        __syncthreads();
    }

    int crow = row0 + (lane >> 4) * 4;
    int ccol = col0 + w * 32 + (lane & 15);
    #pragma unroll
    for (int i = 0; i < 4; ++i)
        #pragma unroll
        for (int j = 0; j < 2; ++j)
            #pragma unroll
            for (int r = 0; r < 4; ++r) {
                size_t rr = (size_t)(crow + i * 16 + r);
                int cc = ccol + j * 16;
                C[rr * N + cc] = acc[i][j][r] + resid[rr * N + cc];
            }
}

// ---------------- x_proj: bf16 MFMA, N=96, register-only (no LDS) ----------
__global__ __launch_bounds__(256) void xproj_kernel(
    const __hip_bfloat16* __restrict__ A,    // 4096 x 2048
    const __hip_bfloat16* __restrict__ W,    // 96 x 2048
    float* __restrict__ xpart)
{
    int tid = threadIdx.x;
    int lane = tid & 63;
    int w = tid >> 6;
    int kz = blockIdx.y;
    int row0 = blockIdx.x * 128 + w * 32;
    int m  = lane & 15;
    int kq = lane >> 4;                      // 0..3

    floatx4 acc[2][6];
    #pragma unroll
    for (int i = 0; i < 2; ++i)
        #pragma unroll
        for (int j = 0; j < 6; ++j) acc[i][j] = (floatx4){0.f, 0.f, 0.f, 0.f};

    const __hip_bfloat16* a0 = A + (size_t)(row0 + m) * DI + kz * (DI / SKX) + kq * 8;
    const __hip_bfloat16* b0 = W + (size_t)m * DI + kz * (DI / SKX) + kq * 8;

    #pragma unroll
    for (int ks = 0; ks < (DI / SKX) / 32; ++ks) {   // 8 steps of BK=32
        short8 af0 = *(const short8*)(a0);
        short8 af1 = *(const short8*)(a0 + (size_t)16 * DI);
        #pragma unroll
        for (int j = 0; j < 6; ++j) {
            short8 bf = *(const short8*)(b0 + (size_t)j * 16 * DI);
            acc[0][j] = __builtin_amdgcn_mfma_f32_16x16x32_bf16(af0, bf, acc[0][j], 0, 0, 0);
            acc[1][j] = __builtin_amdgcn_mfma_f32_16x16x32_bf16(af1, bf, acc[1][j], 0, 0, 0);
        }
        a0 += 32; b0 += 32;
    }

    float* cp = xpart + (size_t)kz * XPROJ_PART;
    int crow = row0 + kq * 4;
    #pragma unroll
    for (int i = 0; i < 2; ++i)
        #pragma unroll
        for (int j = 0; j < 6; ++j)
            #pragma unroll
            for (int r = 0; r < 4; ++r)
                cp[(size_t)(crow + i * 16 + r) * XDW + j * 16 + m] = acc[i][j][r];
}

// Reduce the SKX partial buffers of x_proj into xdbl.
__global__ __launch_bounds__(256) void reduce8_kernel(
    const float* __restrict__ part, float* __restrict__ xdbl)
{
    int i = blockIdx.x * 256 + threadIdx.x;    // over 4096*96
    float s = 0.f;
    #pragma unroll
    for (int k = 0; k < SKX; ++k) s += part[(size_t)k * XPROJ_PART + i];
    xdbl[i] = s;
}

// ---------------- dt_proj: small-K fp32 GEMM, K=64 staged once ----------------
__global__ __launch_bounds__(256) void dtproj_kernel(
    const float* __restrict__ xdbl, const float* __restrict__ W,
    const float* __restrict__ bias, float* __restrict__ dlt)
{
    __shared__ float As[64 * 64];   // [k][m]
    __shared__ float Ws[64 * 64];   // [k][n]
    int tid = threadIdx.x;
    int col0 = blockIdx.x * 64, row0 = blockIdx.y * 64;
    #pragma unroll
    for (int it = 0; it < 4; ++it) {
        int li = it * 256 + tid;
        int m  = li & 63;
        int kq = li >> 6;
        float4 av = *(const float4*)(xdbl + (size_t)(row0 + m) * XDW + kq * 4);
        float4 wv = *(const float4*)(W + (size_t)(col0 + m) * DTR + kq * 4);
        As[(kq*4+0)*64 + m] = av.x; As[(kq*4+1)*64 + m] = av.y;
        As[(kq*4+2)*64 + m] = av.z; As[(kq*4+3)*64 + m] = av.w;
        Ws[(kq*4+0)*64 + m] = wv.x; Ws[(kq*4+1)*64 + m] = wv.y;
        Ws[(kq*4+2)*64 + m] = wv.z; Ws[(kq*4+3)*64 + m] = wv.w;
    }
    __syncthreads();
    int tx = tid & 15, ty = tid >> 4;
    float acc[4][4];
    #pragma unroll
    for (int i = 0; i < 4; ++i)
        #pragma unroll
        for (int j = 0; j < 4; ++j) acc[i][j] = 0.f;
    #pragma unroll 8
    for (int k = 0; k < DTR; ++k) {
        float4 a = *(const float4*)(As + k*64 + ty*4);
        float4 w = *(const float4*)(Ws + k*64 + tx*4);
        float av4[4] = {a.x, a.y, a.z, a.w};
        float wv4[4] = {w.x, w.y, w.z, w.w};
        #pragma unroll
        for (int i = 0; i < 4; ++i)
            #pragma unroll
            for (int j = 0; j < 4; ++j)
                acc[i][j] = fmaf(av4[i], wv4[j], acc[i][j]);
    }
    float4 bv = *(const float4*)(bias + col0 + tx*4);
    float b4[4] = {bv.x, bv.y, bv.z, bv.w};
    #pragma unroll
    for (int i = 0; i < 4; ++i) {
        float4 o;
        o.x = softplusf(acc[i][0] + b4[0]);
        o.y = softplusf(acc[i][1] + b4[1]);
        o.z = softplusf(acc[i][2] + b4[2]);
        o.w = softplusf(acc[i][3] + b4[3]);
        *(float4*)(dlt + (size_t)(row0 + ty*4 + i) * DI + col0 + tx*4) = o;
    }
}

// ---------------- Causal depthwise conv (width 4) + SiLU, bf16 in/out -------
__global__ __launch_bounds__(256) void conv_silu_kernel(
    const __hip_bfloat16* __restrict__ xz, const float* __restrict__ cw,
    const float* __restrict__ cb, ushort4* __restrict__ uc_bf)
{
    int i4 = blockIdx.x * 256 + threadIdx.x;   // 4-ch group over NB*LSEQ*DI/4
    int d4 = i4 & 511;                          // DI/4 = 512
    int bt = i4 >> 9;
    int t  = bt & (LSEQ - 1);
    int d  = d4 * 4;
    float4 w0 = *(const float4*)(cw + (size_t)(d+0) * 4);
    float4 w1 = *(const float4*)(cw + (size_t)(d+1) * 4);
    float4 w2 = *(const float4*)(cw + (size_t)(d+2) * 4);
    float4 w3 = *(const float4*)(cw + (size_t)(d+3) * 4);
    const float* wt0 = (const float*)&w0;
    const float* wt1 = (const float*)&w1;
    const float* wt2 = (const float*)&w2;
    const float* wt3 = (const float*)&w3;
    float4 acc = *(const float4*)(cb + d);
    const __hip_bfloat16* base = xz + ((size_t)bt << 12) + d;   // row stride 4096
    #pragma unroll
    for (int k = 0; k < 4; ++k) {
        int tp = t - 3 + k;
        if (tp >= 0) {
            union { ushort4 u; __hip_bfloat16 h[4]; } raw;
            raw.u = *(const ushort4*)(base - ((size_t)(3 - k) << 12));
            acc.x = fmaf(wt0[k], __bfloat162float(raw.h[0]), acc.x);
            acc.y = fmaf(wt1[k], __bfloat162float(raw.h[1]), acc.y);
            acc.z = fmaf(wt2[k], __bfloat162float(raw.h[2]), acc.z);
            acc.w = fmaf(wt3[k], __bfloat162float(raw.h[3]), acc.w);
        }
    }
    union { __hip_bfloat16 h[4]; ushort4 u; } cv;
    cv.h[0] = __float2bfloat16(siluf(acc.x));
    cv.h[1] = __float2bfloat16(siluf(acc.y));
    cv.h[2] = __float2bfloat16(siluf(acc.z));
    cv.h[3] = __float2bfloat16(siluf(acc.w));
    uc_bf[i4] = cv.u;
}

// ---------------- Chunk-parallel selective scan (bf16 u / res) --------------
template<bool FINAL>
__global__ __launch_bounds__(256) void scan_chunk_kernel(
    const float* __restrict__ dlt, const __hip_bfloat16* __restrict__ uc,
    const float* __restrict__ xdbl, const float* __restrict__ A_log,
    const float* __restrict__ Dp, const __hip_bfloat16* __restrict__ xz,
    float* __restrict__ P, float* __restrict__ S,
    __hip_bfloat16* __restrict__ y)
{
    __shared__ float sBC[TCH][32];     // [tt][0:16]=B, [16:32]=C
    int tid = threadIdx.x;
    int d = blockIdx.x * 256 + tid;
    int c = blockIdx.y;
    int b = blockIdx.z;
    int row0 = b * LSEQ + c * TCH;

    {   // stage B,C rows of this chunk
        int tt = tid >> 3, j4 = (tid & 7) * 4;
        const float4* src = (const float4*)(xdbl + (size_t)(row0 + tt) * XDW + DTR + j4);
        *(float4*)(&sBC[tt][j4]) = *src;
    }
    __syncthreads();

    float Ac[DS], h[DS], p[DS];
    #pragma unroll
    for (int s = 0; s < DS; ++s) {
        Ac[s] = -expf(A_log[(size_t)d * DS + s]);
        p[s] = 1.f;
    }
    size_t soff = (((size_t)b * CCH + c) * DI + d) * DS;
    if (FINAL) {
        #pragma unroll
        for (int s = 0; s < DS; ++s) h[s] = S[soff + s];   // H0 from pass B
    } else {
        #pragma unroll
        for (int s = 0; s < DS; ++s) h[s] = 0.f;
    }
    float Dd = Dp[d];
    size_t ix = (size_t)row0 * DI + d;
    for (int tt = 0; tt < TCH; ++tt) {
        float dv = dlt[ix];
        float ut = __bfloat162float(uc[ix]);
        float du = dv * ut;
        float yacc = 0.f;
        #pragma unroll
        for (int s = 0; s < DS; ++s) {
            float e = __expf(dv * Ac[s]);
            h[s] = fmaf(e, h[s], du * sBC[tt][s]);
            if (FINAL) yacc = fmaf(h[s], sBC[tt][16 + s], yacc);
            else       p[s] *= e;
        }
        if (FINAL) {
            float res = __bfloat162float(xz[((size_t)(row0 + tt) << 12) + DI + d]);
            y[ix] = __float2bfloat16(fmaf(ut, Dd, yacc) * siluf(res));
        }
        ix += DI;
    }
    if (!FINAL) {
        #pragma unroll
        for (int s = 0; s < DS; ++s) { P[soff + s] = p[s]; S[soff + s] = h[s]; }
    }
}

// Pass B: per (b,d,s), sequentially combine chunks; S[c] becomes H0 of chunk c.
__global__ __launch_bounds__(256) void scan_combine_kernel(
    const float* __restrict__ P, float* __restrict__ S)
{
    int idx = blockIdx.x * 256 + threadIdx.x;   // over NB*DI*DS = 65536
    int b = idx >> 15;                          // DI*DS = 32768
    int rest = idx & 32767;
    float h = 0.f;
    for (int c = 0; c < CCH; ++c) {
        size_t off = (((size_t)b * CCH + c) << 15) + rest;
        float tmp = S[off];
        float pv  = P[off];
        S[off] = h;                             // chunk-start state
        h = fmaf(pv, h, tmp);                   // chunk-end state
    }
}

extern "C" void kernel_launch(void* const* d_in, const int* in_sizes, int n_in,
                              void* d_out, int out_size, void* d_ws, size_t ws_size,
                              hipStream_t stream)
{
    const float* x        = (const float*)d_in[0];
    const float* ln_g     = (const float*)d_in[1];
    const float* ln_b     = (const float*)d_in[2];
    const float* in_w     = (const float*)d_in[3];   // (4096, 1024)
    const float* conv_w   = (const float*)d_in[4];   // (2048, 1, 4)
    const float* conv_b   = (const float*)d_in[5];
    const float* xproj_w  = (const float*)d_in[6];   // (96, 2048)
    const float* dtproj_w = (const float*)d_in[7];   // (2048, 64)
    const float* dtproj_b = (const float*)d_in[8];
    const float* A_log    = (const float*)d_in[9];   // (2048, 16)
    const float* Dvec     = (const float*)d_in[10];
    const float* out_w    = (const float*)d_in[11];  // (1024, 2048)
    float* out = (float*)d_out;

    // Workspace layout (byte offsets). Total 157,155,328 B = 157.2 MB.
    char* base = (char*)d_ws;
    __hip_bfloat16* xz_bf    = (__hip_bfloat16*)(base + 0);           // 4096x4096
    float*          dlt      = (float*)         (base + 33554432);    // 4096x2048
    __hip_bfloat16* uc_bf    = (__hip_bfloat16*)(base + 67108864);    // 4096x2048
    float*          xdbl     = (float*)         (base + 83886080);    // 4096x96
    float*          xpart    = (float*)         (base + 85458944);    // 8x4096x96
    float*          Pch      = (float*)         (base + 85458944);    // alias (16.8MB)
    float*          Sch      = (float*)         (base + 102236160);   // 2x64x2048x16
    __hip_bfloat16* xnorm_bf = (__hip_bfloat16*)(base + 119013376);   // 4096x1024
    __hip_bfloat16* yb_bf    = (__hip_bfloat16*)(base + 127401984);   // 4096x2048
    __hip_bfloat16* inw_bf   = (__hip_bfloat16*)(base + 144179200);   // 4096x1024
    __hip_bfloat16* outw_bf  = (__hip_bfloat16*)(base + 152567808);   // 1024x2048
    __hip_bfloat16* xpw_bf   = (__hip_bfloat16*)(base + 156762112);   // 96x2048

    const int R = NB * LSEQ;                  // 4096 rows

    // 0. weight conversions fp32 -> bf16
    f2bf_kernel<<<(4096 * 1024 / 4) / 256, 256, 0, stream>>>(in_w,  (ushort4*)inw_bf);
    f2bf_kernel<<<(1024 * 2048 / 4) / 256, 256, 0, stream>>>(out_w, (ushort4*)outw_bf);
    f2bf_kernel<<<(96 * 2048 / 4) / 256, 256, 0, stream>>>(xproj_w, (ushort4*)xpw_bf);
    // 1. LayerNorm -> bf16
    ln_kernel<<<R, 256, 0, stream>>>(x, ln_g, ln_b, xnorm_bf);
    // 2. in_proj (bf16 MFMA): xz = xnorm @ in_w^T   (4096 x 4096, K=1024), bf16 out
    gemm_bf16mm<true><<<dim3((2*DI)/128, R/128), 256, 0, stream>>>(
        xnorm_bf, inw_bf, (void*)xz_bf, 2*DI, NE);
    // 3. causal depthwise conv + SiLU -> uc_bf (bf16 in, bf16 out)
    conv_silu_kernel<<<(R * DI / 4) / 256, 256, 0, stream>>>(
        xz_bf, conv_w, conv_b, (ushort4*)uc_bf);
    // 4. x_proj (bf16 MFMA, register-only, split-K) + reduce
    xproj_kernel<<<dim3(R/128, SKX), 256, 0, stream>>>(uc_bf, xpw_bf, xpart);
    reduce8_kernel<<<(R * XDW) / 256, 256, 0, stream>>>(xpart, xdbl);
    // 5. dt_proj + softplus (small-K kernel): dlt = softplus(xdbl[:,:64] @ W^T + b)
    dtproj_kernel<<<dim3(DI/64, R/64), 256, 0, stream>>>(
        xdbl, dtproj_w, dtproj_b, dlt);
    // 6. chunk-parallel selective scan (gate fused, bf16 y) -> yb_bf
    dim3 gScan(DI / 256, CCH, NB);            // 8 x 64 x 2 = 1024 blocks
    scan_chunk_kernel<false><<<gScan, 256, 0, stream>>>(
        dlt, uc_bf, xdbl, A_log, Dvec, xz_bf, Pch, Sch, yb_bf);
    scan_combine_kernel<<<(NB * DI * DS) / 256, 256, 0, stream>>>(Pch, Sch);
    scan_chunk_kernel<true><<<gScan, 256, 0, stream>>>(
        dlt, uc_bf, xdbl, A_log, Dvec, xz_bf, Pch, Sch, yb_bf);
    // 7. out_proj (bf16 MFMA, 64x128 tile) + residual: out = x + yb @ out_w^T
    gemm_bf16_n128<<<dim3(NE/128, R/64), 256, 0, stream>>>(
        yb_bf, outw_bf, x, out, NE, DI);
}

// Round 7
// 378.200 us; speedup vs baseline: 7.8136x; 1.0246x over previous
//
#include <hip/hip_runtime.h>
#include <hip/hip_bf16.h>
#include <math.h>

// Problem constants
#define NE    1024   // n_embd
#define DI    2048   // d_inner
#define LSEQ  2048   // L
#define NB    2      // batch
#define DS    16     // d_state
#define DTR   64     // dt_rank
#define XDW   96     // dt_rank + 2*d_state

#define CCH   64           // number of time chunks for the scan
#define TCH   (LSEQ/CCH)   // 32 timesteps per chunk

#define SKX   8            // split-K factor for x_proj
#define XPROJ_PART (4096*96)

typedef __attribute__((ext_vector_type(8))) short short8;   // 8 x bf16 (4 VGPRs)
typedef __attribute__((ext_vector_type(4))) float floatx4;  // MFMA accumulator

__device__ __forceinline__ float softplusf(float x) {
    return (x > 20.f) ? x : log1pf(expf(x));
}
__device__ __forceinline__ float siluf(float x) {
    return x / (1.f + __expf(-x));
}

__device__ __forceinline__ void gld16(const void* g, void* l) {
    __builtin_amdgcn_global_load_lds(
        (const __attribute__((address_space(1))) unsigned int*)g,
        (__attribute__((address_space(3))) unsigned int*)l, 16, 0, 0);
}

// ---------------- fp32 -> bf16 convert: all three weights in one launch -----
#define F2BF_N1 (4096*1024/4)          // in_w groups
#define F2BF_N2 (2048*1024/4)          // out_w groups
#define F2BF_N3 (96*2048/4)            // xproj_w groups
__global__ __launch_bounds__(256) void f2bf3_kernel(
    const float* __restrict__ s1, ushort4* __restrict__ d1,
    const float* __restrict__ s2, ushort4* __restrict__ d2,
    const float* __restrict__ s3, ushort4* __restrict__ d3)
{
    int i = blockIdx.x * 256 + threadIdx.x;
    const float* src; ushort4* dst; int j;
    if (i < F2BF_N1)                 { src = s1; dst = d1; j = i; }
    else if (i < F2BF_N1 + F2BF_N2)  { src = s2; dst = d2; j = i - F2BF_N1; }
    else                             { src = s3; dst = d3; j = i - F2BF_N1 - F2BF_N2; }
    float4 v = ((const float4*)src)[j];
    union { __hip_bfloat16 h[4]; ushort4 u; } cv;
    cv.h[0] = __float2bfloat16(v.x);
    cv.h[1] = __float2bfloat16(v.y);
    cv.h[2] = __float2bfloat16(v.z);
    cv.h[3] = __float2bfloat16(v.w);
    dst[j] = cv.u;
}

// ---------------- LayerNorm: one block per row, bf16 output ----------------
__global__ __launch_bounds__(256) void ln_kernel(
    const float* __restrict__ x, const float* __restrict__ g,
    const float* __restrict__ b, __hip_bfloat16* __restrict__ xn)
{
    int row = blockIdx.x;
    int tid = threadIdx.x;
    const float4* xr = (const float4*)(x + (size_t)row * NE);
    float4 v = xr[tid];                       // 256 threads * 4 = 1024
    float s  = v.x + v.y + v.z + v.w;
    float sq = v.x*v.x + v.y*v.y + v.z*v.z + v.w*v.w;
    #pragma unroll
    for (int off = 32; off > 0; off >>= 1) {  // wave64 reduce
        s  += __shfl_down(s, off);
        sq += __shfl_down(sq, off);
    }
    __shared__ float ss[4], ssq[4];
    __shared__ float smu, srstd;
    int wv = tid >> 6, lane = tid & 63;
    if (lane == 0) { ss[wv] = s; ssq[wv] = sq; }
    __syncthreads();
    if (tid == 0) {
        float a = ss[0] + ss[1] + ss[2] + ss[3];
        float q = ssq[0] + ssq[1] + ssq[2] + ssq[3];
        float mu  = a * (1.f / NE);
        float var = q * (1.f / NE) - mu * mu;   // biased var, matches jnp.var
        smu = mu; srstd = rsqrtf(var + 1e-5f);
    }
    __syncthreads();
    float mu = smu, rstd = srstd;
    float4 gv = ((const float4*)g)[tid];
    float4 bv = ((const float4*)b)[tid];
    union { __hip_bfloat16 h[4]; ushort4 u; } cv;
    cv.h[0] = __float2bfloat16((v.x - mu) * rstd * gv.x + bv.x);
    cv.h[1] = __float2bfloat16((v.y - mu) * rstd * gv.y + bv.y);
    cv.h[2] = __float2bfloat16((v.z - mu) * rstd * gv.z + bv.z);
    cv.h[3] = __float2bfloat16((v.w - mu) * rstd * gv.w + bv.w);
    ((ushort4*)xn)[row * 256 + tid] = cv.u;
}

// ---------------- bf16 MFMA GEMM, 128x128 tile, XOR-swizzled LDS -----------
// A: M x K bf16, W: N x K bf16, C: M x N (bf16 if BF16OUT else fp32).
// LDS 16-B slot c of row r holds global k-slot c ^ ((r>>1)&3)  -> 2-way banks.
template<bool BF16OUT>
__global__ __launch_bounds__(256) void gemm_bf16mm(
    const __hip_bfloat16* __restrict__ A,
    const __hip_bfloat16* __restrict__ W,
    void* __restrict__ Cv, int N, int K)
{
    __shared__ __hip_bfloat16 As[128 * 32];   // row-major, 64 B per row
    __shared__ __hip_bfloat16 Bs[128 * 32];
    int tid = threadIdx.x;
    int lane = tid & 63;
    int w = tid >> 6, wr = w >> 1, wc = w & 1;
    int row0 = blockIdx.y * 128, col0 = blockIdx.x * 128;

    // Staging: LDS row r = tid>>2, slot c = tid&3; source k-slot gc = c^((r>>1)&3).
    // Rows r and r+64 share (r>>1)&3 (since 32&3==0), so one pointer serves both.
    {
        int r = tid >> 2, c = tid & 3;
        int gc = c ^ ((r >> 1) & 3);
        const __hip_bfloat16* ag = A + (size_t)(row0 + r) * K + gc * 8;
        const __hip_bfloat16* bg = W + (size_t)(col0 + r) * K + gc * 8;
        char* la_st = (char*)As + w * 1024;   // wave-uniform base + lane*16
        char* lb_st = (char*)Bs + w * 1024;
        const size_t rowskip = (size_t)64 * K;

        floatx4 acc[4][4];
        #pragma unroll
        for (int i = 0; i < 4; ++i)
            #pragma unroll
            for (int j = 0; j < 4; ++j) acc[i][j] = (floatx4){0.f, 0.f, 0.f, 0.f};

        // Fragment read: row m (lane&15), slot cs = kq ^ ((m>>1)&3); invariant
        // under +16/+64 row offsets, so cs is a per-lane constant.
        int m = lane & 15, kq = lane >> 4;
        int cs = kq ^ ((m >> 1) & 3);
        const char* la = (const char*)As + (wr * 64 + m) * 64 + cs * 16;
        const char* lb = (const char*)Bs + (wc * 64 + m) * 64 + cs * 16;

        for (int k0 = 0; k0 < K; k0 += 32) {
            gld16(ag,           la_st);
            gld16(ag + rowskip, la_st + 4096);
            gld16(bg,           lb_st);
            gld16(bg + rowskip, lb_st + 4096);
            ag += 32; bg += 32;
            __syncthreads();
            short8 af[4], bf[4];
            #pragma unroll
            for (int i = 0; i < 4; ++i) {
                af[i] = *(const short8*)(la + i * 1024);
                bf[i] = *(const short8*)(lb + i * 1024);
            }
            #pragma unroll
            for (int i = 0; i < 4; ++i)
                #pragma unroll
                for (int j = 0; j < 4; ++j)
                    acc[i][j] = __builtin_amdgcn_mfma_f32_16x16x32_bf16(
                        af[i], bf[j], acc[i][j], 0, 0, 0);
            __syncthreads();
        }

        // C/D layout: col = lane&15 (n), row = (lane>>4)*4 + reg (m)
        int crow = row0 + wr * 64 + kq * 4;
        int ccol = col0 + wc * 64 + m;
        #pragma unroll
        for (int i = 0; i < 4; ++i)
            #pragma unroll
            for (int j = 0; j < 4; ++j)
                #pragma unroll
                for (int r2 = 0; r2 < 4; ++r2) {
                    size_t rr = (size_t)(crow + i * 16 + r2);
                    int cc = ccol + j * 16;
                    if (BF16OUT)
                        ((__hip_bfloat16*)Cv)[rr * N + cc] = __float2bfloat16(acc[i][j][r2]);
                    else
                        ((float*)Cv)[rr * N + cc] = acc[i][j][r2];
                }
    }
}

// ---------------- bf16 MFMA GEMM, 64x128 tile, swizzled, fp32 out + resid ---
__global__ __launch_bounds__(256) void gemm_bf16_n128(
    const __hip_bfloat16* __restrict__ A,
    const __hip_bfloat16* __restrict__ W,
    const float* __restrict__ resid,
    float* __restrict__ C, int N, int K)
{
    __shared__ __hip_bfloat16 As[64 * 32];    // 4 KB
    __shared__ __hip_bfloat16 Bs[128 * 32];   // 8 KB
    int tid = threadIdx.x;
    int lane = tid & 63;
    int w = tid >> 6;
    int row0 = blockIdx.y * 64, col0 = blockIdx.x * 128;

    int r = tid >> 2, c = tid & 3;
    int gc = c ^ ((r >> 1) & 3);
    const __hip_bfloat16* ag = A + (size_t)(row0 + r) * K + gc * 8;
    const __hip_bfloat16* bg = W + (size_t)(col0 + r) * K + gc * 8;
    char* la_st = (char*)As + w * 1024;
    char* lb_st = (char*)Bs + w * 1024;
    const size_t rowskip = (size_t)64 * K;

    floatx4 acc[4][2];
    #pragma unroll
    for (int i = 0; i < 4; ++i)
        #pragma unroll
        for (int j = 0; j < 2; ++j) acc[i][j] = (floatx4){0.f, 0.f, 0.f, 0.f};

    int m = lane & 15, kq = lane >> 4;
    int cs = kq ^ ((m >> 1) & 3);
    const char* la = (const char*)As + m * 64 + cs * 16;
    const char* lb = (const char*)Bs + (w * 32 + m) * 64 + cs * 16;

    for (int k0 = 0; k0 < K; k0 += 32) {
        gld16(ag,           la_st);           // A tile: 64 rows = 4 KB, one shot
        gld16(bg,           lb_st);
        gld16(bg + rowskip, lb_st + 4096);
        ag += 32; bg += 32;
        __syncthreads();
        short8 af[4], bf[2];
        #pragma unroll
        for (int i = 0; i < 4; ++i) af[i] = *(const short8*)(la + i * 1024);
        #pragma unroll
        for (int j = 0; j < 2; ++j) bf[j] = *(const short8*)(lb + j * 1024);
        #pragma unroll
        for (int i = 0; i < 4; ++i)
            #pragma unroll
            for (int j = 0; j < 2; ++j)
                acc[i][j] = __builtin_amdgcn_mfma_f32_16x16x32_bf16(
                    af[i], bf[j], acc[i][j], 0, 0, 0);
        __syncthreads();
    }

    int crow = row0 + kq * 4;
    int ccol = col0 + w * 32 + m;
    #pragma unroll
    for (int i = 0; i < 4; ++i)
        #pragma unroll
        for (int j = 0; j < 2; ++j)
            #pragma unroll
            for (int r2 = 0; r2 < 4; ++r2) {
                size_t rr = (size_t)(crow + i * 16 + r2);
                int cc = ccol + j * 16;
                C[rr * N + cc] = acc[i][j][r2] + resid[rr * N + cc];
            }
}

// ---------------- x_proj: bf16 MFMA, N=96, register-only (no LDS) ----------
__global__ __launch_bounds__(256) void xproj_kernel(
    const __hip_bfloat16* __restrict__ A,    // 4096 x 2048
    const __hip_bfloat16* __restrict__ W,    // 96 x 2048
    float* __restrict__ xpart)
{
    int tid = threadIdx.x;
    int lane = tid & 63;
    int w = tid >> 6;
    int kz = blockIdx.y;
    int row0 = blockIdx.x * 128 + w * 32;
    int m  = lane & 15;
    int kq = lane >> 4;                      // 0..3

    floatx4 acc[2][6];
    #pragma unroll
    for (int i = 0; i < 2; ++i)
        #pragma unroll
        for (int j = 0; j < 6; ++j) acc[i][j] = (floatx4){0.f, 0.f, 0.f, 0.f};

    const __hip_bfloat16* a0 = A + (size_t)(row0 + m) * DI + kz * (DI / SKX) + kq * 8;
    const __hip_bfloat16* b0 = W + (size_t)m * DI + kz * (DI / SKX) + kq * 8;

    #pragma unroll
    for (int ks = 0; ks < (DI / SKX) / 32; ++ks) {   // 8 steps of BK=32
        short8 af0 = *(const short8*)(a0);
        short8 af1 = *(const short8*)(a0 + (size_t)16 * DI);
        #pragma unroll
        for (int j = 0; j < 6; ++j) {
            short8 bf = *(const short8*)(b0 + (size_t)j * 16 * DI);
            acc[0][j] = __builtin_amdgcn_mfma_f32_16x16x32_bf16(af0, bf, acc[0][j], 0, 0, 0);
            acc[1][j] = __builtin_amdgcn_mfma_f32_16x16x32_bf16(af1, bf, acc[1][j], 0, 0, 0);
        }
        a0 += 32; b0 += 32;
    }

    float* cp = xpart + (size_t)kz * XPROJ_PART;
    int crow = row0 + kq * 4;
    #pragma unroll
    for (int i = 0; i < 2; ++i)
        #pragma unroll
        for (int j = 0; j < 6; ++j)
            #pragma unroll
            for (int r = 0; r < 4; ++r)
                cp[(size_t)(crow + i * 16 + r) * XDW + j * 16 + m] = acc[i][j][r];
}

// Reduce the SKX partial buffers of x_proj into xdbl.
__global__ __launch_bounds__(256) void reduce8_kernel(
    const float* __restrict__ part, float* __restrict__ xdbl)
{
    int i = blockIdx.x * 256 + threadIdx.x;    // over 4096*96
    float s = 0.f;
    #pragma unroll
    for (int k = 0; k < SKX; ++k) s += part[(size_t)k * XPROJ_PART + i];
    xdbl[i] = s;
}

// ---------------- dt_proj: small-K fp32 GEMM, K=64 staged once, bf16 out ----
__global__ __launch_bounds__(256) void dtproj_kernel(
    const float* __restrict__ xdbl, const float* __restrict__ W,
    const float* __restrict__ bias, __hip_bfloat16* __restrict__ dlt)
{
    __shared__ float As[64 * 64];   // [k][m]
    __shared__ float Ws[64 * 64];   // [k][n]
    int tid = threadIdx.x;
    int col0 = blockIdx.x * 64, row0 = blockIdx.y * 64;
    #pragma unroll
    for (int it = 0; it < 4; ++it) {
        int li = it * 256 + tid;
        int m  = li & 63;
        int kq = li >> 6;
        float4 av = *(const float4*)(xdbl + (size_t)(row0 + m) * XDW + kq * 4);
        float4 wv = *(const float4*)(W + (size_t)(col0 + m) * DTR + kq * 4);
        As[(kq*4+0)*64 + m] = av.x; As[(kq*4+1)*64 + m] = av.y;
        As[(kq*4+2)*64 + m] = av.z; As[(kq*4+3)*64 + m] = av.w;
        Ws[(kq*4+0)*64 + m] = wv.x; Ws[(kq*4+1)*64 + m] = wv.y;
        Ws[(kq*4+2)*64 + m] = wv.z; Ws[(kq*4+3)*64 + m] = wv.w;
    }
    __syncthreads();
    int tx = tid & 15, ty = tid >> 4;
    float acc[4][4];
    #pragma unroll
    for (int i = 0; i < 4; ++i)
        #pragma unroll
        for (int j = 0; j < 4; ++j) acc[i][j] = 0.f;
    #pragma unroll 8
    for (int k = 0; k < DTR; ++k) {
        float4 a = *(const float4*)(As + k*64 + ty*4);
        float4 w = *(const float4*)(Ws + k*64 + tx*4);
        float av4[4] = {a.x, a.y, a.z, a.w};
        float wv4[4] = {w.x, w.y, w.z, w.w};
        #pragma unroll
        for (int i = 0; i < 4; ++i)
            #pragma unroll
            for (int j = 0; j < 4; ++j)
                acc[i][j] = fmaf(av4[i], wv4[j], acc[i][j]);
    }
    float4 bv = *(const float4*)(bias + col0 + tx*4);
    float b4[4] = {bv.x, bv.y, bv.z, bv.w};
    #pragma unroll
    for (int i = 0; i < 4; ++i) {
        union { __hip_bfloat16 h[4]; ushort4 u; } cv;
        cv.h[0] = __float2bfloat16(softplusf(acc[i][0] + b4[0]));
        cv.h[1] = __float2bfloat16(softplusf(acc[i][1] + b4[1]));
        cv.h[2] = __float2bfloat16(softplusf(acc[i][2] + b4[2]));
        cv.h[3] = __float2bfloat16(softplusf(acc[i][3] + b4[3]));
        *(ushort4*)(dlt + (size_t)(row0 + ty*4 + i) * DI + col0 + tx*4) = cv.u;
    }
}

// ---------------- Causal depthwise conv (width 4) + SiLU, bf16 in/out -------
__global__ __launch_bounds__(256) void conv_silu_kernel(
    const __hip_bfloat16* __restrict__ xz, const float* __restrict__ cw,
    const float* __restrict__ cb, ushort4* __restrict__ uc_bf)
{
    int i4 = blockIdx.x * 256 + threadIdx.x;   // 4-ch group over NB*LSEQ*DI/4
    int d4 = i4 & 511;                          // DI/4 = 512
    int bt = i4 >> 9;
    int t  = bt & (LSEQ - 1);
    int d  = d4 * 4;
    float4 w0 = *(const float4*)(cw + (size_t)(d+0) * 4);
    float4 w1 = *(const float4*)(cw + (size_t)(d+1) * 4);
    float4 w2 = *(const float4*)(cw + (size_t)(d+2) * 4);
    float4 w3 = *(const float4*)(cw + (size_t)(d+3) * 4);
    const float* wt0 = (const float*)&w0;
    const float* wt1 = (const float*)&w1;
    const float* wt2 = (const float*)&w2;
    const float* wt3 = (const float*)&w3;
    float4 acc = *(const float4*)(cb + d);
    const __hip_bfloat16* base = xz + ((size_t)bt << 12) + d;   // row stride 4096
    #pragma unroll
    for (int k = 0; k < 4; ++k) {
        int tp = t - 3 + k;
        if (tp >= 0) {
            union { ushort4 u; __hip_bfloat16 h[4]; } raw;
            raw.u = *(const ushort4*)(base - ((size_t)(3 - k) << 12));
            acc.x = fmaf(wt0[k], __bfloat162float(raw.h[0]), acc.x);
            acc.y = fmaf(wt1[k], __bfloat162float(raw.h[1]), acc.y);
            acc.z = fmaf(wt2[k], __bfloat162float(raw.h[2]), acc.z);
            acc.w = fmaf(wt3[k], __bfloat162float(raw.h[3]), acc.w);
        }
    }
    union { __hip_bfloat16 h[4]; ushort4 u; } cv;
    cv.h[0] = __float2bfloat16(siluf(acc.x));
    cv.h[1] = __float2bfloat16(siluf(acc.y));
    cv.h[2] = __float2bfloat16(siluf(acc.z));
    cv.h[3] = __float2bfloat16(siluf(acc.w));
    uc_bf[i4] = cv.u;
}

// ---------------- Chunk-parallel selective scan (bf16 u / res / dlt) --------
template<bool FINAL>
__global__ __launch_bounds__(256) void scan_chunk_kernel(
    const __hip_bfloat16* __restrict__ dlt, const __hip_bfloat16* __restrict__ uc,
    const float* __restrict__ xdbl, const float* __restrict__ A_log,
    const float* __restrict__ Dp, const __hip_bfloat16* __restrict__ xz,
    float* __restrict__ P, float* __restrict__ S,
    __hip_bfloat16* __restrict__ y)
{
    __shared__ float sBC[TCH][32];     // [tt][0:16]=B, [16:32]=C
    int tid = threadIdx.x;
    int d = blockIdx.x * 256 + tid;
    int c = blockIdx.y;
    int b = blockIdx.z;
    int row0 = b * LSEQ + c * TCH;

    {   // stage B,C rows of this chunk
        int tt = tid >> 3, j4 = (tid & 7) * 4;
        const float4* src = (const float4*)(xdbl + (size_t)(row0 + tt) * XDW + DTR + j4);
        *(float4*)(&sBC[tt][j4]) = *src;
    }
    __syncthreads();

    float Ac[DS], h[DS], p[DS];
    #pragma unroll
    for (int s = 0; s < DS; ++s) {
        Ac[s] = -expf(A_log[(size_t)d * DS + s]);
        p[s] = 1.f;
    }
    size_t soff = (((size_t)b * CCH + c) * DI + d) * DS;
    if (FINAL) {
        #pragma unroll
        for (int s = 0; s < DS; ++s) h[s] = S[soff + s];   // H0 from pass B
    } else {
        #pragma unroll
        for (int s = 0; s < DS; ++s) h[s] = 0.f;
    }
    float Dd = Dp[d];
    size_t ix = (size_t)row0 * DI + d;
    for (int tt = 0; tt < TCH; ++tt) {
        float dv = __bfloat162float(dlt[ix]);
        float ut = __bfloat162float(uc[ix]);
        float du = dv * ut;
        float yacc = 0.f;
        #pragma unroll
        for (int s = 0; s < DS; ++s) {
            float e = __expf(dv * Ac[s]);
            h[s] = fmaf(e, h[s], du * sBC[tt][s]);
            if (FINAL) yacc = fmaf(h[s], sBC[tt][16 + s], yacc);
            else       p[s] *= e;
        }
        if (FINAL) {
            float res = __bfloat162float(xz[((size_t)(row0 + tt) << 12) + DI + d]);
            y[ix] = __float2bfloat16(fmaf(ut, Dd, yacc) * siluf(res));
        }
        ix += DI;
    }
    if (!FINAL) {
        #pragma unroll
        for (int s = 0; s < DS; ++s) { P[soff + s] = p[s]; S[soff + s] = h[s]; }
    }
}

// Pass B: per (b,d,s), sequentially combine chunks; S[c] becomes H0 of chunk c.
__global__ __launch_bounds__(256) void scan_combine_kernel(
    const float* __restrict__ P, float* __restrict__ S)
{
    int idx = blockIdx.x * 256 + threadIdx.x;   // over NB*DI*DS = 65536
    int b = idx >> 15;                          // DI*DS = 32768
    int rest = idx & 32767;
    float h = 0.f;
    for (int c = 0; c < CCH; ++c) {
        size_t off = (((size_t)b * CCH + c) << 15) + rest;
        float tmp = S[off];
        float pv  = P[off];
        S[off] = h;                             // chunk-start state
        h = fmaf(pv, h, tmp);                   // chunk-end state
    }
}

extern "C" void kernel_launch(void* const* d_in, const int* in_sizes, int n_in,
                              void* d_out, int out_size, void* d_ws, size_t ws_size,
                              hipStream_t stream)
{
    const float* x        = (const float*)d_in[0];
    const float* ln_g     = (const float*)d_in[1];
    const float* ln_b     = (const float*)d_in[2];
    const float* in_w     = (const float*)d_in[3];   // (4096, 1024)
    const float* conv_w   = (const float*)d_in[4];   // (2048, 1, 4)
    const float* conv_b   = (const float*)d_in[5];
    const float* xproj_w  = (const float*)d_in[6];   // (96, 2048)
    const float* dtproj_w = (const float*)d_in[7];   // (2048, 64)
    const float* dtproj_b = (const float*)d_in[8];
    const float* A_log    = (const float*)d_in[9];   // (2048, 16)
    const float* Dvec     = (const float*)d_in[10];
    const float* out_w    = (const float*)d_in[11];  // (1024, 2048)
    float* out = (float*)d_out;

    // Workspace layout (byte offsets). Total 157,155,328 B = 157.2 MB.
    char* base = (char*)d_ws;
    __hip_bfloat16* xz_bf    = (__hip_bfloat16*)(base + 0);           // 4096x4096
    __hip_bfloat16* dlt_bf   = (__hip_bfloat16*)(base + 33554432);    // 4096x2048 bf16
    __hip_bfloat16* uc_bf    = (__hip_bfloat16*)(base + 67108864);    // 4096x2048
    float*          xdbl     = (float*)         (base + 83886080);    // 4096x96
    float*          xpart    = (float*)         (base + 85458944);    // 8x4096x96
    float*          Pch      = (float*)         (base + 85458944);    // alias (16.8MB)
    float*          Sch      = (float*)         (base + 102236160);   // 2x64x2048x16
    __hip_bfloat16* xnorm_bf = (__hip_bfloat16*)(base + 119013376);   // 4096x1024
    __hip_bfloat16* yb_bf    = (__hip_bfloat16*)(base + 127401984);   // 4096x2048
    __hip_bfloat16* inw_bf   = (__hip_bfloat16*)(base + 144179200);   // 4096x1024
    __hip_bfloat16* outw_bf  = (__hip_bfloat16*)(base + 152567808);   // 1024x2048
    __hip_bfloat16* xpw_bf   = (__hip_bfloat16*)(base + 156762112);   // 96x2048

    const int R = NB * LSEQ;                  // 4096 rows

    // 0. weight conversions fp32 -> bf16 (single launch)
    f2bf3_kernel<<<(F2BF_N1 + F2BF_N2 + F2BF_N3 + 255) / 256, 256, 0, stream>>>(
        in_w, (ushort4*)inw_bf, out_w, (ushort4*)outw_bf, xproj_w, (ushort4*)xpw_bf);
    // 1. LayerNorm -> bf16
    ln_kernel<<<R, 256, 0, stream>>>(x, ln_g, ln_b, xnorm_bf);
    // 2. in_proj (bf16 MFMA, swizzled LDS): xz = xnorm @ in_w^T, bf16 out
    gemm_bf16mm<true><<<dim3((2*DI)/128, R/128), 256, 0, stream>>>(
        xnorm_bf, inw_bf, (void*)xz_bf, 2*DI, NE);
    // 3. causal depthwise conv + SiLU -> uc_bf
    conv_silu_kernel<<<(R * DI / 4) / 256, 256, 0, stream>>>(
        xz_bf, conv_w, conv_b, (ushort4*)uc_bf);
    // 4. x_proj (bf16 MFMA, register-only, split-K) + reduce
    xproj_kernel<<<dim3(R/128, SKX), 256, 0, stream>>>(uc_bf, xpw_bf, xpart);
    reduce8_kernel<<<(R * XDW) / 256, 256, 0, stream>>>(xpart, xdbl);
    // 5. dt_proj + softplus -> dlt (bf16)
    dtproj_kernel<<<dim3(DI/64, R/64), 256, 0, stream>>>(
        xdbl, dtproj_w, dtproj_b, dlt_bf);
    // 6. chunk-parallel selective scan (gate fused, bf16 y) -> yb_bf
    dim3 gScan(DI / 256, CCH, NB);            // 8 x 64 x 2 = 1024 blocks
    scan_chunk_kernel<false><<<gScan, 256, 0, stream>>>(
        dlt_bf, uc_bf, xdbl, A_log, Dvec, xz_bf, Pch, Sch, yb_bf);
    scan_combine_kernel<<<(NB * DI * DS) / 256, 256, 0, stream>>>(Pch, Sch);
    scan_chunk_kernel<true><<<gScan, 256, 0, stream>>>(
        dlt_bf, uc_bf, xdbl, A_log, Dvec, xz_bf, Pch, Sch, yb_bf);
    // 7. out_proj (bf16 MFMA, 64x128 tile, swizzled) + residual
    gemm_bf16_n128<<<dim3(NE/128, R/64), 256, 0, stream>>>(
        yb_bf, outw_bf, x, out, NE, DI);
}

// Round 8
// 375.364 us; speedup vs baseline: 7.8726x; 1.0076x over previous
//
#include <hip/hip_runtime.h>
#include <hip/hip_bf16.h>
#include <math.h>

// Problem constants
#define NE    1024   // n_embd
#define DI    2048   // d_inner
#define LSEQ  2048   // L
#define NB    2      // batch
#define DS    16     // d_state
#define DTR   64     // dt_rank
#define XDW   96     // dt_rank + 2*d_state

#define CCH   64           // number of time chunks for the scan
#define TCH   (LSEQ/CCH)   // 32 timesteps per chunk

#define SKX   8            // split-K factor for x_proj
#define XPROJ_PART (4096*96)

typedef __attribute__((ext_vector_type(8))) short short8;   // 8 x bf16 (4 VGPRs)
typedef __attribute__((ext_vector_type(4))) float floatx4;  // MFMA accumulator

__device__ __forceinline__ float softplusf(float x) {
    return (x > 20.f) ? x : log1pf(expf(x));
}
__device__ __forceinline__ float siluf(float x) {
    return x / (1.f + __expf(-x));
}

__device__ __forceinline__ void gld16(const void* g, void* l) {
    __builtin_amdgcn_global_load_lds(
        (const __attribute__((address_space(1))) unsigned int*)g,
        (__attribute__((address_space(3))) unsigned int*)l, 16, 0, 0);
}

// ---------------- prep: LayerNorm (blocks 0..4095) + 3x f2bf (rest) ---------
#define F2BF_N1 (4096*1024/4)          // in_w groups
#define F2BF_N2 (2048*1024/4)          // out_w groups
#define F2BF_N3 (96*2048/4)            // xproj_w groups
#define LN_BLOCKS 4096
#define F2BF_BLOCKS ((F2BF_N1 + F2BF_N2 + F2BF_N3) / 256)   // 6336

__global__ __launch_bounds__(256) void prep_kernel(
    const float* __restrict__ x, const float* __restrict__ g,
    const float* __restrict__ b, __hip_bfloat16* __restrict__ xn,
    const float* __restrict__ s1, ushort4* __restrict__ d1,
    const float* __restrict__ s2, ushort4* __restrict__ d2,
    const float* __restrict__ s3, ushort4* __restrict__ d3)
{
    int tid = threadIdx.x;
    if (blockIdx.x >= LN_BLOCKS) {
        int i = (blockIdx.x - LN_BLOCKS) * 256 + tid;
        const float* src; ushort4* dst; int j;
        if (i < F2BF_N1)                 { src = s1; dst = d1; j = i; }
        else if (i < F2BF_N1 + F2BF_N2)  { src = s2; dst = d2; j = i - F2BF_N1; }
        else                             { src = s3; dst = d3; j = i - F2BF_N1 - F2BF_N2; }
        float4 v = ((const float4*)src)[j];
        union { __hip_bfloat16 h[4]; ushort4 u; } cv;
        cv.h[0] = __float2bfloat16(v.x);
        cv.h[1] = __float2bfloat16(v.y);
        cv.h[2] = __float2bfloat16(v.z);
        cv.h[3] = __float2bfloat16(v.w);
        dst[j] = cv.u;
        return;
    }
    int row = blockIdx.x;
    const float4* xr = (const float4*)(x + (size_t)row * NE);
    float4 v = xr[tid];                       // 256 threads * 4 = 1024
    float s  = v.x + v.y + v.z + v.w;
    float sq = v.x*v.x + v.y*v.y + v.z*v.z + v.w*v.w;
    #pragma unroll
    for (int off = 32; off > 0; off >>= 1) {  // wave64 reduce
        s  += __shfl_down(s, off);
        sq += __shfl_down(sq, off);
    }
    __shared__ float ss[4], ssq[4];
    __shared__ float smu, srstd;
    int wv = tid >> 6, lane = tid & 63;
    if (lane == 0) { ss[wv] = s; ssq[wv] = sq; }
    __syncthreads();
    if (tid == 0) {
        float a = ss[0] + ss[1] + ss[2] + ss[3];
        float q = ssq[0] + ssq[1] + ssq[2] + ssq[3];
        float mu  = a * (1.f / NE);
        float var = q * (1.f / NE) - mu * mu;   // biased var, matches jnp.var
        smu = mu; srstd = rsqrtf(var + 1e-5f);
    }
    __syncthreads();
    float mu = smu, rstd = srstd;
    float4 gv = ((const float4*)g)[tid];
    float4 bv = ((const float4*)b)[tid];
    union { __hip_bfloat16 h[4]; ushort4 u; } cv;
    cv.h[0] = __float2bfloat16((v.x - mu) * rstd * gv.x + bv.x);
    cv.h[1] = __float2bfloat16((v.y - mu) * rstd * gv.y + bv.y);
    cv.h[2] = __float2bfloat16((v.z - mu) * rstd * gv.z + bv.z);
    cv.h[3] = __float2bfloat16((v.w - mu) * rstd * gv.w + bv.w);
    ((ushort4*)xn)[row * 256 + tid] = cv.u;
}

// ---------------- bf16 MFMA GEMM, 128x128 tile, BK=64, swizzled LDS --------
// A: M x K bf16, W: N x K bf16, C: M x N (bf16 if BF16OUT else fp32).
// LDS row = 64 bf16 = 128 B = 8 x 16-B granules. LDS slot c of row r holds
// global granule c ^ (r&7) -> fragment reads are bank-balanced at BW floor.
// 16 K-iterations for K=1024 (half the barriers of BK=32).
template<bool BF16OUT>
__global__ __launch_bounds__(256) void gemm_bf16mm(
    const __hip_bfloat16* __restrict__ A,
    const __hip_bfloat16* __restrict__ W,
    void* __restrict__ Cv, int N, int K)
{
    __shared__ __hip_bfloat16 As[128 * 64];   // 16 KB
    __shared__ __hip_bfloat16 Bs[128 * 64];   // 16 KB
    int tid = threadIdx.x;
    int lane = tid & 63;
    int w = tid >> 6, wr = w >> 1, wc = w & 1;
    int row0 = blockIdx.y * 128, col0 = blockIdx.x * 128;

    // Staging: 4 rounds per matrix; round j covers rows j*32 + (tid>>3),
    // slot c = tid&7, source granule gc = c ^ (r&7)  (r&7 == (tid>>3)&7).
    int sr = tid >> 3, sc = tid & 7;
    int gc = sc ^ (sr & 7);
    const __hip_bfloat16* ag = A + (size_t)(row0 + sr) * K + gc * 8;
    const __hip_bfloat16* bg = W + (size_t)(col0 + sr) * K + gc * 8;
    char* la_st = (char*)As + w * 1024;       // + j*4096 per round
    char* lb_st = (char*)Bs + w * 1024;
    const size_t rs32 = (size_t)32 * K;

    floatx4 acc[4][4];
    #pragma unroll
    for (int i = 0; i < 4; ++i)
        #pragma unroll
        for (int j = 0; j < 4; ++j) acc[i][j] = (floatx4){0.f, 0.f, 0.f, 0.f};

    // Fragment addresses: row m (lane&15), kq = lane>>4.
    // k-half h: granule g = h*4 + kq, slot = g ^ (m&7).
    int m = lane & 15, kq = lane >> 4;
    int s0 = kq ^ (m & 7);
    int s1 = (4 + kq) ^ (m & 7);
    const char* la0 = (const char*)As + (wr * 64 + m) * 128 + s0 * 16;
    const char* la1 = (const char*)As + (wr * 64 + m) * 128 + s1 * 16;
    const char* lb0 = (const char*)Bs + (wc * 64 + m) * 128 + s0 * 16;
    const char* lb1 = (const char*)Bs + (wc * 64 + m) * 128 + s1 * 16;

    for (int k0 = 0; k0 < K; k0 += 64) {
        #pragma unroll
        for (int j = 0; j < 4; ++j) {
            gld16(ag + j * rs32, la_st + j * 4096);
            gld16(bg + j * rs32, lb_st + j * 4096);
        }
        ag += 64; bg += 64;
        __syncthreads();
        {   // k-half 0
            short8 af[4], bf[4];
            #pragma unroll
            for (int i = 0; i < 4; ++i) {
                af[i] = *(const short8*)(la0 + i * 2048);   // +16 rows
                bf[i] = *(const short8*)(lb0 + i * 2048);
            }
            #pragma unroll
            for (int i = 0; i < 4; ++i)
                #pragma unroll
                for (int j = 0; j < 4; ++j)
                    acc[i][j] = __builtin_amdgcn_mfma_f32_16x16x32_bf16(
                        af[i], bf[j], acc[i][j], 0, 0, 0);
        }
        {   // k-half 1
            short8 af[4], bf[4];
            #pragma unroll
            for (int i = 0; i < 4; ++i) {
                af[i] = *(const short8*)(la1 + i * 2048);
                bf[i] = *(const short8*)(lb1 + i * 2048);
            }
            #pragma unroll
            for (int i = 0; i < 4; ++i)
                #pragma unroll
                for (int j = 0; j < 4; ++j)
                    acc[i][j] = __builtin_amdgcn_mfma_f32_16x16x32_bf16(
                        af[i], bf[j], acc[i][j], 0, 0, 0);
        }
        __syncthreads();
    }

    // C/D layout: col = lane&15 (n), row = (lane>>4)*4 + reg (m)
    int crow = row0 + wr * 64 + kq * 4;
    int ccol = col0 + wc * 64 + m;
    #pragma unroll
    for (int i = 0; i < 4; ++i)
        #pragma unroll
        for (int j = 0; j < 4; ++j)
            #pragma unroll
            for (int r2 = 0; r2 < 4; ++r2) {
                size_t rr = (size_t)(crow + i * 16 + r2);
                int cc = ccol + j * 16;
                if (BF16OUT)
                    ((__hip_bfloat16*)Cv)[rr * N + cc] = __float2bfloat16(acc[i][j][r2]);
                else
                    ((float*)Cv)[rr * N + cc] = acc[i][j][r2];
            }
}

// ---------------- bf16 MFMA GEMM, 64x128 tile, BK=64, fp32 out + resid ------
// out_proj: grid (N/128, M/64) = 512 blocks (2/CU). LDS 24 KB.
__global__ __launch_bounds__(256) void gemm_bf16_n128(
    const __hip_bfloat16* __restrict__ A,
    const __hip_bfloat16* __restrict__ W,
    const float* __restrict__ resid,
    float* __restrict__ C, int N, int K)
{
    __shared__ __hip_bfloat16 As[64 * 64];    // 8 KB
    __shared__ __hip_bfloat16 Bs[128 * 64];   // 16 KB
    int tid = threadIdx.x;
    int lane = tid & 63;
    int w = tid >> 6;
    int row0 = blockIdx.y * 64, col0 = blockIdx.x * 128;

    int sr = tid >> 3, sc = tid & 7;
    int gc = sc ^ (sr & 7);
    const __hip_bfloat16* ag = A + (size_t)(row0 + sr) * K + gc * 8;
    const __hip_bfloat16* bg = W + (size_t)(col0 + sr) * K + gc * 8;
    char* la_st = (char*)As + w * 1024;
    char* lb_st = (char*)Bs + w * 1024;
    const size_t rs32 = (size_t)32 * K;

    floatx4 acc[4][2];
    #pragma unroll
    for (int i = 0; i < 4; ++i)
        #pragma unroll
        for (int j = 0; j < 2; ++j) acc[i][j] = (floatx4){0.f, 0.f, 0.f, 0.f};

    int m = lane & 15, kq = lane >> 4;
    int s0 = kq ^ (m & 7);
    int s1 = (4 + kq) ^ (m & 7);
    const char* la0 = (const char*)As + m * 128 + s0 * 16;
    const char* la1 = (const char*)As + m * 128 + s1 * 16;
    const char* lb0 = (const char*)Bs + (w * 32 + m) * 128 + s0 * 16;
    const char* lb1 = (const char*)Bs + (w * 32 + m) * 128 + s1 * 16;

    for (int k0 = 0; k0 < K; k0 += 64) {
        gld16(ag,        la_st);              // A rows 0..31
        gld16(ag + rs32, la_st + 4096);       // A rows 32..63
        #pragma unroll
        for (int j = 0; j < 4; ++j)
            gld16(bg + j * rs32, lb_st + j * 4096);
        ag += 64; bg += 64;
        __syncthreads();
        {
            short8 af[4], bf[2];
            #pragma unroll
            for (int i = 0; i < 4; ++i) af[i] = *(const short8*)(la0 + i * 2048);
            #pragma unroll
            for (int j = 0; j < 2; ++j) bf[j] = *(const short8*)(lb0 + j * 2048);
            #pragma unroll
            for (int i = 0; i < 4; ++i)
                #pragma unroll
                for (int j = 0; j < 2; ++j)
                    acc[i][j] = __builtin_amdgcn_mfma_f32_16x16x32_bf16(
                        af[i], bf[j], acc[i][j], 0, 0, 0);
        }
        {
            short8 af[4], bf[2];
            #pragma unroll
            for (int i = 0; i < 4; ++i) af[i] = *(const short8*)(la1 + i * 2048);
            #pragma unroll
            for (int j = 0; j < 2; ++j) bf[j] = *(const short8*)(lb1 + j * 2048);
            #pragma unroll
            for (int i = 0; i < 4; ++i)
                #pragma unroll
                for (int j = 0; j < 2; ++j)
                    acc[i][j] = __builtin_amdgcn_mfma_f32_16x16x32_bf16(
                        af[i], bf[j], acc[i][j], 0, 0, 0);
        }
        __syncthreads();
    }

    int crow = row0 + kq * 4;
    int ccol = col0 + w * 32 + m;
    #pragma unroll
    for (int i = 0; i < 4; ++i)
        #pragma unroll
        for (int j = 0; j < 2; ++j)
            #pragma unroll
            for (int r2 = 0; r2 < 4; ++r2) {
                size_t rr = (size_t)(crow + i * 16 + r2);
                int cc = ccol + j * 16;
                C[rr * N + cc] = acc[i][j][r2] + resid[rr * N + cc];
            }
}

// ---------------- x_proj: bf16 MFMA, N=96, register-only (no LDS) ----------
__global__ __launch_bounds__(256) void xproj_kernel(
    const __hip_bfloat16* __restrict__ A,    // 4096 x 2048
    const __hip_bfloat16* __restrict__ W,    // 96 x 2048
    float* __restrict__ xpart)
{
    int tid = threadIdx.x;
    int lane = tid & 63;
    int w = tid >> 6;
    int kz = blockIdx.y;
    int row0 = blockIdx.x * 128 + w * 32;
    int m  = lane & 15;
    int kq = lane >> 4;                      // 0..3

    floatx4 acc[2][6];
    #pragma unroll
    for (int i = 0; i < 2; ++i)
        #pragma unroll
        for (int j = 0; j < 6; ++j) acc[i][j] = (floatx4){0.f, 0.f, 0.f, 0.f};

    const __hip_bfloat16* a0 = A + (size_t)(row0 + m) * DI + kz * (DI / SKX) + kq * 8;
    const __hip_bfloat16* b0 = W + (size_t)m * DI + kz * (DI / SKX) + kq * 8;

    #pragma unroll
    for (int ks = 0; ks < (DI / SKX) / 32; ++ks) {   // 8 steps of BK=32
        short8 af0 = *(const short8*)(a0);
        short8 af1 = *(const short8*)(a0 + (size_t)16 * DI);
        #pragma unroll
        for (int j = 0; j < 6; ++j) {
            short8 bf = *(const short8*)(b0 + (size_t)j * 16 * DI);
            acc[0][j] = __builtin_amdgcn_mfma_f32_16x16x32_bf16(af0, bf, acc[0][j], 0, 0, 0);
            acc[1][j] = __builtin_amdgcn_mfma_f32_16x16x32_bf16(af1, bf, acc[1][j], 0, 0, 0);
        }
        a0 += 32; b0 += 32;
    }

    float* cp = xpart + (size_t)kz * XPROJ_PART;
    int crow = row0 + kq * 4;
    #pragma unroll
    for (int i = 0; i < 2; ++i)
        #pragma unroll
        for (int j = 0; j < 6; ++j)
            #pragma unroll
            for (int r = 0; r < 4; ++r)
                cp[(size_t)(crow + i * 16 + r) * XDW + j * 16 + m] = acc[i][j][r];
}

// ---------------- dt_proj (fused split-K reduce): K=64 staged once ----------
// A-stage sums the 8 xpart parts on the fly (cols 0..64). Blocks with
// blockIdx.x==0 additionally reduce cols 64..96 into xdbl for the scan.
__global__ __launch_bounds__(256) void dtproj_kernel(
    const float* __restrict__ xpart, const float* __restrict__ W,
    const float* __restrict__ bias, __hip_bfloat16* __restrict__ dlt,
    float* __restrict__ xdbl)
{
    __shared__ float As[64 * 64];   // [k][m]
    __shared__ float Ws[64 * 64];   // [k][n]
    int tid = threadIdx.x;
    int col0 = blockIdx.x * 64, row0 = blockIdx.y * 64;
    #pragma unroll
    for (int it = 0; it < 4; ++it) {
        int li = it * 256 + tid;
        int m  = li & 63;
        int kq = li >> 6;
        float4 av = make_float4(0.f, 0.f, 0.f, 0.f);
        const float* ap = xpart + (size_t)(row0 + m) * XDW + kq * 4;
        #pragma unroll
        for (int p = 0; p < SKX; ++p) {
            float4 t = *(const float4*)(ap + (size_t)p * XPROJ_PART);
            av.x += t.x; av.y += t.y; av.z += t.z; av.w += t.w;
        }
        float4 wv = *(const float4*)(W + (size_t)(col0 + m) * DTR + kq * 4);
        As[(kq*4+0)*64 + m] = av.x; As[(kq*4+1)*64 + m] = av.y;
        As[(kq*4+2)*64 + m] = av.z; As[(kq*4+3)*64 + m] = av.w;
        Ws[(kq*4+0)*64 + m] = wv.x; Ws[(kq*4+1)*64 + m] = wv.y;
        Ws[(kq*4+2)*64 + m] = wv.z; Ws[(kq*4+3)*64 + m] = wv.w;
    }
    // Side job: reduce B/C cols (64..96) of this row tile into xdbl.
    if (blockIdx.x == 0) {
        int rr = tid >> 2, cg = tid & 3;               // 64 rows x 4 col-groups
        const float* ap = xpart + (size_t)(row0 + rr) * XDW + DTR + cg * 8;
        float4 a0 = make_float4(0.f,0.f,0.f,0.f), a1 = a0;
        #pragma unroll
        for (int p = 0; p < SKX; ++p) {
            float4 t0 = *(const float4*)(ap + (size_t)p * XPROJ_PART);
            float4 t1 = *(const float4*)(ap + (size_t)p * XPROJ_PART + 4);
            a0.x += t0.x; a0.y += t0.y; a0.z += t0.z; a0.w += t0.w;
            a1.x += t1.x; a1.y += t1.y; a1.z += t1.z; a1.w += t1.w;
        }
        float* op = xdbl + (size_t)(row0 + rr) * XDW + DTR + cg * 8;
        *(float4*)op = a0;
        *(float4*)(op + 4) = a1;
    }
    __syncthreads();
    int tx = tid & 15, ty = tid >> 4;
    float acc[4][4];
    #pragma unroll
    for (int i = 0; i < 4; ++i)
        #pragma unroll
        for (int j = 0; j < 4; ++j) acc[i][j] = 0.f;
    #pragma unroll 8
    for (int k = 0; k < DTR; ++k) {
        float4 a = *(const float4*)(As + k*64 + ty*4);
        float4 w = *(const float4*)(Ws + k*64 + tx*4);
        float av4[4] = {a.x, a.y, a.z, a.w};
        float wv4[4] = {w.x, w.y, w.z, w.w};
        #pragma unroll
        for (int i = 0; i < 4; ++i)
            #pragma unroll
            for (int j = 0; j < 4; ++j)
                acc[i][j] = fmaf(av4[i], wv4[j], acc[i][j]);
    }
    float4 bv = *(const float4*)(bias + col0 + tx*4);
    float b4[4] = {bv.x, bv.y, bv.z, bv.w};
    #pragma unroll
    for (int i = 0; i < 4; ++i) {
        union { __hip_bfloat16 h[4]; ushort4 u; } cv;
        cv.h[0] = __float2bfloat16(softplusf(acc[i][0] + b4[0]));
        cv.h[1] = __float2bfloat16(softplusf(acc[i][1] + b4[1]));
        cv.h[2] = __float2bfloat16(softplusf(acc[i][2] + b4[2]));
        cv.h[3] = __float2bfloat16(softplusf(acc[i][3] + b4[3]));
        *(ushort4*)(dlt + (size_t)(row0 + ty*4 + i) * DI + col0 + tx*4) = cv.u;
    }
}

// ---------------- Causal depthwise conv (width 4) + SiLU, bf16 in/out -------
__global__ __launch_bounds__(256) void conv_silu_kernel(
    const __hip_bfloat16* __restrict__ xz, const float* __restrict__ cw,
    const float* __restrict__ cb, ushort4* __restrict__ uc_bf)
{
    int i4 = blockIdx.x * 256 + threadIdx.x;   // 4-ch group over NB*LSEQ*DI/4
    int d4 = i4 & 511;                          // DI/4 = 512
    int bt = i4 >> 9;
    int t  = bt & (LSEQ - 1);
    int d  = d4 * 4;
    float4 w0 = *(const float4*)(cw + (size_t)(d+0) * 4);
    float4 w1 = *(const float4*)(cw + (size_t)(d+1) * 4);
    float4 w2 = *(const float4*)(cw + (size_t)(d+2) * 4);
    float4 w3 = *(const float4*)(cw + (size_t)(d+3) * 4);
    const float* wt0 = (const float*)&w0;
    const float* wt1 = (const float*)&w1;
    const float* wt2 = (const float*)&w2;
    const float* wt3 = (const float*)&w3;
    float4 acc = *(const float4*)(cb + d);
    const __hip_bfloat16* base = xz + ((size_t)bt << 12) + d;   // row stride 4096
    #pragma unroll
    for (int k = 0; k < 4; ++k) {
        int tp = t - 3 + k;
        if (tp >= 0) {
            union { ushort4 u; __hip_bfloat16 h[4]; } raw;
            raw.u = *(const ushort4*)(base - ((size_t)(3 - k) << 12));
            acc.x = fmaf(wt0[k], __bfloat162float(raw.h[0]), acc.x);
            acc.y = fmaf(wt1[k], __bfloat162float(raw.h[1]), acc.y);
            acc.z = fmaf(wt2[k], __bfloat162float(raw.h[2]), acc.z);
            acc.w = fmaf(wt3[k], __bfloat162float(raw.h[3]), acc.w);
        }
    }
    union { __hip_bfloat16 h[4]; ushort4 u; } cv;
    cv.h[0] = __float2bfloat16(siluf(acc.x));
    cv.h[1] = __float2bfloat16(siluf(acc.y));
    cv.h[2] = __float2bfloat16(siluf(acc.z));
    cv.h[3] = __float2bfloat16(siluf(acc.w));
    uc_bf[i4] = cv.u;
}

// ---------------- Chunk-parallel selective scan (bf16 u / res / dlt) --------
template<bool FINAL>
__global__ __launch_bounds__(256) void scan_chunk_kernel(
    const __hip_bfloat16* __restrict__ dlt, const __hip_bfloat16* __restrict__ uc,
    const float* __restrict__ xdbl, const float* __restrict__ A_log,
    const float* __restrict__ Dp, const __hip_bfloat16* __restrict__ xz,
    float* __restrict__ P, float* __restrict__ S,
    __hip_bfloat16* __restrict__ y)
{
    __shared__ float sBC[TCH][32];     // [tt][0:16]=B, [16:32]=C
    int tid = threadIdx.x;
    int d = blockIdx.x * 256 + tid;
    int c = blockIdx.y;
    int b = blockIdx.z;
    int row0 = b * LSEQ + c * TCH;

    {   // stage B,C rows of this chunk
        int tt = tid >> 3, j4 = (tid & 7) * 4;
        const float4* src = (const float4*)(xdbl + (size_t)(row0 + tt) * XDW + DTR + j4);
        *(float4*)(&sBC[tt][j4]) = *src;
    }
    __syncthreads();

    float Ac[DS], h[DS], p[DS];
    #pragma unroll
    for (int s = 0; s < DS; ++s) {
        Ac[s] = -expf(A_log[(size_t)d * DS + s]);
        p[s] = 1.f;
    }
    size_t soff = (((size_t)b * CCH + c) * DI + d) * DS;
    if (FINAL) {
        #pragma unroll
        for (int s = 0; s < DS; ++s) h[s] = S[soff + s];   // H0 from pass B
    } else {
        #pragma unroll
        for (int s = 0; s < DS; ++s) h[s] = 0.f;
    }
    float Dd = Dp[d];
    size_t ix = (size_t)row0 * DI + d;
    for (int tt = 0; tt < TCH; ++tt) {
        float dv = __bfloat162float(dlt[ix]);
        float ut = __bfloat162float(uc[ix]);
        float du = dv * ut;
        float yacc = 0.f;
        #pragma unroll
        for (int s = 0; s < DS; ++s) {
            float e = __expf(dv * Ac[s]);
            h[s] = fmaf(e, h[s], du * sBC[tt][s]);
            if (FINAL) yacc = fmaf(h[s], sBC[tt][16 + s], yacc);
            else       p[s] *= e;
        }
        if (FINAL) {
            float res = __bfloat162float(xz[((size_t)(row0 + tt) << 12) + DI + d]);
            y[ix] = __float2bfloat16(fmaf(ut, Dd, yacc) * siluf(res));
        }
        ix += DI;
    }
    if (!FINAL) {
        #pragma unroll
        for (int s = 0; s < DS; ++s) { P[soff + s] = p[s]; S[soff + s] = h[s]; }
    }
}

// Pass B: per (b,d,s), sequentially combine chunks; S[c] becomes H0 of chunk c.
__global__ __launch_bounds__(256) void scan_combine_kernel(
    const float* __restrict__ P, float* __restrict__ S)
{
    int idx = blockIdx.x * 256 + threadIdx.x;   // over NB*DI*DS = 65536
    int b = idx >> 15;                          // DI*DS = 32768
    int rest = idx & 32767;
    float h = 0.f;
    for (int c = 0; c < CCH; ++c) {
        size_t off = (((size_t)b * CCH + c) << 15) + rest;
        float tmp = S[off];
        float pv  = P[off];
        S[off] = h;                             // chunk-start state
        h = fmaf(pv, h, tmp);                   // chunk-end state
    }
}

extern "C" void kernel_launch(void* const* d_in, const int* in_sizes, int n_in,
                              void* d_out, int out_size, void* d_ws, size_t ws_size,
                              hipStream_t stream)
{
    const float* x        = (const float*)d_in[0];
    const float* ln_g     = (const float*)d_in[1];
    const float* ln_b     = (const float*)d_in[2];
    const float* in_w     = (const float*)d_in[3];   // (4096, 1024)
    const float* conv_w   = (const float*)d_in[4];   // (2048, 1, 4)
    const float* conv_b   = (const float*)d_in[5];
    const float* xproj_w  = (const float*)d_in[6];   // (96, 2048)
    const float* dtproj_w = (const float*)d_in[7];   // (2048, 64)
    const float* dtproj_b = (const float*)d_in[8];
    const float* A_log    = (const float*)d_in[9];   // (2048, 16)
    const float* Dvec     = (const float*)d_in[10];
    const float* out_w    = (const float*)d_in[11];  // (1024, 2048)
    float* out = (float*)d_out;

    // Workspace layout (byte offsets). Total 157,155,328 B = 157.2 MB.
    char* base = (char*)d_ws;
    __hip_bfloat16* xz_bf    = (__hip_bfloat16*)(base + 0);           // 4096x4096
    __hip_bfloat16* dlt_bf   = (__hip_bfloat16*)(base + 33554432);    // 4096x2048 bf16
    __hip_bfloat16* uc_bf    = (__hip_bfloat16*)(base + 67108864);    // 4096x2048
    float*          xdbl     = (float*)         (base + 83886080);    // 4096x96
    float*          xpart    = (float*)         (base + 85458944);    // 8x4096x96
    float*          Pch      = (float*)         (base + 85458944);    // alias (xpart dead after dtproj)
    float*          Sch      = (float*)         (base + 102236160);   // 2x64x2048x16
    __hip_bfloat16* xnorm_bf = (__hip_bfloat16*)(base + 119013376);   // 4096x1024
    __hip_bfloat16* yb_bf    = (__hip_bfloat16*)(base + 127401984);   // 4096x2048
    __hip_bfloat16* inw_bf   = (__hip_bfloat16*)(base + 144179200);   // 4096x1024
    __hip_bfloat16* outw_bf  = (__hip_bfloat16*)(base + 152567808);   // 1024x2048
    __hip_bfloat16* xpw_bf   = (__hip_bfloat16*)(base + 156762112);   // 96x2048

    const int R = NB * LSEQ;                  // 4096 rows

    // 0+1. weight conversions + LayerNorm in one launch
    prep_kernel<<<LN_BLOCKS + F2BF_BLOCKS, 256, 0, stream>>>(
        x, ln_g, ln_b, xnorm_bf,
        in_w, (ushort4*)inw_bf, out_w, (ushort4*)outw_bf, xproj_w, (ushort4*)xpw_bf);
    // 2. in_proj (bf16 MFMA, BK=64, swizzled LDS): xz = xnorm @ in_w^T, bf16 out
    gemm_bf16mm<true><<<dim3((2*DI)/128, R/128), 256, 0, stream>>>(
        xnorm_bf, inw_bf, (void*)xz_bf, 2*DI, NE);
    // 3. causal depthwise conv + SiLU -> uc_bf
    conv_silu_kernel<<<(R * DI / 4) / 256, 256, 0, stream>>>(
        xz_bf, conv_w, conv_b, (ushort4*)uc_bf);
    // 4. x_proj (bf16 MFMA, register-only, split-K)
    xproj_kernel<<<dim3(R/128, SKX), 256, 0, stream>>>(uc_bf, xpw_bf, xpart);
    // 5. dt_proj + softplus (self-reducing split-K) -> dlt (bf16); also reduces
    //    B/C cols into xdbl (blockIdx.x==0 blocks).
    dtproj_kernel<<<dim3(DI/64, R/64), 256, 0, stream>>>(
        xpart, dtproj_w, dtproj_b, dlt_bf, xdbl);
    // 6. chunk-parallel selective scan (gate fused, bf16 y) -> yb_bf
    dim3 gScan(DI / 256, CCH, NB);            // 8 x 64 x 2 = 1024 blocks
    scan_chunk_kernel<false><<<gScan, 256, 0, stream>>>(
        dlt_bf, uc_bf, xdbl, A_log, Dvec, xz_bf, Pch, Sch, yb_bf);
    scan_combine_kernel<<<(NB * DI * DS) / 256, 256, 0, stream>>>(Pch, Sch);
    scan_chunk_kernel<true><<<gScan, 256, 0, stream>>>(
        dlt_bf, uc_bf, xdbl, A_log, Dvec, xz_bf, Pch, Sch, yb_bf);
    // 7. out_proj (bf16 MFMA, 64x128 tile, BK=64) + residual
    gemm_bf16_n128<<<dim3(NE/128, R/64), 256, 0, stream>>>(
        yb_bf, outw_bf, x, out, NE, DI);
}

// Round 9
// 358.848 us; speedup vs baseline: 8.2349x; 1.0460x over previous
//
#include <hip/hip_runtime.h>
#include <hip/hip_bf16.h>
#include <math.h>

// Problem constants
#define NE    1024   // n_embd
#define DI    2048   // d_inner
#define LSEQ  2048   // L
#define NB    2      // batch
#define DS    16     // d_state
#define DTR   64     // dt_rank
#define XDW   96     // dt_rank + 2*d_state

#define CCH   64           // number of time chunks for the scan
#define TCH   (LSEQ/CCH)   // 32 timesteps per chunk

#define SKX   8            // split-K factor for x_proj
#define XPROJ_PART (4096*96)

typedef __attribute__((ext_vector_type(8))) short short8;   // 8 x bf16 (4 VGPRs)
typedef __attribute__((ext_vector_type(4))) float floatx4;  // MFMA accumulator

__device__ __forceinline__ float softplusf(float x) {
    return (x > 20.f) ? x : log1pf(expf(x));
}
__device__ __forceinline__ float siluf(float x) {
    return x / (1.f + __expf(-x));
}

__device__ __forceinline__ void gld16(const void* g, void* l) {
    __builtin_amdgcn_global_load_lds(
        (const __attribute__((address_space(1))) unsigned int*)g,
        (__attribute__((address_space(3))) unsigned int*)l, 16, 0, 0);
}

// ---------------- prep: LayerNorm (blocks 0..4095) + 3x f2bf (rest) ---------
#define F2BF_N1 (4096*1024/4)          // in_w groups
#define F2BF_N2 (2048*1024/4)          // out_w groups
#define F2BF_N3 (96*2048/4)            // xproj_w groups
#define LN_BLOCKS 4096
#define F2BF_BLOCKS ((F2BF_N1 + F2BF_N2 + F2BF_N3) / 256)   // 6336

__global__ __launch_bounds__(256) void prep_kernel(
    const float* __restrict__ x, const float* __restrict__ g,
    const float* __restrict__ b, __hip_bfloat16* __restrict__ xn,
    const float* __restrict__ s1, ushort4* __restrict__ d1,
    const float* __restrict__ s2, ushort4* __restrict__ d2,
    const float* __restrict__ s3, ushort4* __restrict__ d3)
{
    int tid = threadIdx.x;
    if (blockIdx.x >= LN_BLOCKS) {
        int i = (blockIdx.x - LN_BLOCKS) * 256 + tid;
        const float* src; ushort4* dst; int j;
        if (i < F2BF_N1)                 { src = s1; dst = d1; j = i; }
        else if (i < F2BF_N1 + F2BF_N2)  { src = s2; dst = d2; j = i - F2BF_N1; }
        else                             { src = s3; dst = d3; j = i - F2BF_N1 - F2BF_N2; }
        float4 v = ((const float4*)src)[j];
        union { __hip_bfloat16 h[4]; ushort4 u; } cv;
        cv.h[0] = __float2bfloat16(v.x);
        cv.h[1] = __float2bfloat16(v.y);
        cv.h[2] = __float2bfloat16(v.z);
        cv.h[3] = __float2bfloat16(v.w);
        dst[j] = cv.u;
        return;
    }
    int row = blockIdx.x;
    const float4* xr = (const float4*)(x + (size_t)row * NE);
    float4 v = xr[tid];                       // 256 threads * 4 = 1024
    float s  = v.x + v.y + v.z + v.w;
    float sq = v.x*v.x + v.y*v.y + v.z*v.z + v.w*v.w;
    #pragma unroll
    for (int off = 32; off > 0; off >>= 1) {  // wave64 reduce
        s  += __shfl_down(s, off);
        sq += __shfl_down(sq, off);
    }
    __shared__ float ss[4], ssq[4];
    __shared__ float smu, srstd;
    int wv = tid >> 6, lane = tid & 63;
    if (lane == 0) { ss[wv] = s; ssq[wv] = sq; }
    __syncthreads();
    if (tid == 0) {
        float a = ss[0] + ss[1] + ss[2] + ss[3];
        float q = ssq[0] + ssq[1] + ssq[2] + ssq[3];
        float mu  = a * (1.f / NE);
        float var = q * (1.f / NE) - mu * mu;   // biased var, matches jnp.var
        smu = mu; srstd = rsqrtf(var + 1e-5f);
    }
    __syncthreads();
    float mu = smu, rstd = srstd;
    float4 gv = ((const float4*)g)[tid];
    float4 bv = ((const float4*)b)[tid];
    union { __hip_bfloat16 h[4]; ushort4 u; } cv;
    cv.h[0] = __float2bfloat16((v.x - mu) * rstd * gv.x + bv.x);
    cv.h[1] = __float2bfloat16((v.y - mu) * rstd * gv.y + bv.y);
    cv.h[2] = __float2bfloat16((v.z - mu) * rstd * gv.z + bv.z);
    cv.h[3] = __float2bfloat16((v.w - mu) * rstd * gv.w + bv.w);
    ((ushort4*)xn)[row * 256 + tid] = cv.u;
}

// ---------------- bf16 MFMA GEMM, 128x128 tile, BK=64, swizzled LDS --------
// A: M x K bf16, W: N x K bf16, C: M x N (bf16 if BF16OUT else fp32).
// LDS row = 64 bf16 = 128 B = 8 x 16-B granules. LDS slot c of row r holds
// global granule c ^ (r&7) -> fragment reads are bank-balanced at BW floor.
template<bool BF16OUT>
__global__ __launch_bounds__(256) void gemm_bf16mm(
    const __hip_bfloat16* __restrict__ A,
    const __hip_bfloat16* __restrict__ W,
    void* __restrict__ Cv, int N, int K)
{
    __shared__ __hip_bfloat16 As[128 * 64];   // 16 KB
    __shared__ __hip_bfloat16 Bs[128 * 64];   // 16 KB
    int tid = threadIdx.x;
    int lane = tid & 63;
    int w = tid >> 6, wr = w >> 1, wc = w & 1;
    int row0 = blockIdx.y * 128, col0 = blockIdx.x * 128;

    int sr = tid >> 3, sc = tid & 7;
    int gc = sc ^ (sr & 7);
    const __hip_bfloat16* ag = A + (size_t)(row0 + sr) * K + gc * 8;
    const __hip_bfloat16* bg = W + (size_t)(col0 + sr) * K + gc * 8;
    char* la_st = (char*)As + w * 1024;       // + j*4096 per round
    char* lb_st = (char*)Bs + w * 1024;
    const size_t rs32 = (size_t)32 * K;

    floatx4 acc[4][4];
    #pragma unroll
    for (int i = 0; i < 4; ++i)
        #pragma unroll
        for (int j = 0; j < 4; ++j) acc[i][j] = (floatx4){0.f, 0.f, 0.f, 0.f};

    int m = lane & 15, kq = lane >> 4;
    int s0 = kq ^ (m & 7);
    int s1 = (4 + kq) ^ (m & 7);
    const char* la0 = (const char*)As + (wr * 64 + m) * 128 + s0 * 16;
    const char* la1 = (const char*)As + (wr * 64 + m) * 128 + s1 * 16;
    const char* lb0 = (const char*)Bs + (wc * 64 + m) * 128 + s0 * 16;
    const char* lb1 = (const char*)Bs + (wc * 64 + m) * 128 + s1 * 16;

    for (int k0 = 0; k0 < K; k0 += 64) {
        #pragma unroll
        for (int j = 0; j < 4; ++j) {
            gld16(ag + j * rs32, la_st + j * 4096);
            gld16(bg + j * rs32, lb_st + j * 4096);
        }
        ag += 64; bg += 64;
        __syncthreads();
        {   // k-half 0
            short8 af[4], bf[4];
            #pragma unroll
            for (int i = 0; i < 4; ++i) {
                af[i] = *(const short8*)(la0 + i * 2048);   // +16 rows
                bf[i] = *(const short8*)(lb0 + i * 2048);
            }
            #pragma unroll
            for (int i = 0; i < 4; ++i)
                #pragma unroll
                for (int j = 0; j < 4; ++j)
                    acc[i][j] = __builtin_amdgcn_mfma_f32_16x16x32_bf16(
                        af[i], bf[j], acc[i][j], 0, 0, 0);
        }
        {   // k-half 1
            short8 af[4], bf[4];
            #pragma unroll
            for (int i = 0; i < 4; ++i) {
                af[i] = *(const short8*)(la1 + i * 2048);
                bf[i] = *(const short8*)(lb1 + i * 2048);
            }
            #pragma unroll
            for (int i = 0; i < 4; ++i)
                #pragma unroll
                for (int j = 0; j < 4; ++j)
                    acc[i][j] = __builtin_amdgcn_mfma_f32_16x16x32_bf16(
                        af[i], bf[j], acc[i][j], 0, 0, 0);
        }
        __syncthreads();
    }

    // C/D layout: col = lane&15 (n), row = (lane>>4)*4 + reg (m)
    int crow = row0 + wr * 64 + kq * 4;
    int ccol = col0 + wc * 64 + m;
    #pragma unroll
    for (int i = 0; i < 4; ++i)
        #pragma unroll
        for (int j = 0; j < 4; ++j)
            #pragma unroll
            for (int r2 = 0; r2 < 4; ++r2) {
                size_t rr = (size_t)(crow + i * 16 + r2);
                int cc = ccol + j * 16;
                if (BF16OUT)
                    ((__hip_bfloat16*)Cv)[rr * N + cc] = __float2bfloat16(acc[i][j][r2]);
                else
                    ((float*)Cv)[rr * N + cc] = acc[i][j][r2];
            }
}

// ---------------- bf16 MFMA GEMM, 64x128 tile, BK=64, fp32 out + resid ------
__global__ __launch_bounds__(256) void gemm_bf16_n128(
    const __hip_bfloat16* __restrict__ A,
    const __hip_bfloat16* __restrict__ W,
    const float* __restrict__ resid,
    float* __restrict__ C, int N, int K)
{
    __shared__ __hip_bfloat16 As[64 * 64];    // 8 KB
    __shared__ __hip_bfloat16 Bs[128 * 64];   // 16 KB
    int tid = threadIdx.x;
    int lane = tid & 63;
    int w = tid >> 6;
    int row0 = blockIdx.y * 64, col0 = blockIdx.x * 128;

    int sr = tid >> 3, sc = tid & 7;
    int gc = sc ^ (sr & 7);
    const __hip_bfloat16* ag = A + (size_t)(row0 + sr) * K + gc * 8;
    const __hip_bfloat16* bg = W + (size_t)(col0 + sr) * K + gc * 8;
    char* la_st = (char*)As + w * 1024;
    char* lb_st = (char*)Bs + w * 1024;
    const size_t rs32 = (size_t)32 * K;

    floatx4 acc[4][2];
    #pragma unroll
    for (int i = 0; i < 4; ++i)
        #pragma unroll
        for (int j = 0; j < 2; ++j) acc[i][j] = (floatx4){0.f, 0.f, 0.f, 0.f};

    int m = lane & 15, kq = lane >> 4;
    int s0 = kq ^ (m & 7);
    int s1 = (4 + kq) ^ (m & 7);
    const char* la0 = (const char*)As + m * 128 + s0 * 16;
    const char* la1 = (const char*)As + m * 128 + s1 * 16;
    const char* lb0 = (const char*)Bs + (w * 32 + m) * 128 + s0 * 16;
    const char* lb1 = (const char*)Bs + (w * 32 + m) * 128 + s1 * 16;

    for (int k0 = 0; k0 < K; k0 += 64) {
        gld16(ag,        la_st);              // A rows 0..31
        gld16(ag + rs32, la_st + 4096);       // A rows 32..63
        #pragma unroll
        for (int j = 0; j < 4; ++j)
            gld16(bg + j * rs32, lb_st + j * 4096);
        ag += 64; bg += 64;
        __syncthreads();
        {
            short8 af[4], bf[2];
            #pragma unroll
            for (int i = 0; i < 4; ++i) af[i] = *(const short8*)(la0 + i * 2048);
            #pragma unroll
            for (int j = 0; j < 2; ++j) bf[j] = *(const short8*)(lb0 + j * 2048);
            #pragma unroll
            for (int i = 0; i < 4; ++i)
                #pragma unroll
                for (int j = 0; j < 2; ++j)
                    acc[i][j] = __builtin_amdgcn_mfma_f32_16x16x32_bf16(
                        af[i], bf[j], acc[i][j], 0, 0, 0);
        }
        {
            short8 af[4], bf[2];
            #pragma unroll
            for (int i = 0; i < 4; ++i) af[i] = *(const short8*)(la1 + i * 2048);
            #pragma unroll
            for (int j = 0; j < 2; ++j) bf[j] = *(const short8*)(lb1 + j * 2048);
            #pragma unroll
            for (int i = 0; i < 4; ++i)
                #pragma unroll
                for (int j = 0; j < 2; ++j)
                    acc[i][j] = __builtin_amdgcn_mfma_f32_16x16x32_bf16(
                        af[i], bf[j], acc[i][j], 0, 0, 0);
        }
        __syncthreads();
    }

    int crow = row0 + kq * 4;
    int ccol = col0 + w * 32 + m;
    #pragma unroll
    for (int i = 0; i < 4; ++i)
        #pragma unroll
        for (int j = 0; j < 2; ++j)
            #pragma unroll
            for (int r2 = 0; r2 < 4; ++r2) {
                size_t rr = (size_t)(crow + i * 16 + r2);
                int cc = ccol + j * 16;
                C[rr * N + cc] = acc[i][j][r2] + resid[rr * N + cc];
            }
}

// ---------------- x_proj: bf16 MFMA, N=96, register-only (no LDS) ----------
__global__ __launch_bounds__(256) void xproj_kernel(
    const __hip_bfloat16* __restrict__ A,    // 4096 x 2048
    const __hip_bfloat16* __restrict__ W,    // 96 x 2048
    float* __restrict__ xpart)
{
    int tid = threadIdx.x;
    int lane = tid & 63;
    int w = tid >> 6;
    int kz = blockIdx.y;
    int row0 = blockIdx.x * 128 + w * 32;
    int m  = lane & 15;
    int kq = lane >> 4;                      // 0..3

    floatx4 acc[2][6];
    #pragma unroll
    for (int i = 0; i < 2; ++i)
        #pragma unroll
        for (int j = 0; j < 6; ++j) acc[i][j] = (floatx4){0.f, 0.f, 0.f, 0.f};

    const __hip_bfloat16* a0 = A + (size_t)(row0 + m) * DI + kz * (DI / SKX) + kq * 8;
    const __hip_bfloat16* b0 = W + (size_t)m * DI + kz * (DI / SKX) + kq * 8;

    #pragma unroll
    for (int ks = 0; ks < (DI / SKX) / 32; ++ks) {   // 8 steps of BK=32
        short8 af0 = *(const short8*)(a0);
        short8 af1 = *(const short8*)(a0 + (size_t)16 * DI);
        #pragma unroll
        for (int j = 0; j < 6; ++j) {
            short8 bf = *(const short8*)(b0 + (size_t)j * 16 * DI);
            acc[0][j] = __builtin_amdgcn_mfma_f32_16x16x32_bf16(af0, bf, acc[0][j], 0, 0, 0);
            acc[1][j] = __builtin_amdgcn_mfma_f32_16x16x32_bf16(af1, bf, acc[1][j], 0, 0, 0);
        }
        a0 += 32; b0 += 32;
    }

    float* cp = xpart + (size_t)kz * XPROJ_PART;
    int crow = row0 + kq * 4;
    #pragma unroll
    for (int i = 0; i < 2; ++i)
        #pragma unroll
        for (int j = 0; j < 6; ++j)
            #pragma unroll
            for (int r = 0; r < 4; ++r)
                cp[(size_t)(crow + i * 16 + r) * XDW + j * 16 + m] = acc[i][j][r];
}

// Reduce the SKX partial buffers of x_proj into xdbl.
__global__ __launch_bounds__(256) void reduce8_kernel(
    const float* __restrict__ part, float* __restrict__ xdbl)
{
    int i = blockIdx.x * 256 + threadIdx.x;    // over 4096*96
    float s = 0.f;
    #pragma unroll
    for (int k = 0; k < SKX; ++k) s += part[(size_t)k * XPROJ_PART + i];
    xdbl[i] = s;
}

// ---------------- dt_proj: small-K fp32 GEMM, K=64 staged once, bf16 out ----
__global__ __launch_bounds__(256) void dtproj_kernel(
    const float* __restrict__ xdbl, const float* __restrict__ W,
    const float* __restrict__ bias, __hip_bfloat16* __restrict__ dlt)
{
    __shared__ float As[64 * 64];   // [k][m]
    __shared__ float Ws[64 * 64];   // [k][n]
    int tid = threadIdx.x;
    int col0 = blockIdx.x * 64, row0 = blockIdx.y * 64;
    #pragma unroll
    for (int it = 0; it < 4; ++it) {
        int li = it * 256 + tid;
        int m  = li & 63;
        int kq = li >> 6;
        float4 av = *(const float4*)(xdbl + (size_t)(row0 + m) * XDW + kq * 4);
        float4 wv = *(const float4*)(W + (size_t)(col0 + m) * DTR + kq * 4);
        As[(kq*4+0)*64 + m] = av.x; As[(kq*4+1)*64 + m] = av.y;
        As[(kq*4+2)*64 + m] = av.z; As[(kq*4+3)*64 + m] = av.w;
        Ws[(kq*4+0)*64 + m] = wv.x; Ws[(kq*4+1)*64 + m] = wv.y;
        Ws[(kq*4+2)*64 + m] = wv.z; Ws[(kq*4+3)*64 + m] = wv.w;
    }
    __syncthreads();
    int tx = tid & 15, ty = tid >> 4;
    float acc[4][4];
    #pragma unroll
    for (int i = 0; i < 4; ++i)
        #pragma unroll
        for (int j = 0; j < 4; ++j) acc[i][j] = 0.f;
    #pragma unroll 8
    for (int k = 0; k < DTR; ++k) {
        float4 a = *(const float4*)(As + k*64 + ty*4);
        float4 w = *(const float4*)(Ws + k*64 + tx*4);
        float av4[4] = {a.x, a.y, a.z, a.w};
        float wv4[4] = {w.x, w.y, w.z, w.w};
        #pragma unroll
        for (int i = 0; i < 4; ++i)
            #pragma unroll
            for (int j = 0; j < 4; ++j)
                acc[i][j] = fmaf(av4[i], wv4[j], acc[i][j]);
    }
    float4 bv = *(const float4*)(bias + col0 + tx*4);
    float b4[4] = {bv.x, bv.y, bv.z, bv.w};
    #pragma unroll
    for (int i = 0; i < 4; ++i) {
        union { __hip_bfloat16 h[4]; ushort4 u; } cv;
        cv.h[0] = __float2bfloat16(softplusf(acc[i][0] + b4[0]));
        cv.h[1] = __float2bfloat16(softplusf(acc[i][1] + b4[1]));
        cv.h[2] = __float2bfloat16(softplusf(acc[i][2] + b4[2]));
        cv.h[3] = __float2bfloat16(softplusf(acc[i][3] + b4[3]));
        *(ushort4*)(dlt + (size_t)(row0 + ty*4 + i) * DI + col0 + tx*4) = cv.u;
    }
}

// ---------------- Causal depthwise conv (width 4) + SiLU, bf16 in/out -------
__global__ __launch_bounds__(256) void conv_silu_kernel(
    const __hip_bfloat16* __restrict__ xz, const float* __restrict__ cw,
    const float* __restrict__ cb, ushort4* __restrict__ uc_bf)
{
    int i4 = blockIdx.x * 256 + threadIdx.x;   // 4-ch group over NB*LSEQ*DI/4
    int d4 = i4 & 511;                          // DI/4 = 512
    int bt = i4 >> 9;
    int t  = bt & (LSEQ - 1);
    int d  = d4 * 4;
    float4 w0 = *(const float4*)(cw + (size_t)(d+0) * 4);
    float4 w1 = *(const float4*)(cw + (size_t)(d+1) * 4);
    float4 w2 = *(const float4*)(cw + (size_t)(d+2) * 4);
    float4 w3 = *(const float4*)(cw + (size_t)(d+3) * 4);
    const float* wt0 = (const float*)&w0;
    const float* wt1 = (const float*)&w1;
    const float* wt2 = (const float*)&w2;
    const float* wt3 = (const float*)&w3;
    float4 acc = *(const float4*)(cb + d);
    const __hip_bfloat16* base = xz + ((size_t)bt << 12) + d;   // row stride 4096
    #pragma unroll
    for (int k = 0; k < 4; ++k) {
        int tp = t - 3 + k;
        if (tp >= 0) {
            union { ushort4 u; __hip_bfloat16 h[4]; } raw;
            raw.u = *(const ushort4*)(base - ((size_t)(3 - k) << 12));
            acc.x = fmaf(wt0[k], __bfloat162float(raw.h[0]), acc.x);
            acc.y = fmaf(wt1[k], __bfloat162float(raw.h[1]), acc.y);
            acc.z = fmaf(wt2[k], __bfloat162float(raw.h[2]), acc.z);
            acc.w = fmaf(wt3[k], __bfloat162float(raw.h[3]), acc.w);
        }
    }
    union { __hip_bfloat16 h[4]; ushort4 u; } cv;
    cv.h[0] = __float2bfloat16(siluf(acc.x));
    cv.h[1] = __float2bfloat16(siluf(acc.y));
    cv.h[2] = __float2bfloat16(siluf(acc.z));
    cv.h[3] = __float2bfloat16(siluf(acc.w));
    uc_bf[i4] = cv.u;
}

// ---------------- Chunk-parallel selective scan (bf16 u / res / dlt) --------
template<bool FINAL>
__global__ __launch_bounds__(256) void scan_chunk_kernel(
    const __hip_bfloat16* __restrict__ dlt, const __hip_bfloat16* __restrict__ uc,
    const float* __restrict__ xdbl, const float* __restrict__ A_log,
    const float* __restrict__ Dp, const __hip_bfloat16* __restrict__ xz,
    float* __restrict__ P, float* __restrict__ S,
    __hip_bfloat16* __restrict__ y)
{
    __shared__ float sBC[TCH][32];     // [tt][0:16]=B, [16:32]=C
    int tid = threadIdx.x;
    int d = blockIdx.x * 256 + tid;
    int c = blockIdx.y;
    int b = blockIdx.z;
    int row0 = b * LSEQ + c * TCH;

    {   // stage B,C rows of this chunk
        int tt = tid >> 3, j4 = (tid & 7) * 4;
        const float4* src = (const float4*)(xdbl + (size_t)(row0 + tt) * XDW + DTR + j4);
        *(float4*)(&sBC[tt][j4]) = *src;
    }
    __syncthreads();

    float Ac[DS], h[DS], p[DS];
    #pragma unroll
    for (int s = 0; s < DS; ++s) {
        Ac[s] = -expf(A_log[(size_t)d * DS + s]);
        p[s] = 1.f;
    }
    size_t soff = (((size_t)b * CCH + c) * DI + d) * DS;
    if (FINAL) {
        #pragma unroll
        for (int s = 0; s < DS; ++s) h[s] = S[soff + s];   // H0 from pass B
    } else {
        #pragma unroll
        for (int s = 0; s < DS; ++s) h[s] = 0.f;
    }
    float Dd = Dp[d];
    size_t ix = (size_t)row0 * DI + d;
    for (int tt = 0; tt < TCH; ++tt) {
        float dv = __bfloat162float(dlt[ix]);
        float ut = __bfloat162float(uc[ix]);
        float du = dv * ut;
        float yacc = 0.f;
        #pragma unroll
        for (int s = 0; s < DS; ++s) {
            float e = __expf(dv * Ac[s]);
            h[s] = fmaf(e, h[s], du * sBC[tt][s]);
            if (FINAL) yacc = fmaf(h[s], sBC[tt][16 + s], yacc);
            else       p[s] *= e;
        }
        if (FINAL) {
            float res = __bfloat162float(xz[((size_t)(row0 + tt) << 12) + DI + d]);
            y[ix] = __float2bfloat16(fmaf(ut, Dd, yacc) * siluf(res));
        }
        ix += DI;
    }
    if (!FINAL) {
        #pragma unroll
        for (int s = 0; s < DS; ++s) { P[soff + s] = p[s]; S[soff + s] = h[s]; }
    }
}

// Pass B: per (b,d,s), sequentially combine chunks; S[c] becomes H0 of chunk c.
__global__ __launch_bounds__(256) void scan_combine_kernel(
    const float* __restrict__ P, float* __restrict__ S)
{
    int idx = blockIdx.x * 256 + threadIdx.x;   // over NB*DI*DS = 65536
    int b = idx >> 15;                          // DI*DS = 32768
    int rest = idx & 32767;
    float h = 0.f;
    for (int c = 0; c < CCH; ++c) {
        size_t off = (((size_t)b * CCH + c) << 15) + rest;
        float tmp = S[off];
        float pv  = P[off];
        S[off] = h;                             // chunk-start state
        h = fmaf(pv, h, tmp);                   // chunk-end state
    }
}

extern "C" void kernel_launch(void* const* d_in, const int* in_sizes, int n_in,
                              void* d_out, int out_size, void* d_ws, size_t ws_size,
                              hipStream_t stream)
{
    const float* x        = (const float*)d_in[0];
    const float* ln_g     = (const float*)d_in[1];
    const float* ln_b     = (const float*)d_in[2];
    const float* in_w     = (const float*)d_in[3];   // (4096, 1024)
    const float* conv_w   = (const float*)d_in[4];   // (2048, 1, 4)
    const float* conv_b   = (const float*)d_in[5];
    const float* xproj_w  = (const float*)d_in[6];   // (96, 2048)
    const float* dtproj_w = (const float*)d_in[7];   // (2048, 64)
    const float* dtproj_b = (const float*)d_in[8];
    const float* A_log    = (const float*)d_in[9];   // (2048, 16)
    const float* Dvec     = (const float*)d_in[10];
    const float* out_w    = (const float*)d_in[11];  // (1024, 2048)
    float* out = (float*)d_out;

    // Workspace layout (byte offsets). Total 157,155,328 B = 157.2 MB.
    char* base = (char*)d_ws;
    __hip_bfloat16* xz_bf    = (__hip_bfloat16*)(base + 0);           // 4096x4096
    __hip_bfloat16* dlt_bf   = (__hip_bfloat16*)(base + 33554432);    // 4096x2048 bf16
    __hip_bfloat16* uc_bf    = (__hip_bfloat16*)(base + 67108864);    // 4096x2048
    float*          xdbl     = (float*)         (base + 83886080);    // 4096x96
    float*          xpart    = (float*)         (base + 85458944);    // 8x4096x96
    float*          Pch      = (float*)         (base + 85458944);    // alias (xpart dead after dtproj)
    float*          Sch      = (float*)         (base + 102236160);   // 2x64x2048x16
    __hip_bfloat16* xnorm_bf = (__hip_bfloat16*)(base + 119013376);   // 4096x1024
    __hip_bfloat16* yb_bf    = (__hip_bfloat16*)(base + 127401984);   // 4096x2048
    __hip_bfloat16* inw_bf   = (__hip_bfloat16*)(base + 144179200);   // 4096x1024
    __hip_bfloat16* outw_bf  = (__hip_bfloat16*)(base + 152567808);   // 1024x2048
    __hip_bfloat16* xpw_bf   = (__hip_bfloat16*)(base + 156762112);   // 96x2048

    const int R = NB * LSEQ;                  // 4096 rows

    // 0+1. weight conversions + LayerNorm in one launch
    prep_kernel<<<LN_BLOCKS + F2BF_BLOCKS, 256, 0, stream>>>(
        x, ln_g, ln_b, xnorm_bf,
        in_w, (ushort4*)inw_bf, out_w, (ushort4*)outw_bf, xproj_w, (ushort4*)xpw_bf);
    // 2. in_proj (bf16 MFMA, BK=64, swizzled LDS): xz = xnorm @ in_w^T, bf16 out
    gemm_bf16mm<true><<<dim3((2*DI)/128, R/128), 256, 0, stream>>>(
        xnorm_bf, inw_bf, (void*)xz_bf, 2*DI, NE);
    // 3. causal depthwise conv + SiLU -> uc_bf
    conv_silu_kernel<<<(R * DI / 4) / 256, 256, 0, stream>>>(
        xz_bf, conv_w, conv_b, (ushort4*)uc_bf);
    // 4. x_proj (bf16 MFMA, register-only, split-K) + one-pass reduce
    xproj_kernel<<<dim3(R/128, SKX), 256, 0, stream>>>(uc_bf, xpw_bf, xpart);
    reduce8_kernel<<<(R * XDW) / 256, 256, 0, stream>>>(xpart, xdbl);
    // 5. dt_proj + softplus -> dlt (bf16), reading L2-hot xdbl
    dtproj_kernel<<<dim3(DI/64, R/64), 256, 0, stream>>>(
        xdbl, dtproj_w, dtproj_b, dlt_bf);
    // 6. chunk-parallel selective scan (gate fused, bf16 y) -> yb_bf
    dim3 gScan(DI / 256, CCH, NB);            // 8 x 64 x 2 = 1024 blocks
    scan_chunk_kernel<false><<<gScan, 256, 0, stream>>>(
        dlt_bf, uc_bf, xdbl, A_log, Dvec, xz_bf, Pch, Sch, yb_bf);
    scan_combine_kernel<<<(NB * DI * DS) / 256, 256, 0, stream>>>(Pch, Sch);
    scan_chunk_kernel<true><<<gScan, 256, 0, stream>>>(
        dlt_bf, uc_bf, xdbl, A_log, Dvec, xz_bf, Pch, Sch, yb_bf);
    // 7. out_proj (bf16 MFMA, 64x128 tile, BK=64) + residual
    gemm_bf16_n128<<<dim3(NE/128, R/64), 256, 0, stream>>>(
        yb_bf, outw_bf, x, out, NE, DI);
}

// Round 10
// 330.310 us; speedup vs baseline: 8.9464x; 1.0864x over previous
//
#include <hip/hip_runtime.h>
#include <hip/hip_bf16.h>
#include <math.h>

// Problem constants
#define NE    1024   // n_embd
#define DI    2048   // d_inner
#define LSEQ  2048   // L
#define NB    2      // batch
#define DS    16     // d_state
#define DTR   64     // dt_rank
#define XDW   96     // dt_rank + 2*d_state

#define CCH   64           // number of time chunks for the scan
#define TCH   (LSEQ/CCH)   // 32 timesteps per chunk

#define SKX   8            // split-K factor for x_proj
#define XPROJ_PART (4096*96)

typedef __attribute__((ext_vector_type(8))) short short8;   // 8 x bf16 (4 VGPRs)
typedef __attribute__((ext_vector_type(4))) float floatx4;  // MFMA accumulator

__device__ __forceinline__ float softplusf(float x) {
    return (x > 20.f) ? x : log1pf(expf(x));
}
__device__ __forceinline__ float softplus_fast(float x) {
    return (x > 20.f) ? x : __logf(1.f + __expf(x));
}
__device__ __forceinline__ float siluf(float x) {
    return x / (1.f + __expf(-x));
}

__device__ __forceinline__ void gld16(const void* g, void* l) {
    __builtin_amdgcn_global_load_lds(
        (const __attribute__((address_space(1))) unsigned int*)g,
        (__attribute__((address_space(3))) unsigned int*)l, 16, 0, 0);
}

// ---------------- prep: LayerNorm (blocks 0..4095) + 4x f2bf (rest) ---------
#define F2BF_N1 (4096*1024/4)          // in_w groups
#define F2BF_N2 (2048*1024/4)          // out_w groups
#define F2BF_N3 (96*2048/4)            // xproj_w groups
#define F2BF_N4 (2048*64/4)            // dtproj_w groups
#define LN_BLOCKS 4096
#define F2BF_BLOCKS ((F2BF_N1 + F2BF_N2 + F2BF_N3 + F2BF_N4) / 256)

__global__ __launch_bounds__(256) void prep_kernel(
    const float* __restrict__ x, const float* __restrict__ g,
    const float* __restrict__ b, __hip_bfloat16* __restrict__ xn,
    const float* __restrict__ s1, ushort4* __restrict__ d1,
    const float* __restrict__ s2, ushort4* __restrict__ d2,
    const float* __restrict__ s3, ushort4* __restrict__ d3,
    const float* __restrict__ s4, ushort4* __restrict__ d4)
{
    int tid = threadIdx.x;
    if (blockIdx.x >= LN_BLOCKS) {
        int i = (blockIdx.x - LN_BLOCKS) * 256 + tid;
        const float* src; ushort4* dst; int j;
        if (i < F2BF_N1)                           { src = s1; dst = d1; j = i; }
        else if (i < F2BF_N1 + F2BF_N2)            { src = s2; dst = d2; j = i - F2BF_N1; }
        else if (i < F2BF_N1 + F2BF_N2 + F2BF_N3)  { src = s3; dst = d3; j = i - F2BF_N1 - F2BF_N2; }
        else                                       { src = s4; dst = d4; j = i - F2BF_N1 - F2BF_N2 - F2BF_N3; }
        float4 v = ((const float4*)src)[j];
        union { __hip_bfloat16 h[4]; ushort4 u; } cv;
        cv.h[0] = __float2bfloat16(v.x);
        cv.h[1] = __float2bfloat16(v.y);
        cv.h[2] = __float2bfloat16(v.z);
        cv.h[3] = __float2bfloat16(v.w);
        dst[j] = cv.u;
        return;
    }
    int row = blockIdx.x;
    const float4* xr = (const float4*)(x + (size_t)row * NE);
    float4 v = xr[tid];                       // 256 threads * 4 = 1024
    float s  = v.x + v.y + v.z + v.w;
    float sq = v.x*v.x + v.y*v.y + v.z*v.z + v.w*v.w;
    #pragma unroll
    for (int off = 32; off > 0; off >>= 1) {  // wave64 reduce
        s  += __shfl_down(s, off);
        sq += __shfl_down(sq, off);
    }
    __shared__ float ss[4], ssq[4];
    __shared__ float smu, srstd;
    int wv = tid >> 6, lane = tid & 63;
    if (lane == 0) { ss[wv] = s; ssq[wv] = sq; }
    __syncthreads();
    if (tid == 0) {
        float a = ss[0] + ss[1] + ss[2] + ss[3];
        float q = ssq[0] + ssq[1] + ssq[2] + ssq[3];
        float mu  = a * (1.f / NE);
        float var = q * (1.f / NE) - mu * mu;   // biased var, matches jnp.var
        smu = mu; srstd = rsqrtf(var + 1e-5f);
    }
    __syncthreads();
    float mu = smu, rstd = srstd;
    float4 gv = ((const float4*)g)[tid];
    float4 bv = ((const float4*)b)[tid];
    union { __hip_bfloat16 h[4]; ushort4 u; } cv;
    cv.h[0] = __float2bfloat16((v.x - mu) * rstd * gv.x + bv.x);
    cv.h[1] = __float2bfloat16((v.y - mu) * rstd * gv.y + bv.y);
    cv.h[2] = __float2bfloat16((v.z - mu) * rstd * gv.z + bv.z);
    cv.h[3] = __float2bfloat16((v.w - mu) * rstd * gv.w + bv.w);
    ((ushort4*)xn)[row * 256 + tid] = cv.u;
}

// ---------------- bf16 MFMA GEMM, 128x128 tile, BK=64, swizzled LDS --------
template<bool BF16OUT>
__global__ __launch_bounds__(256) void gemm_bf16mm(
    const __hip_bfloat16* __restrict__ A,
    const __hip_bfloat16* __restrict__ W,
    void* __restrict__ Cv, int N, int K)
{
    __shared__ __hip_bfloat16 As[128 * 64];   // 16 KB
    __shared__ __hip_bfloat16 Bs[128 * 64];   // 16 KB
    int tid = threadIdx.x;
    int lane = tid & 63;
    int w = tid >> 6, wr = w >> 1, wc = w & 1;
    int row0 = blockIdx.y * 128, col0 = blockIdx.x * 128;

    int sr = tid >> 3, sc = tid & 7;
    int gc = sc ^ (sr & 7);
    const __hip_bfloat16* ag = A + (size_t)(row0 + sr) * K + gc * 8;
    const __hip_bfloat16* bg = W + (size_t)(col0 + sr) * K + gc * 8;
    char* la_st = (char*)As + w * 1024;       // + j*4096 per round
    char* lb_st = (char*)Bs + w * 1024;
    const size_t rs32 = (size_t)32 * K;

    floatx4 acc[4][4];
    #pragma unroll
    for (int i = 0; i < 4; ++i)
        #pragma unroll
        for (int j = 0; j < 4; ++j) acc[i][j] = (floatx4){0.f, 0.f, 0.f, 0.f};

    int m = lane & 15, kq = lane >> 4;
    int s0 = kq ^ (m & 7);
    int s1 = (4 + kq) ^ (m & 7);
    const char* la0 = (const char*)As + (wr * 64 + m) * 128 + s0 * 16;
    const char* la1 = (const char*)As + (wr * 64 + m) * 128 + s1 * 16;
    const char* lb0 = (const char*)Bs + (wc * 64 + m) * 128 + s0 * 16;
    const char* lb1 = (const char*)Bs + (wc * 64 + m) * 128 + s1 * 16;

    for (int k0 = 0; k0 < K; k0 += 64) {
        #pragma unroll
        for (int j = 0; j < 4; ++j) {
            gld16(ag + j * rs32, la_st + j * 4096);
            gld16(bg + j * rs32, lb_st + j * 4096);
        }
        ag += 64; bg += 64;
        __syncthreads();
        {   // k-half 0
            short8 af[4], bf[4];
            #pragma unroll
            for (int i = 0; i < 4; ++i) {
                af[i] = *(const short8*)(la0 + i * 2048);   // +16 rows
                bf[i] = *(const short8*)(lb0 + i * 2048);
            }
            #pragma unroll
            for (int i = 0; i < 4; ++i)
                #pragma unroll
                for (int j = 0; j < 4; ++j)
                    acc[i][j] = __builtin_amdgcn_mfma_f32_16x16x32_bf16(
                        af[i], bf[j], acc[i][j], 0, 0, 0);
        }
        {   // k-half 1
            short8 af[4], bf[4];
            #pragma unroll
            for (int i = 0; i < 4; ++i) {
                af[i] = *(const short8*)(la1 + i * 2048);
                bf[i] = *(const short8*)(lb1 + i * 2048);
            }
            #pragma unroll
            for (int i = 0; i < 4; ++i)
                #pragma unroll
                for (int j = 0; j < 4; ++j)
                    acc[i][j] = __builtin_amdgcn_mfma_f32_16x16x32_bf16(
                        af[i], bf[j], acc[i][j], 0, 0, 0);
        }
        __syncthreads();
    }

    // C/D layout: col = lane&15 (n), row = (lane>>4)*4 + reg (m)
    int crow = row0 + wr * 64 + kq * 4;
    int ccol = col0 + wc * 64 + m;
    #pragma unroll
    for (int i = 0; i < 4; ++i)
        #pragma unroll
        for (int j = 0; j < 4; ++j)
            #pragma unroll
            for (int r2 = 0; r2 < 4; ++r2) {
                size_t rr = (size_t)(crow + i * 16 + r2);
                int cc = ccol + j * 16;
                if (BF16OUT)
                    ((__hip_bfloat16*)Cv)[rr * N + cc] = __float2bfloat16(acc[i][j][r2]);
                else
                    ((float*)Cv)[rr * N + cc] = acc[i][j][r2];
            }
}

// ---------------- dt_proj: bf16 MFMA, K=64 (single BK step) -----------------
// dlt[r,n] = softplus(dtx[r,:] . dtw[n,:] + bias[n]), bf16 out.
__global__ __launch_bounds__(256) void dtproj_mfma(
    const __hip_bfloat16* __restrict__ A,    // dtx 4096 x 64
    const __hip_bfloat16* __restrict__ W,    // dtw 2048 x 64
    const float* __restrict__ bias,
    __hip_bfloat16* __restrict__ dlt)
{
    __shared__ __hip_bfloat16 As[128 * 64];   // 16 KB
    __shared__ __hip_bfloat16 Bs[128 * 64];   // 16 KB
    int tid = threadIdx.x;
    int lane = tid & 63;
    int w = tid >> 6, wr = w >> 1, wc = w & 1;
    int row0 = blockIdx.y * 128, col0 = blockIdx.x * 128;
    const int K = DTR;                        // 64

    int sr = tid >> 3, sc = tid & 7;
    int gc = sc ^ (sr & 7);
    const __hip_bfloat16* ag = A + (size_t)(row0 + sr) * K + gc * 8;
    const __hip_bfloat16* bg = W + (size_t)(col0 + sr) * K + gc * 8;
    char* la_st = (char*)As + w * 1024;
    char* lb_st = (char*)Bs + w * 1024;
    const size_t rs32 = (size_t)32 * K;

    #pragma unroll
    for (int j = 0; j < 4; ++j) {
        gld16(ag + j * rs32, la_st + j * 4096);
        gld16(bg + j * rs32, lb_st + j * 4096);
    }

    floatx4 acc[4][4];
    #pragma unroll
    for (int i = 0; i < 4; ++i)
        #pragma unroll
        for (int j = 0; j < 4; ++j) acc[i][j] = (floatx4){0.f, 0.f, 0.f, 0.f};

    int m = lane & 15, kq = lane >> 4;
    int s0 = kq ^ (m & 7);
    int s1 = (4 + kq) ^ (m & 7);
    const char* la0 = (const char*)As + (wr * 64 + m) * 128 + s0 * 16;
    const char* la1 = (const char*)As + (wr * 64 + m) * 128 + s1 * 16;
    const char* lb0 = (const char*)Bs + (wc * 64 + m) * 128 + s0 * 16;
    const char* lb1 = (const char*)Bs + (wc * 64 + m) * 128 + s1 * 16;
    __syncthreads();
    {
        short8 af[4], bf[4];
        #pragma unroll
        for (int i = 0; i < 4; ++i) {
            af[i] = *(const short8*)(la0 + i * 2048);
            bf[i] = *(const short8*)(lb0 + i * 2048);
        }
        #pragma unroll
        for (int i = 0; i < 4; ++i)
            #pragma unroll
            for (int j = 0; j < 4; ++j)
                acc[i][j] = __builtin_amdgcn_mfma_f32_16x16x32_bf16(
                    af[i], bf[j], acc[i][j], 0, 0, 0);
    }
    {
        short8 af[4], bf[4];
        #pragma unroll
        for (int i = 0; i < 4; ++i) {
            af[i] = *(const short8*)(la1 + i * 2048);
            bf[i] = *(const short8*)(lb1 + i * 2048);
        }
        #pragma unroll
        for (int i = 0; i < 4; ++i)
            #pragma unroll
            for (int j = 0; j < 4; ++j)
                acc[i][j] = __builtin_amdgcn_mfma_f32_16x16x32_bf16(
                    af[i], bf[j], acc[i][j], 0, 0, 0);
    }

    int crow = row0 + wr * 64 + kq * 4;
    int ccol = col0 + wc * 64 + m;
    float bj[4];
    #pragma unroll
    for (int j = 0; j < 4; ++j) bj[j] = bias[ccol + j * 16];
    #pragma unroll
    for (int i = 0; i < 4; ++i)
        #pragma unroll
        for (int j = 0; j < 4; ++j)
            #pragma unroll
            for (int r2 = 0; r2 < 4; ++r2) {
                size_t rr = (size_t)(crow + i * 16 + r2);
                int cc = ccol + j * 16;
                dlt[rr * DI + cc] =
                    __float2bfloat16(softplus_fast(acc[i][j][r2] + bj[j]));
            }
}

// ---------------- bf16 MFMA GEMM, 64x128 tile, BK=64, fp32 out + resid ------
__global__ __launch_bounds__(256) void gemm_bf16_n128(
    const __hip_bfloat16* __restrict__ A,
    const __hip_bfloat16* __restrict__ W,
    const float* __restrict__ resid,
    float* __restrict__ C, int N, int K)
{
    __shared__ __hip_bfloat16 As[64 * 64];    // 8 KB
    __shared__ __hip_bfloat16 Bs[128 * 64];   // 16 KB
    int tid = threadIdx.x;
    int lane = tid & 63;
    int w = tid >> 6;
    int row0 = blockIdx.y * 64, col0 = blockIdx.x * 128;

    int sr = tid >> 3, sc = tid & 7;
    int gc = sc ^ (sr & 7);
    const __hip_bfloat16* ag = A + (size_t)(row0 + sr) * K + gc * 8;
    const __hip_bfloat16* bg = W + (size_t)(col0 + sr) * K + gc * 8;
    char* la_st = (char*)As + w * 1024;
    char* lb_st = (char*)Bs + w * 1024;
    const size_t rs32 = (size_t)32 * K;

    floatx4 acc[4][2];
    #pragma unroll
    for (int i = 0; i < 4; ++i)
        #pragma unroll
        for (int j = 0; j < 2; ++j) acc[i][j] = (floatx4){0.f, 0.f, 0.f, 0.f};

    int m = lane & 15, kq = lane >> 4;
    int s0 = kq ^ (m & 7);
    int s1 = (4 + kq) ^ (m & 7);
    const char* la0 = (const char*)As + m * 128 + s0 * 16;
    const char* la1 = (const char*)As + m * 128 + s1 * 16;
    const char* lb0 = (const char*)Bs + (w * 32 + m) * 128 + s0 * 16;
    const char* lb1 = (const char*)Bs + (w * 32 + m) * 128 + s1 * 16;

    for (int k0 = 0; k0 < K; k0 += 64) {
        gld16(ag,        la_st);              // A rows 0..31
        gld16(ag + rs32, la_st + 4096);       // A rows 32..63
        #pragma unroll
        for (int j = 0; j < 4; ++j)
            gld16(bg + j * rs32, lb_st + j * 4096);
        ag += 64; bg += 64;
        __syncthreads();
        {
            short8 af[4], bf[2];
            #pragma unroll
            for (int i = 0; i < 4; ++i) af[i] = *(const short8*)(la0 + i * 2048);
            #pragma unroll
            for (int j = 0; j < 2; ++j) bf[j] = *(const short8*)(lb0 + j * 2048);
            #pragma unroll
            for (int i = 0; i < 4; ++i)
                #pragma unroll
                for (int j = 0; j < 2; ++j)
                    acc[i][j] = __builtin_amdgcn_mfma_f32_16x16x32_bf16(
                        af[i], bf[j], acc[i][j], 0, 0, 0);
        }
        {
            short8 af[4], bf[2];
            #pragma unroll
            for (int i = 0; i < 4; ++i) af[i] = *(const short8*)(la1 + i * 2048);
            #pragma unroll
            for (int j = 0; j < 2; ++j) bf[j] = *(const short8*)(lb1 + j * 2048);
            #pragma unroll
            for (int i = 0; i < 4; ++i)
                #pragma unroll
                for (int j = 0; j < 2; ++j)
                    acc[i][j] = __builtin_amdgcn_mfma_f32_16x16x32_bf16(
                        af[i], bf[j], acc[i][j], 0, 0, 0);
        }
        __syncthreads();
    }

    int crow = row0 + kq * 4;
    int ccol = col0 + w * 32 + m;
    #pragma unroll
    for (int i = 0; i < 4; ++i)
        #pragma unroll
        for (int j = 0; j < 2; ++j)
            #pragma unroll
            for (int r2 = 0; r2 < 4; ++r2) {
                size_t rr = (size_t)(crow + i * 16 + r2);
                int cc = ccol + j * 16;
                C[rr * N + cc] = acc[i][j][r2] + resid[rr * N + cc];
            }
}

// ---------------- x_proj: bf16 MFMA, N=96, register-only (no LDS) ----------
__global__ __launch_bounds__(256) void xproj_kernel(
    const __hip_bfloat16* __restrict__ A,    // 4096 x 2048
    const __hip_bfloat16* __restrict__ W,    // 96 x 2048
    float* __restrict__ xpart)
{
    int tid = threadIdx.x;
    int lane = tid & 63;
    int w = tid >> 6;
    int kz = blockIdx.y;
    int row0 = blockIdx.x * 128 + w * 32;
    int m  = lane & 15;
    int kq = lane >> 4;                      // 0..3

    floatx4 acc[2][6];
    #pragma unroll
    for (int i = 0; i < 2; ++i)
        #pragma unroll
        for (int j = 0; j < 6; ++j) acc[i][j] = (floatx4){0.f, 0.f, 0.f, 0.f};

    const __hip_bfloat16* a0 = A + (size_t)(row0 + m) * DI + kz * (DI / SKX) + kq * 8;
    const __hip_bfloat16* b0 = W + (size_t)m * DI + kz * (DI / SKX) + kq * 8;

    #pragma unroll
    for (int ks = 0; ks < (DI / SKX) / 32; ++ks) {   // 8 steps of BK=32
        short8 af0 = *(const short8*)(a0);
        short8 af1 = *(const short8*)(a0 + (size_t)16 * DI);
        #pragma unroll
        for (int j = 0; j < 6; ++j) {
            short8 bf = *(const short8*)(b0 + (size_t)j * 16 * DI);
            acc[0][j] = __builtin_amdgcn_mfma_f32_16x16x32_bf16(af0, bf, acc[0][j], 0, 0, 0);
            acc[1][j] = __builtin_amdgcn_mfma_f32_16x16x32_bf16(af1, bf, acc[1][j], 0, 0, 0);
        }
        a0 += 32; b0 += 32;
    }

    float* cp = xpart + (size_t)kz * XPROJ_PART;
    int crow = row0 + kq * 4;
    #pragma unroll
    for (int i = 0; i < 2; ++i)
        #pragma unroll
        for (int j = 0; j < 6; ++j)
            #pragma unroll
            for (int r = 0; r < 4; ++r)
                cp[(size_t)(crow + i * 16 + r) * XDW + j * 16 + m] = acc[i][j][r];
}

// Reduce SKX partials into xdbl (fp32); also emit bf16 dt-columns for dtproj.
__global__ __launch_bounds__(256) void reduce8_kernel(
    const float* __restrict__ part, float* __restrict__ xdbl,
    __hip_bfloat16* __restrict__ dtx)
{
    int i = blockIdx.x * 256 + threadIdx.x;    // over 4096*96
    float s = 0.f;
    #pragma unroll
    for (int k = 0; k < SKX; ++k) s += part[(size_t)k * XPROJ_PART + i];
    xdbl[i] = s;
    int row = i / XDW;
    int col = i - row * XDW;
    if (col < DTR)
        dtx[(size_t)row * DTR + col] = __float2bfloat16(s);
}

// ---------------- Causal depthwise conv (width 4) + SiLU, bf16 in/out -------
__global__ __launch_bounds__(256) void conv_silu_kernel(
    const __hip_bfloat16* __restrict__ xz, const float* __restrict__ cw,
    const float* __restrict__ cb, ushort4* __restrict__ uc_bf)
{
    int i4 = blockIdx.x * 256 + threadIdx.x;   // 4-ch group over NB*LSEQ*DI/4
    int d4 = i4 & 511;                          // DI/4 = 512
    int bt = i4 >> 9;
    int t  = bt & (LSEQ - 1);
    int d  = d4 * 4;
    float4 w0 = *(const float4*)(cw + (size_t)(d+0) * 4);
    float4 w1 = *(const float4*)(cw + (size_t)(d+1) * 4);
    float4 w2 = *(const float4*)(cw + (size_t)(d+2) * 4);
    float4 w3 = *(const float4*)(cw + (size_t)(d+3) * 4);
    const float* wt0 = (const float*)&w0;
    const float* wt1 = (const float*)&w1;
    const float* wt2 = (const float*)&w2;
    const float* wt3 = (const float*)&w3;
    float4 acc = *(const float4*)(cb + d);
    const __hip_bfloat16* base = xz + ((size_t)bt << 12) + d;   // row stride 4096
    #pragma unroll
    for (int k = 0; k < 4; ++k) {
        int tp = t - 3 + k;
        if (tp >= 0) {
            union { ushort4 u; __hip_bfloat16 h[4]; } raw;
            raw.u = *(const ushort4*)(base - ((size_t)(3 - k) << 12));
            acc.x = fmaf(wt0[k], __bfloat162float(raw.h[0]), acc.x);
            acc.y = fmaf(wt1[k], __bfloat162float(raw.h[1]), acc.y);
            acc.z = fmaf(wt2[k], __bfloat162float(raw.h[2]), acc.z);
            acc.w = fmaf(wt3[k], __bfloat162float(raw.h[3]), acc.w);
        }
    }
    union { __hip_bfloat16 h[4]; ushort4 u; } cv;
    cv.h[0] = __float2bfloat16(siluf(acc.x));
    cv.h[1] = __float2bfloat16(siluf(acc.y));
    cv.h[2] = __float2bfloat16(siluf(acc.z));
    cv.h[3] = __float2bfloat16(siluf(acc.w));
    uc_bf[i4] = cv.u;
}

// ---------------- Chunk-parallel selective scan (bf16 u / res / dlt) --------
template<bool FINAL>
__global__ __launch_bounds__(256) void scan_chunk_kernel(
    const __hip_bfloat16* __restrict__ dlt, const __hip_bfloat16* __restrict__ uc,
    const float* __restrict__ xdbl, const float* __restrict__ A_log,
    const float* __restrict__ Dp, const __hip_bfloat16* __restrict__ xz,
    float* __restrict__ P, float* __restrict__ S,
    __hip_bfloat16* __restrict__ y)
{
    __shared__ float sBC[TCH][32];     // [tt][0:16]=B, [16:32]=C
    int tid = threadIdx.x;
    int d = blockIdx.x * 256 + tid;
    int c = blockIdx.y;
    int b = blockIdx.z;
    int row0 = b * LSEQ + c * TCH;

    {   // stage B,C rows of this chunk
        int tt = tid >> 3, j4 = (tid & 7) * 4;
        const float4* src = (const float4*)(xdbl + (size_t)(row0 + tt) * XDW + DTR + j4);
        *(float4*)(&sBC[tt][j4]) = *src;
    }
    __syncthreads();

    float Ac[DS], h[DS], p[DS];
    #pragma unroll
    for (int s = 0; s < DS; ++s) {
        Ac[s] = -expf(A_log[(size_t)d * DS + s]);
        p[s] = 1.f;
    }
    size_t soff = (((size_t)b * CCH + c) * DI + d) * DS;
    if (FINAL) {
        #pragma unroll
        for (int s = 0; s < DS; ++s) h[s] = S[soff + s];   // H0 from pass B
    } else {
        #pragma unroll
        for (int s = 0; s < DS; ++s) h[s] = 0.f;
    }
    float Dd = Dp[d];
    size_t ix = (size_t)row0 * DI + d;
    for (int tt = 0; tt < TCH; ++tt) {
        float dv = __bfloat162float(dlt[ix]);
        float ut = __bfloat162float(uc[ix]);
        float du = dv * ut;
        float yacc = 0.f;
        #pragma unroll
        for (int s = 0; s < DS; ++s) {
            float e = __expf(dv * Ac[s]);
            h[s] = fmaf(e, h[s], du * sBC[tt][s]);
            if (FINAL) yacc = fmaf(h[s], sBC[tt][16 + s], yacc);
            else       p[s] *= e;
        }
        if (FINAL) {
            float res = __bfloat162float(xz[((size_t)(row0 + tt) << 12) + DI + d]);
            y[ix] = __float2bfloat16(fmaf(ut, Dd, yacc) * siluf(res));
        }
        ix += DI;
    }
    if (!FINAL) {
        #pragma unroll
        for (int s = 0; s < DS; ++s) { P[soff + s] = p[s]; S[soff + s] = h[s]; }
    }
}

// Pass B: per (b,d,s), sequentially combine chunks; S[c] becomes H0 of chunk c.
__global__ __launch_bounds__(256) void scan_combine_kernel(
    const float* __restrict__ P, float* __restrict__ S)
{
    int idx = blockIdx.x * 256 + threadIdx.x;   // over NB*DI*DS = 65536
    int b = idx >> 15;                          // DI*DS = 32768
    int rest = idx & 32767;
    float h = 0.f;
    for (int c = 0; c < CCH; ++c) {
        size_t off = (((size_t)b * CCH + c) << 15) + rest;
        float tmp = S[off];
        float pv  = P[off];
        S[off] = h;                             // chunk-start state
        h = fmaf(pv, h, tmp);                   // chunk-end state
    }
}

extern "C" void kernel_launch(void* const* d_in, const int* in_sizes, int n_in,
                              void* d_out, int out_size, void* d_ws, size_t ws_size,
                              hipStream_t stream)
{
    const float* x        = (const float*)d_in[0];
    const float* ln_g     = (const float*)d_in[1];
    const float* ln_b     = (const float*)d_in[2];
    const float* in_w     = (const float*)d_in[3];   // (4096, 1024)
    const float* conv_w   = (const float*)d_in[4];   // (2048, 1, 4)
    const float* conv_b   = (const float*)d_in[5];
    const float* xproj_w  = (const float*)d_in[6];   // (96, 2048)
    const float* dtproj_w = (const float*)d_in[7];   // (2048, 64)
    const float* dtproj_b = (const float*)d_in[8];
    const float* A_log    = (const float*)d_in[9];   // (2048, 16)
    const float* Dvec     = (const float*)d_in[10];
    const float* out_w    = (const float*)d_in[11];  // (1024, 2048)
    float* out = (float*)d_out;

    // Workspace layout (byte offsets). Total 157,941,760 B = 157.9 MB.
    char* base = (char*)d_ws;
    __hip_bfloat16* xz_bf    = (__hip_bfloat16*)(base + 0);           // 4096x4096
    __hip_bfloat16* dlt_bf   = (__hip_bfloat16*)(base + 33554432);    // 4096x2048 bf16
    __hip_bfloat16* uc_bf    = (__hip_bfloat16*)(base + 67108864);    // 4096x2048
    float*          xdbl     = (float*)         (base + 83886080);    // 4096x96
    float*          xpart    = (float*)         (base + 85458944);    // 8x4096x96
    float*          Pch      = (float*)         (base + 85458944);    // alias (xpart dead after reduce8)
    float*          Sch      = (float*)         (base + 102236160);   // 2x64x2048x16
    __hip_bfloat16* xnorm_bf = (__hip_bfloat16*)(base + 119013376);   // 4096x1024
    __hip_bfloat16* yb_bf    = (__hip_bfloat16*)(base + 127401984);   // 4096x2048
    __hip_bfloat16* inw_bf   = (__hip_bfloat16*)(base + 144179200);   // 4096x1024
    __hip_bfloat16* outw_bf  = (__hip_bfloat16*)(base + 152567808);   // 1024x2048
    __hip_bfloat16* xpw_bf   = (__hip_bfloat16*)(base + 156762112);   // 96x2048
    __hip_bfloat16* dtx_bf   = (__hip_bfloat16*)(base + 157155328);   // 4096x64
    __hip_bfloat16* dtw_bf   = (__hip_bfloat16*)(base + 157679616);   // 2048x64

    const int R = NB * LSEQ;                  // 4096 rows

    // 0+1. weight conversions + LayerNorm in one launch
    prep_kernel<<<LN_BLOCKS + F2BF_BLOCKS, 256, 0, stream>>>(
        x, ln_g, ln_b, xnorm_bf,
        in_w, (ushort4*)inw_bf, out_w, (ushort4*)outw_bf,
        xproj_w, (ushort4*)xpw_bf, dtproj_w, (ushort4*)dtw_bf);
    // 2. in_proj (bf16 MFMA, BK=64, swizzled LDS): xz = xnorm @ in_w^T, bf16 out
    gemm_bf16mm<true><<<dim3((2*DI)/128, R/128), 256, 0, stream>>>(
        xnorm_bf, inw_bf, (void*)xz_bf, 2*DI, NE);
    // 3. causal depthwise conv + SiLU -> uc_bf
    conv_silu_kernel<<<(R * DI / 4) / 256, 256, 0, stream>>>(
        xz_bf, conv_w, conv_b, (ushort4*)uc_bf);
    // 4. x_proj (bf16 MFMA, register-only, split-K) + one-pass reduce (+bf16 dtx)
    xproj_kernel<<<dim3(R/128, SKX), 256, 0, stream>>>(uc_bf, xpw_bf, xpart);
    reduce8_kernel<<<(R * XDW) / 256, 256, 0, stream>>>(xpart, xdbl, dtx_bf);
    // 5. dt_proj + softplus (bf16 MFMA, single K-step) -> dlt (bf16)
    dtproj_mfma<<<dim3(DI/128, R/128), 256, 0, stream>>>(
        dtx_bf, dtw_bf, dtproj_b, dlt_bf);
    // 6. chunk-parallel selective scan (gate fused, bf16 y) -> yb_bf
    dim3 gScan(DI / 256, CCH, NB);            // 8 x 64 x 2 = 1024 blocks
    scan_chunk_kernel<false><<<gScan, 256, 0, stream>>>(
        dlt_bf, uc_bf, xdbl, A_log, Dvec, xz_bf, Pch, Sch, yb_bf);
    scan_combine_kernel<<<(NB * DI * DS) / 256, 256, 0, stream>>>(Pch, Sch);
    scan_chunk_kernel<true><<<gScan, 256, 0, stream>>>(
        dlt_bf, uc_bf, xdbl, A_log, Dvec, xz_bf, Pch, Sch, yb_bf);
    // 7. out_proj (bf16 MFMA, 64x128 tile, BK=64) + residual
    gemm_bf16_n128<<<dim3(NE/128, R/64), 256, 0, stream>>>(
        yb_bf, outw_bf, x, out, NE, DI);
}